// Round 1
// baseline (889.993 us; speedup 1.0000x reference)
//
#include <hip/hip_runtime.h>
#include <math.h>

#define N_NODES 100000
#define N_EDGES 400000
#define NG 2048
#define H 128
#define NLAYERS 3
#define SLOPE 0.2f

__device__ __forceinline__ float wave_reduce_sum(float v){
  #pragma unroll
  for (int off = 32; off > 0; off >>= 1) v += __shfl_xor(v, off, 64);
  return v;
}
__device__ __forceinline__ float wave_reduce_max(float v){
  #pragma unroll
  for (int off = 32; off > 0; off >>= 1) v = fmaxf(v, __shfl_xor(v, off, 64));
  return v;
}

// ---- preprocessing ----------------------------------------------------------

// scal[0] = sum(edge_attr)
__global__ void k_ea_sum(const float* __restrict__ ea, float* __restrict__ scal){
  int i = blockIdx.x * blockDim.x + threadIdx.x;
  int stride = gridDim.x * blockDim.x;
  float v = 0.f;
  for (; i < N_EDGES; i += stride) v += ea[i];
  v = wave_reduce_sum(v);
  if ((threadIdx.x & 63) == 0) atomicAdd(&scal[0], v);
}

// scal[1+l] = dot(edge_W[l], att_edge[l]); one wave per layer
__global__ void k_dots(const float* __restrict__ ew, const float* __restrict__ ae,
                       float* __restrict__ scal){
  int l = blockIdx.x;
  int lane = threadIdx.x;  // blockDim = 64
  float p = ew[l*H + lane]*ae[l*H + lane] + ew[l*H + lane + 64]*ae[l*H + lane + 64];
  p = wave_reduce_sum(p);
  if (lane == 0) scal[1 + l] = p;
}

// h[n,:] = emb[x[n],:]
__global__ void k_embed(const int* __restrict__ x, const float* __restrict__ emb,
                        float* __restrict__ h){
  int i = blockIdx.x * blockDim.x + threadIdx.x;    // one float4 each
  if (i >= N_NODES * (H/4)) return;
  int n  = i >> 5;            // / (H/4)
  int c4 = (i & 31) << 2;
  int v = x[n];
  *(float4*)(h + (size_t)n*H + c4) = *(const float4*)(emb + (size_t)v*H + c4);
}

// degree count over E real edges + N self loops
__global__ void k_deg(const int* __restrict__ ei, int* __restrict__ deg){
  int i = blockIdx.x * blockDim.x + threadIdx.x;
  if (i >= N_EDGES + N_NODES) return;
  int d = (i < N_EDGES) ? ei[N_EDGES + i] : (i - N_EDGES);
  atomicAdd(&deg[d], 1);
}

// allocate disjoint CSR ranges (order across nodes is irrelevant -> no scan)
__global__ void k_alloc(const int* __restrict__ deg, int* __restrict__ row_ptr,
                        int* __restrict__ counter){
  int n = blockIdx.x * blockDim.x + threadIdx.x;
  if (n >= N_NODES) return;
  row_ptr[n] = atomicAdd(counter, deg[n]);
}

__global__ void k_scatter(const int* __restrict__ ei, const float* __restrict__ ea,
                          const float* __restrict__ scal, const int* __restrict__ row_ptr,
                          int* __restrict__ cursor, int* __restrict__ csr_src,
                          float* __restrict__ csr_ea){
  int i = blockIdx.x * blockDim.x + threadIdx.x;
  if (i >= N_EDGES + N_NODES) return;
  int s, d; float v;
  if (i < N_EDGES){ s = ei[i]; d = ei[N_EDGES + i]; v = ea[i]; }
  else            { s = d = i - N_EDGES; v = scal[0] * (1.0f / N_EDGES); }  // ea_mean
  int pos = row_ptr[d] + atomicAdd(&cursor[d], 1);
  csr_src[pos] = s;
  csr_ea[pos]  = v;
}

// ---- GEMM: C[n,j] = sum_k A[n,k] W[k,j]  (+fused epilogues) -----------------
// mode 0: write C=xt, plus a_s[n]=xt[n]·att_src, a_d[n]=xt[n]·att_dst
// mode 1: C = relu(A@W + bias)
__global__ __launch_bounds__(256) void k_gemm(
    const float* __restrict__ A, const float* __restrict__ W,
    float* __restrict__ C,
    const float* __restrict__ attn_s, const float* __restrict__ attn_d,
    float* __restrict__ a_s_out, float* __restrict__ a_d_out,
    const float* __restrict__ bias, int mode, int nrows)
{
  __shared__ float hs[64 * 132];   // 64 rows x 128 cols, +4 pad
  int tid = threadIdx.x;
  int tx = tid & 15;               // col group: j0 = tx*8
  int ty = tid >> 4;               // row group: 4 rows each
  size_t block_n = (size_t)blockIdx.x * 64;

  #pragma unroll
  for (int it = 0; it < 8; ++it){
    int flat = (it*256 + tid) * 4;
    int r  = flat >> 7;
    int cc = flat & 127;
    size_t gr = block_n + r;
    float4 v = make_float4(0.f,0.f,0.f,0.f);
    if (gr < (size_t)nrows) v = *(const float4*)(A + gr*H + cc);
    *(float4*)(hs + r*132 + cc) = v;
  }
  __syncthreads();

  int j0 = tx * 8;
  float acc[4][8];
  #pragma unroll
  for (int m = 0; m < 4; ++m)
    #pragma unroll
    for (int i = 0; i < 8; ++i) acc[m][i] = 0.f;

  for (int k = 0; k < H; ++k){
    float4 w0 = *(const float4*)(W + k*H + j0);
    float4 w1 = *(const float4*)(W + k*H + j0 + 4);
    #pragma unroll
    for (int m = 0; m < 4; ++m){
      float a = hs[(ty*4 + m)*132 + k];
      acc[m][0] += a*w0.x; acc[m][1] += a*w0.y; acc[m][2] += a*w0.z; acc[m][3] += a*w0.w;
      acc[m][4] += a*w1.x; acc[m][5] += a*w1.y; acc[m][6] += a*w1.z; acc[m][7] += a*w1.w;
    }
  }

  if (mode == 0){
    float as8[8], ad8[8];
    #pragma unroll
    for (int i = 0; i < 8; ++i){ as8[i] = attn_s[j0+i]; ad8[i] = attn_d[j0+i]; }
    #pragma unroll
    for (int m = 0; m < 4; ++m){
      size_t gr = block_n + ty*4 + m;
      bool ok = gr < (size_t)nrows;
      if (ok){
        *(float4*)(C + gr*H + j0)     = make_float4(acc[m][0],acc[m][1],acc[m][2],acc[m][3]);
        *(float4*)(C + gr*H + j0 + 4) = make_float4(acc[m][4],acc[m][5],acc[m][6],acc[m][7]);
      }
      float ps = 0.f, pd = 0.f;
      #pragma unroll
      for (int i = 0; i < 8; ++i){ ps += acc[m][i]*as8[i]; pd += acc[m][i]*ad8[i]; }
      #pragma unroll
      for (int msk = 8; msk > 0; msk >>= 1){
        ps += __shfl_xor(ps, msk, 64);
        pd += __shfl_xor(pd, msk, 64);
      }
      if (ok && tx == 0){ a_s_out[gr] = ps; a_d_out[gr] = pd; }
    }
  } else {
    float b8[8];
    #pragma unroll
    for (int i = 0; i < 8; ++i) b8[i] = bias[j0+i];
    #pragma unroll
    for (int m = 0; m < 4; ++m){
      size_t gr = block_n + ty*4 + m;
      if (gr >= (size_t)nrows) continue;
      float r[8];
      #pragma unroll
      for (int i = 0; i < 8; ++i) r[i] = fmaxf(acc[m][i] + b8[i], 0.f);
      *(float4*)(C + gr*H + j0)     = make_float4(r[0],r[1],r[2],r[3]);
      *(float4*)(C + gr*H + j0 + 4) = make_float4(r[4],r[5],r[6],r[7]);
    }
  }
}

// ---- per-node softmax-aggregate + bias + L2 normalize -----------------------
__global__ __launch_bounds__(128) void k_aggregate(
    const float* __restrict__ xt, const float* __restrict__ a_s,
    const float* __restrict__ a_d, const int* __restrict__ csr_src,
    const float* __restrict__ csr_ea, const int* __restrict__ row_ptr,
    const int* __restrict__ deg, const float* __restrict__ scal, int l,
    const float* __restrict__ bias, float* __restrict__ hout)
{
  __shared__ float red[2];
  int n = blockIdx.x;
  int tid = threadIdx.x;
  int beg = row_ptr[n];
  int end = beg + deg[n];
  float adn = a_d[n];
  float dl = scal[1 + l];

  // pass 1: segment max (threads stride over edges)
  float m = -1e30f;
  for (int e = beg + tid; e < end; e += 128){
    float lg = a_s[csr_src[e]] + adn + dl*csr_ea[e];
    lg = (lg > 0.f) ? lg : SLOPE*lg;
    m = fmaxf(m, lg);
  }
  m = wave_reduce_max(m);
  if ((tid & 63) == 0) red[tid >> 6] = m;
  __syncthreads();
  m = fmaxf(red[0], red[1]);
  __syncthreads();

  // pass 2: every thread walks all edges (scalar ops broadcast from cache);
  // thread tid accumulates feature column `tid`. Divide by softmax denom at end.
  float acc = 0.f, ssum = 0.f;
  for (int e = beg; e < end; ++e){
    int s = csr_src[e];
    float lg = a_s[s] + adn + dl*csr_ea[e];
    lg = (lg > 0.f) ? lg : SLOPE*lg;
    float w = __expf(lg - m);
    ssum += w;
    acc += w * xt[(size_t)s*H + tid];
  }
  acc = acc / ssum + bias[tid];

  float sq = wave_reduce_sum(acc*acc);
  if ((tid & 63) == 0) red[tid >> 6] = sq;
  __syncthreads();
  float nrm = sqrtf(red[0] + red[1]);
  hout[(size_t)n*H + tid] = acc / fmaxf(nrm, 1e-12f);
}

// ---- readout ----------------------------------------------------------------
__global__ void k_out_init(float* __restrict__ out, const float* __restrict__ wp_b){
  int g = blockIdx.x * blockDim.x + threadIdx.x;
  if (g < NG) out[g] = wp_b[0];
}

// out[batch[n]] += h[n]·wp  (readout dot commutes with segment sum)
__global__ void k_readout(const float* __restrict__ h, const int* __restrict__ batch,
                          const float* __restrict__ wp, float* __restrict__ out){
  int node = blockIdx.x * 4 + (threadIdx.x >> 6);
  int lane = threadIdx.x & 63;
  if (node >= N_NODES) return;
  const float* hr = h + (size_t)node*H;
  float s = hr[lane]*wp[lane] + hr[lane + 64]*wp[lane + 64];
  s = wave_reduce_sum(s);
  if (lane == 0) atomicAdd(&out[batch[node]], s);
}

// ---- launch -----------------------------------------------------------------
extern "C" void kernel_launch(void* const* d_in, const int* in_sizes, int n_in,
                              void* d_out, int out_size, void* d_ws, size_t ws_size,
                              hipStream_t stream) {
  const int*   x          = (const int*)  d_in[0];
  const int*   edge_index = (const int*)  d_in[1];
  const float* edge_attr  = (const float*)d_in[2];
  const int*   batch      = (const int*)  d_in[3];
  const float* emb        = (const float*)d_in[4];
  const float* gat_W      = (const float*)d_in[5];
  const float* att_src    = (const float*)d_in[6];
  const float* att_dst    = (const float*)d_in[7];
  const float* edge_W     = (const float*)d_in[8];
  const float* att_edge   = (const float*)d_in[9];
  const float* gat_b      = (const float*)d_in[10];
  const float* lin_W      = (const float*)d_in[11];
  const float* lin_b      = (const float*)d_in[12];
  const float* wp_W       = (const float*)d_in[13];
  const float* wp_b       = (const float*)d_in[14];
  float* out = (float*)d_out;

  // workspace layout
  float* ws     = (float*)d_ws;
  float* h      = ws;                                   // N*H
  float* xt     = h + (size_t)N_NODES*H;                // N*H
  float* a_s    = xt + (size_t)N_NODES*H;               // N
  float* a_d    = a_s + N_NODES;                        // N
  float* csr_ea = a_d + N_NODES;                        // E+N
  float* scal   = csr_ea + (N_EDGES + N_NODES);         // 8: [0]=ea_sum,[1..3]=dotl,[4]=counter(int)
  int*   deg    = (int*)(scal + 8);                     // N   (zeroed)
  int*   cursor = deg + N_NODES;                        // N   (zeroed)
  int*   row_ptr= cursor + N_NODES;                     // N
  int*   csr_src= row_ptr + N_NODES;                    // E+N

  // zero scal + deg + cursor (contiguous)
  hipMemsetAsync(scal, 0, (size_t)(8 + 2*N_NODES) * sizeof(float), stream);

  k_ea_sum<<<256, 256, 0, stream>>>(edge_attr, scal);
  k_dots  <<<NLAYERS, 64, 0, stream>>>(edge_W, att_edge, scal);
  k_embed <<<(N_NODES*(H/4) + 255)/256, 256, 0, stream>>>(x, emb, h);
  k_deg   <<<(N_EDGES + N_NODES + 255)/256, 256, 0, stream>>>(edge_index, deg);
  k_alloc <<<(N_NODES + 255)/256, 256, 0, stream>>>(deg, row_ptr, (int*)&scal[4]);
  k_scatter<<<(N_EDGES + N_NODES + 255)/256, 256, 0, stream>>>(
      edge_index, edge_attr, scal, row_ptr, cursor, csr_src, csr_ea);

  const int gemm_grid = (N_NODES + 63) / 64;
  for (int l = 0; l < NLAYERS; ++l){
    k_gemm<<<gemm_grid, 256, 0, stream>>>(
        h, gat_W + (size_t)l*H*H, xt,
        att_src + l*H, att_dst + l*H, a_s, a_d,
        nullptr, 0, N_NODES);
    k_aggregate<<<N_NODES, 128, 0, stream>>>(
        xt, a_s, a_d, csr_src, csr_ea, row_ptr, deg, scal, l,
        gat_b + l*H, h);
  }
  // dense layers: h -> xt -> h
  k_gemm<<<gemm_grid, 256, 0, stream>>>(h, lin_W,           xt, nullptr, nullptr,
                                        nullptr, nullptr, lin_b,     1, N_NODES);
  k_gemm<<<gemm_grid, 256, 0, stream>>>(xt, lin_W + H*H,    h,  nullptr, nullptr,
                                        nullptr, nullptr, lin_b + H, 1, N_NODES);

  k_out_init<<<(NG + 255)/256, 256, 0, stream>>>(out, wp_b);
  k_readout <<<(N_NODES + 3)/4, 256, 0, stream>>>(h, batch, wp_W, out);
}

// Round 2
// 851.839 us; speedup vs baseline: 1.0448x; 1.0448x over previous
//
#include <hip/hip_runtime.h>
#include <math.h>

#define N_NODES 100000
#define N_EDGES 400000
#define NG 2048
#define H 128
#define NLAYERS 3
#define SLOPE 0.2f

__device__ __forceinline__ float wave_reduce_sum(float v){
  #pragma unroll
  for (int off = 32; off > 0; off >>= 1) v += __shfl_xor(v, off, 64);
  return v;
}

// ---- preprocessing ----------------------------------------------------------

// scal[0] = sum(edge_attr)
__global__ void k_ea_sum(const float* __restrict__ ea, float* __restrict__ scal){
  int i = blockIdx.x * blockDim.x + threadIdx.x;
  int stride = gridDim.x * blockDim.x;
  float v = 0.f;
  for (; i < N_EDGES; i += stride) v += ea[i];
  v = wave_reduce_sum(v);
  if ((threadIdx.x & 63) == 0) atomicAdd(&scal[0], v);
}

// scal[1+l] = dot(edge_W[l], att_edge[l]); one wave per layer
__global__ void k_dots(const float* __restrict__ ew, const float* __restrict__ ae,
                       float* __restrict__ scal){
  int l = blockIdx.x;
  int lane = threadIdx.x;  // blockDim = 64
  float p = ew[l*H + lane]*ae[l*H + lane] + ew[l*H + lane + 64]*ae[l*H + lane + 64];
  p = wave_reduce_sum(p);
  if (lane == 0) scal[1 + l] = p;
}

// h[n,:] = emb[x[n],:]
__global__ void k_embed(const int* __restrict__ x, const float* __restrict__ emb,
                        float* __restrict__ h){
  int i = blockIdx.x * blockDim.x + threadIdx.x;    // one float4 each
  if (i >= N_NODES * (H/4)) return;
  int n  = i >> 5;            // / (H/4)
  int c4 = (i & 31) << 2;
  int v = x[n];
  *(float4*)(h + (size_t)n*H + c4) = *(const float4*)(emb + (size_t)v*H + c4);
}

// degree count over E real edges + N self loops
__global__ void k_deg(const int* __restrict__ ei, int* __restrict__ deg){
  int i = blockIdx.x * blockDim.x + threadIdx.x;
  if (i >= N_EDGES + N_NODES) return;
  int d = (i < N_EDGES) ? ei[N_EDGES + i] : (i - N_EDGES);
  atomicAdd(&deg[d], 1);
}

// allocate disjoint CSR ranges (order across nodes is irrelevant -> no scan)
__global__ void k_alloc(const int* __restrict__ deg, int* __restrict__ row_ptr,
                        int* __restrict__ counter){
  int n = blockIdx.x * blockDim.x + threadIdx.x;
  if (n >= N_NODES) return;
  row_ptr[n] = atomicAdd(counter, deg[n]);
}

__global__ void k_scatter(const int* __restrict__ ei, const float* __restrict__ ea,
                          const float* __restrict__ scal, const int* __restrict__ row_ptr,
                          int* __restrict__ cursor, int* __restrict__ csr_src,
                          float* __restrict__ csr_ea){
  int i = blockIdx.x * blockDim.x + threadIdx.x;
  if (i >= N_EDGES + N_NODES) return;
  int s, d; float v;
  if (i < N_EDGES){ s = ei[i]; d = ei[N_EDGES + i]; v = ea[i]; }
  else            { s = d = i - N_EDGES; v = scal[0] * (1.0f / N_EDGES); }  // ea_mean
  int pos = row_ptr[d] + atomicAdd(&cursor[d], 1);
  csr_src[pos] = s;
  csr_ea[pos]  = v;
}

// ---- GEMM: C[n,j] = sum_k A[n,k] W[k,j]  (+fused epilogues) -----------------
// mode 0: write C=xt, plus a_s[n]=xt[n]·att_src, a_d[n]=xt[n]·att_dst
// mode 1: C = relu(A@W + bias)
__global__ __launch_bounds__(256) void k_gemm(
    const float* __restrict__ A, const float* __restrict__ W,
    float* __restrict__ C,
    const float* __restrict__ attn_s, const float* __restrict__ attn_d,
    float* __restrict__ a_s_out, float* __restrict__ a_d_out,
    const float* __restrict__ bias, int mode, int nrows)
{
  __shared__ float hs[64 * 132];   // 64 rows x 128 cols, +4 pad
  int tid = threadIdx.x;
  int tx = tid & 15;               // col group: j0 = tx*8
  int ty = tid >> 4;               // row group: 4 rows each
  size_t block_n = (size_t)blockIdx.x * 64;

  #pragma unroll
  for (int it = 0; it < 8; ++it){
    int flat = (it*256 + tid) * 4;
    int r  = flat >> 7;
    int cc = flat & 127;
    size_t gr = block_n + r;
    float4 v = make_float4(0.f,0.f,0.f,0.f);
    if (gr < (size_t)nrows) v = *(const float4*)(A + gr*H + cc);
    *(float4*)(hs + r*132 + cc) = v;
  }
  __syncthreads();

  int j0 = tx * 8;
  float acc[4][8];
  #pragma unroll
  for (int m = 0; m < 4; ++m)
    #pragma unroll
    for (int i = 0; i < 8; ++i) acc[m][i] = 0.f;

  for (int k = 0; k < H; ++k){
    float4 w0 = *(const float4*)(W + k*H + j0);
    float4 w1 = *(const float4*)(W + k*H + j0 + 4);
    #pragma unroll
    for (int m = 0; m < 4; ++m){
      float a = hs[(ty*4 + m)*132 + k];
      acc[m][0] += a*w0.x; acc[m][1] += a*w0.y; acc[m][2] += a*w0.z; acc[m][3] += a*w0.w;
      acc[m][4] += a*w1.x; acc[m][5] += a*w1.y; acc[m][6] += a*w1.z; acc[m][7] += a*w1.w;
    }
  }

  if (mode == 0){
    float as8[8], ad8[8];
    #pragma unroll
    for (int i = 0; i < 8; ++i){ as8[i] = attn_s[j0+i]; ad8[i] = attn_d[j0+i]; }
    #pragma unroll
    for (int m = 0; m < 4; ++m){
      size_t gr = block_n + ty*4 + m;
      bool ok = gr < (size_t)nrows;
      if (ok){
        *(float4*)(C + gr*H + j0)     = make_float4(acc[m][0],acc[m][1],acc[m][2],acc[m][3]);
        *(float4*)(C + gr*H + j0 + 4) = make_float4(acc[m][4],acc[m][5],acc[m][6],acc[m][7]);
      }
      float ps = 0.f, pd = 0.f;
      #pragma unroll
      for (int i = 0; i < 8; ++i){ ps += acc[m][i]*as8[i]; pd += acc[m][i]*ad8[i]; }
      #pragma unroll
      for (int msk = 8; msk > 0; msk >>= 1){
        ps += __shfl_xor(ps, msk, 64);
        pd += __shfl_xor(pd, msk, 64);
      }
      if (ok && tx == 0){ a_s_out[gr] = ps; a_d_out[gr] = pd; }
    }
  } else {
    float b8[8];
    #pragma unroll
    for (int i = 0; i < 8; ++i) b8[i] = bias[j0+i];
    #pragma unroll
    for (int m = 0; m < 4; ++m){
      size_t gr = block_n + ty*4 + m;
      if (gr >= (size_t)nrows) continue;
      float r[8];
      #pragma unroll
      for (int i = 0; i < 8; ++i) r[i] = fmaxf(acc[m][i] + b8[i], 0.f);
      *(float4*)(C + gr*H + j0)     = make_float4(r[0],r[1],r[2],r[3]);
      *(float4*)(C + gr*H + j0 + 4) = make_float4(r[4],r[5],r[6],r[7]);
    }
  }
}

// ---- per-node softmax-aggregate + bias + L2 normalize -----------------------
// No max-subtraction: exp(lg)/sum(exp(lg)) is mathematically identical to the
// stabilized form; logits here are O(+-6) so fp32 exp is safe.
// 8-wide clamped unroll: 8 independent gathers in flight -> 2 latency levels
// per round instead of 2 per edge.
__global__ __launch_bounds__(128) void k_aggregate(
    const float* __restrict__ xt, const float* __restrict__ a_s,
    const float* __restrict__ a_d, const int* __restrict__ csr_src,
    const float* __restrict__ csr_ea, const int* __restrict__ row_ptr,
    const int* __restrict__ deg, const float* __restrict__ scal, int l,
    const float* __restrict__ bias, float* __restrict__ hout)
{
  __shared__ float red[2];
  int n = blockIdx.x;
  int tid = threadIdx.x;
  int beg = row_ptr[n];
  int last = beg + deg[n] - 1;      // deg >= 1 (self loop)
  float adn = a_d[n];
  float dl = scal[1 + l];

  float acc = 0.f, ss = 0.f;
  for (int e = beg; e <= last; e += 8){
    int   si[8]; float eai[8], msk[8];
    #pragma unroll
    for (int j = 0; j < 8; ++j){
      int idx = e + j;
      int c   = idx <= last ? idx : last;
      msk[j]  = idx <= last ? 1.f : 0.f;
      si[j]   = csr_src[c];
      eai[j]  = csr_ea[c];
    }
    float xv[8], asv[8];
    #pragma unroll
    for (int j = 0; j < 8; ++j){
      xv[j]  = xt[(size_t)si[j]*H + tid];
      asv[j] = a_s[si[j]];
    }
    #pragma unroll
    for (int j = 0; j < 8; ++j){
      float lg = asv[j] + adn + dl*eai[j];
      lg = (lg > 0.f) ? lg : SLOPE*lg;
      float w = msk[j] * __expf(lg);
      ss  += w;
      acc += w * xv[j];
    }
  }

  acc = acc / ss + bias[tid];

  float sq = wave_reduce_sum(acc*acc);
  if ((tid & 63) == 0) red[tid >> 6] = sq;
  __syncthreads();
  float nrm = sqrtf(red[0] + red[1]);
  hout[(size_t)n*H + tid] = acc / fmaxf(nrm, 1e-12f);
}

// ---- readout ----------------------------------------------------------------
__global__ void k_out_init(float* __restrict__ out, const float* __restrict__ wp_b){
  int g = blockIdx.x * blockDim.x + threadIdx.x;
  if (g < NG) out[g] = wp_b[0];
}

// out[batch[n]] += h[n]·wp  (readout dot commutes with segment sum)
__global__ void k_readout(const float* __restrict__ h, const int* __restrict__ batch,
                          const float* __restrict__ wp, float* __restrict__ out){
  int node = blockIdx.x * 4 + (threadIdx.x >> 6);
  int lane = threadIdx.x & 63;
  if (node >= N_NODES) return;
  const float* hr = h + (size_t)node*H;
  float s = hr[lane]*wp[lane] + hr[lane + 64]*wp[lane + 64];
  s = wave_reduce_sum(s);
  if (lane == 0) atomicAdd(&out[batch[node]], s);
}

// ---- launch -----------------------------------------------------------------
extern "C" void kernel_launch(void* const* d_in, const int* in_sizes, int n_in,
                              void* d_out, int out_size, void* d_ws, size_t ws_size,
                              hipStream_t stream) {
  const int*   x          = (const int*)  d_in[0];
  const int*   edge_index = (const int*)  d_in[1];
  const float* edge_attr  = (const float*)d_in[2];
  const int*   batch      = (const int*)  d_in[3];
  const float* emb        = (const float*)d_in[4];
  const float* gat_W      = (const float*)d_in[5];
  const float* att_src    = (const float*)d_in[6];
  const float* att_dst    = (const float*)d_in[7];
  const float* edge_W     = (const float*)d_in[8];
  const float* att_edge   = (const float*)d_in[9];
  const float* gat_b      = (const float*)d_in[10];
  const float* lin_W      = (const float*)d_in[11];
  const float* lin_b      = (const float*)d_in[12];
  const float* wp_W       = (const float*)d_in[13];
  const float* wp_b       = (const float*)d_in[14];
  float* out = (float*)d_out;

  // workspace layout
  float* ws     = (float*)d_ws;
  float* h      = ws;                                   // N*H
  float* xt     = h + (size_t)N_NODES*H;                // N*H
  float* a_s    = xt + (size_t)N_NODES*H;               // N
  float* a_d    = a_s + N_NODES;                        // N
  float* csr_ea = a_d + N_NODES;                        // E+N
  float* scal   = csr_ea + (N_EDGES + N_NODES);         // 8: [0]=ea_sum,[1..3]=dotl,[4]=counter(int)
  int*   deg    = (int*)(scal + 8);                     // N   (zeroed)
  int*   cursor = deg + N_NODES;                        // N   (zeroed)
  int*   row_ptr= cursor + N_NODES;                     // N
  int*   csr_src= row_ptr + N_NODES;                    // E+N

  // zero scal + deg + cursor (contiguous)
  hipMemsetAsync(scal, 0, (size_t)(8 + 2*N_NODES) * sizeof(float), stream);

  k_ea_sum<<<256, 256, 0, stream>>>(edge_attr, scal);
  k_dots  <<<NLAYERS, 64, 0, stream>>>(edge_W, att_edge, scal);
  k_embed <<<(N_NODES*(H/4) + 255)/256, 256, 0, stream>>>(x, emb, h);
  k_deg   <<<(N_EDGES + N_NODES + 255)/256, 256, 0, stream>>>(edge_index, deg);
  k_alloc <<<(N_NODES + 255)/256, 256, 0, stream>>>(deg, row_ptr, (int*)&scal[4]);
  k_scatter<<<(N_EDGES + N_NODES + 255)/256, 256, 0, stream>>>(
      edge_index, edge_attr, scal, row_ptr, cursor, csr_src, csr_ea);

  const int gemm_grid = (N_NODES + 63) / 64;
  for (int l = 0; l < NLAYERS; ++l){
    k_gemm<<<gemm_grid, 256, 0, stream>>>(
        h, gat_W + (size_t)l*H*H, xt,
        att_src + l*H, att_dst + l*H, a_s, a_d,
        nullptr, 0, N_NODES);
    k_aggregate<<<N_NODES, 128, 0, stream>>>(
        xt, a_s, a_d, csr_src, csr_ea, row_ptr, deg, scal, l,
        gat_b + l*H, h);
  }
  // dense layers: h -> xt -> h
  k_gemm<<<gemm_grid, 256, 0, stream>>>(h, lin_W,           xt, nullptr, nullptr,
                                        nullptr, nullptr, lin_b,     1, N_NODES);
  k_gemm<<<gemm_grid, 256, 0, stream>>>(xt, lin_W + H*H,    h,  nullptr, nullptr,
                                        nullptr, nullptr, lin_b + H, 1, N_NODES);

  k_out_init<<<(NG + 255)/256, 256, 0, stream>>>(out, wp_b);
  k_readout <<<(N_NODES + 3)/4, 256, 0, stream>>>(h, batch, wp_W, out);
}

// Round 3
// 797.255 us; speedup vs baseline: 1.1163x; 1.0685x over previous
//
#include <hip/hip_runtime.h>
#include <math.h>

#define N_NODES 100000
#define N_EDGES 400000
#define NG 2048
#define H 128
#define NLAYERS 3
#define SLOPE 0.2f

__device__ __forceinline__ float wave_reduce_sum(float v){
  #pragma unroll
  for (int off = 32; off > 0; off >>= 1) v += __shfl_xor(v, off, 64);
  return v;
}

// ---- preprocessing ----------------------------------------------------------

// scal[0] = sum(edge_attr)
__global__ void k_ea_sum(const float* __restrict__ ea, float* __restrict__ scal){
  int i = blockIdx.x * blockDim.x + threadIdx.x;
  int stride = gridDim.x * blockDim.x;
  float v = 0.f;
  for (; i < N_EDGES; i += stride) v += ea[i];
  v = wave_reduce_sum(v);
  if ((threadIdx.x & 63) == 0) atomicAdd(&scal[0], v);
}

// scal[1+l] = dot(edge_W[l], att_edge[l]); one wave per layer
__global__ void k_dots(const float* __restrict__ ew, const float* __restrict__ ae,
                       float* __restrict__ scal){
  int l = blockIdx.x;
  int lane = threadIdx.x;  // blockDim = 64
  float p = ew[l*H + lane]*ae[l*H + lane] + ew[l*H + lane + 64]*ae[l*H + lane + 64];
  p = wave_reduce_sum(p);
  if (lane == 0) scal[1 + l] = p;
}

// h[n,:] = emb[x[n],:]
__global__ void k_embed(const int* __restrict__ x, const float* __restrict__ emb,
                        float* __restrict__ h){
  int i = blockIdx.x * blockDim.x + threadIdx.x;    // one float4 each
  if (i >= N_NODES * (H/4)) return;
  int n  = i >> 5;            // / (H/4)
  int c4 = (i & 31) << 2;
  int v = x[n];
  *(float4*)(h + (size_t)n*H + c4) = *(const float4*)(emb + (size_t)v*H + c4);
}

// degree count over E real edges + N self loops
__global__ void k_deg(const int* __restrict__ ei, int* __restrict__ deg){
  int i = blockIdx.x * blockDim.x + threadIdx.x;
  if (i >= N_EDGES + N_NODES) return;
  int d = (i < N_EDGES) ? ei[N_EDGES + i] : (i - N_EDGES);
  atomicAdd(&deg[d], 1);
}

// allocate disjoint CSR ranges. Block-level scan + ONE atomic per block
// (order across nodes is irrelevant -> no global scan needed).
__global__ __launch_bounds__(256) void k_alloc(
    const int* __restrict__ deg, int* __restrict__ row_ptr, int* __restrict__ counter){
  __shared__ int wsum[4];
  __shared__ int base;
  int n = blockIdx.x * 256 + threadIdx.x;
  int d = (n < N_NODES) ? deg[n] : 0;
  int lane = threadIdx.x & 63, wid = threadIdx.x >> 6;
  int v = d;                      // inclusive scan within wave
  #pragma unroll
  for (int off = 1; off < 64; off <<= 1){
    int u = __shfl_up(v, off, 64);
    if (lane >= off) v += u;
  }
  if (lane == 63) wsum[wid] = v;
  __syncthreads();
  if (threadIdx.x == 0){
    int t0 = wsum[0], t1 = wsum[1], t2 = wsum[2], t3 = wsum[3];
    base = atomicAdd(counter, t0 + t1 + t2 + t3);
    wsum[0] = 0; wsum[1] = t0; wsum[2] = t0 + t1; wsum[3] = t0 + t1 + t2;
  }
  __syncthreads();
  if (n < N_NODES) row_ptr[n] = base + wsum[wid] + (v - d);   // exclusive offset
}

__global__ void k_scatter(const int* __restrict__ ei, const float* __restrict__ ea,
                          const float* __restrict__ scal, const int* __restrict__ row_ptr,
                          int* __restrict__ cursor, int* __restrict__ csr_src,
                          int* __restrict__ csr_dst, float* __restrict__ csr_ea){
  int i = blockIdx.x * blockDim.x + threadIdx.x;
  if (i >= N_EDGES + N_NODES) return;
  int s, d; float v;
  if (i < N_EDGES){ s = ei[i]; d = ei[N_EDGES + i]; v = ea[i]; }
  else            { s = d = i - N_EDGES; v = scal[0] * (1.0f / N_EDGES); }  // ea_mean
  int pos = row_ptr[d] + atomicAdd(&cursor[d], 1);
  csr_src[pos] = s;
  csr_dst[pos] = d;
  csr_ea[pos]  = v;
}

// per-edge softmax numerator (unstabilized exp is exact: e^l/sum e^l; logits O(+-6))
__global__ void k_edgew(const float* __restrict__ a_s, const float* __restrict__ a_d,
                        const int* __restrict__ csr_src, const int* __restrict__ csr_dst,
                        const float* __restrict__ csr_ea, const float* __restrict__ scal,
                        int l, float* __restrict__ csr_w){
  int i = blockIdx.x * blockDim.x + threadIdx.x;
  if (i >= N_EDGES + N_NODES) return;
  float lg = a_s[csr_src[i]] + a_d[csr_dst[i]] + scal[1 + l]*csr_ea[i];
  lg = (lg > 0.f) ? lg : SLOPE*lg;
  csr_w[i] = __expf(lg);
}

// ---- GEMM: C[n,j] = sum_k A[n,k] W[k,j]  (+fused epilogues) -----------------
// mode 0: write C=xt, plus a_s[n]=xt[n]·att_src, a_d[n]=xt[n]·att_dst
// mode 1: C = relu(A@W + bias)
__global__ __launch_bounds__(256) void k_gemm(
    const float* __restrict__ A, const float* __restrict__ W,
    float* __restrict__ C,
    const float* __restrict__ attn_s, const float* __restrict__ attn_d,
    float* __restrict__ a_s_out, float* __restrict__ a_d_out,
    const float* __restrict__ bias, int mode, int nrows)
{
  __shared__ float hs[64 * 132];   // 64 rows x 128 cols, +4 pad
  int tid = threadIdx.x;
  int tx = tid & 15;               // col group: j0 = tx*8
  int ty = tid >> 4;               // row group: 4 rows each
  size_t block_n = (size_t)blockIdx.x * 64;

  #pragma unroll
  for (int it = 0; it < 8; ++it){
    int flat = (it*256 + tid) * 4;
    int r  = flat >> 7;
    int cc = flat & 127;
    size_t gr = block_n + r;
    float4 v = make_float4(0.f,0.f,0.f,0.f);
    if (gr < (size_t)nrows) v = *(const float4*)(A + gr*H + cc);
    *(float4*)(hs + r*132 + cc) = v;
  }
  __syncthreads();

  int j0 = tx * 8;
  float acc[4][8];
  #pragma unroll
  for (int m = 0; m < 4; ++m)
    #pragma unroll
    for (int i = 0; i < 8; ++i) acc[m][i] = 0.f;

  for (int k = 0; k < H; ++k){
    float4 w0 = *(const float4*)(W + k*H + j0);
    float4 w1 = *(const float4*)(W + k*H + j0 + 4);
    #pragma unroll
    for (int m = 0; m < 4; ++m){
      float a = hs[(ty*4 + m)*132 + k];
      acc[m][0] += a*w0.x; acc[m][1] += a*w0.y; acc[m][2] += a*w0.z; acc[m][3] += a*w0.w;
      acc[m][4] += a*w1.x; acc[m][5] += a*w1.y; acc[m][6] += a*w1.z; acc[m][7] += a*w1.w;
    }
  }

  if (mode == 0){
    float as8[8], ad8[8];
    #pragma unroll
    for (int i = 0; i < 8; ++i){ as8[i] = attn_s[j0+i]; ad8[i] = attn_d[j0+i]; }
    #pragma unroll
    for (int m = 0; m < 4; ++m){
      size_t gr = block_n + ty*4 + m;
      bool ok = gr < (size_t)nrows;
      if (ok){
        *(float4*)(C + gr*H + j0)     = make_float4(acc[m][0],acc[m][1],acc[m][2],acc[m][3]);
        *(float4*)(C + gr*H + j0 + 4) = make_float4(acc[m][4],acc[m][5],acc[m][6],acc[m][7]);
      }
      float ps = 0.f, pd = 0.f;
      #pragma unroll
      for (int i = 0; i < 8; ++i){ ps += acc[m][i]*as8[i]; pd += acc[m][i]*ad8[i]; }
      #pragma unroll
      for (int msk = 8; msk > 0; msk >>= 1){
        ps += __shfl_xor(ps, msk, 64);
        pd += __shfl_xor(pd, msk, 64);
      }
      if (ok && tx == 0){ a_s_out[gr] = ps; a_d_out[gr] = pd; }
    }
  } else {
    float b8[8];
    #pragma unroll
    for (int i = 0; i < 8; ++i) b8[i] = bias[j0+i];
    #pragma unroll
    for (int m = 0; m < 4; ++m){
      size_t gr = block_n + ty*4 + m;
      if (gr >= (size_t)nrows) continue;
      float r[8];
      #pragma unroll
      for (int i = 0; i < 8; ++i) r[i] = fmaxf(acc[m][i] + b8[i], 0.f);
      *(float4*)(C + gr*H + j0)     = make_float4(r[0],r[1],r[2],r[3]);
      *(float4*)(C + gr*H + j0 + 4) = make_float4(r[4],r[5],r[6],r[7]);
    }
  }
}

// ---- per-node aggregate + bias + L2 normalize -------------------------------
// Edge (src, w) pairs staged in LDS once per block; inner loop is pure
// "gather xt row, fma" with 4 independent gathers in flight.
__global__ __launch_bounds__(128) void k_aggregate(
    const float* __restrict__ xt, const int* __restrict__ csr_src,
    const float* __restrict__ csr_w, const int* __restrict__ row_ptr,
    const int* __restrict__ deg, const float* __restrict__ bias,
    float* __restrict__ hout)
{
  __shared__ int   ls[128];
  __shared__ float lw[128];
  __shared__ float red[2];
  int n = blockIdx.x;
  int tid = threadIdx.x;
  int beg = row_ptr[n];
  int d   = deg[n];

  float acc = 0.f, ss = 0.f;
  for (int base = 0; base < d; base += 128){
    int cnt = min(128, d - base);
    if (base) __syncthreads();
    if (tid < cnt){
      ls[tid] = csr_src[beg + base + tid];
      lw[tid] = csr_w[beg + base + tid];
    }
    __syncthreads();
    int j = 0;
    for (; j + 4 <= cnt; j += 4){
      int s0 = ls[j], s1 = ls[j+1], s2 = ls[j+2], s3 = ls[j+3];
      float w0 = lw[j], w1 = lw[j+1], w2 = lw[j+2], w3 = lw[j+3];
      float x0 = xt[(size_t)s0*H + tid];
      float x1 = xt[(size_t)s1*H + tid];
      float x2 = xt[(size_t)s2*H + tid];
      float x3 = xt[(size_t)s3*H + tid];
      ss  += (w0 + w1) + (w2 + w3);
      acc += w0*x0; acc += w1*x1; acc += w2*x2; acc += w3*x3;
    }
    for (; j < cnt; ++j){
      int s = ls[j]; float w = lw[j];
      ss  += w;
      acc += w * xt[(size_t)s*H + tid];
    }
  }

  acc = acc / ss + bias[tid];

  float sq = wave_reduce_sum(acc*acc);
  if ((tid & 63) == 0) red[tid >> 6] = sq;
  __syncthreads();
  float nrm = sqrtf(red[0] + red[1]);
  hout[(size_t)n*H + tid] = acc / fmaxf(nrm, 1e-12f);
}

// ---- readout ----------------------------------------------------------------
__global__ void k_out_init(float* __restrict__ out, const float* __restrict__ wp_b){
  int g = blockIdx.x * blockDim.x + threadIdx.x;
  if (g < NG) out[g] = wp_b[0];
}

// out[batch[n]] += h[n]·wp  (readout dot commutes with segment sum)
__global__ void k_readout(const float* __restrict__ h, const int* __restrict__ batch,
                          const float* __restrict__ wp, float* __restrict__ out){
  int node = blockIdx.x * 4 + (threadIdx.x >> 6);
  int lane = threadIdx.x & 63;
  if (node >= N_NODES) return;
  const float* hr = h + (size_t)node*H;
  float s = hr[lane]*wp[lane] + hr[lane + 64]*wp[lane + 64];
  s = wave_reduce_sum(s);
  if (lane == 0) atomicAdd(&out[batch[node]], s);
}

// ---- launch -----------------------------------------------------------------
extern "C" void kernel_launch(void* const* d_in, const int* in_sizes, int n_in,
                              void* d_out, int out_size, void* d_ws, size_t ws_size,
                              hipStream_t stream) {
  const int*   x          = (const int*)  d_in[0];
  const int*   edge_index = (const int*)  d_in[1];
  const float* edge_attr  = (const float*)d_in[2];
  const int*   batch      = (const int*)  d_in[3];
  const float* emb        = (const float*)d_in[4];
  const float* gat_W      = (const float*)d_in[5];
  const float* att_src    = (const float*)d_in[6];
  const float* att_dst    = (const float*)d_in[7];
  const float* edge_W     = (const float*)d_in[8];
  const float* att_edge   = (const float*)d_in[9];
  const float* gat_b      = (const float*)d_in[10];
  const float* lin_W      = (const float*)d_in[11];
  const float* lin_b      = (const float*)d_in[12];
  const float* wp_W       = (const float*)d_in[13];
  const float* wp_b       = (const float*)d_in[14];
  float* out = (float*)d_out;

  // workspace layout
  float* ws     = (float*)d_ws;
  float* h      = ws;                                   // N*H
  float* xt     = h + (size_t)N_NODES*H;                // N*H
  float* a_s    = xt + (size_t)N_NODES*H;               // N
  float* a_d    = a_s + N_NODES;                        // N
  float* csr_ea = a_d + N_NODES;                        // E+N
  float* csr_w  = csr_ea + (N_EDGES + N_NODES);         // E+N
  float* scal   = csr_w + (N_EDGES + N_NODES);          // 8: [0]=ea_sum,[1..3]=dotl,[4]=counter(int)
  int*   deg    = (int*)(scal + 8);                     // N   (zeroed)
  int*   cursor = deg + N_NODES;                        // N   (zeroed)
  int*   row_ptr= cursor + N_NODES;                     // N
  int*   csr_src= row_ptr + N_NODES;                    // E+N
  int*   csr_dst= csr_src + (N_EDGES + N_NODES);        // E+N

  // zero scal + deg + cursor (contiguous)
  hipMemsetAsync(scal, 0, (size_t)(8 + 2*N_NODES) * sizeof(float), stream);

  k_ea_sum<<<256, 256, 0, stream>>>(edge_attr, scal);
  k_dots  <<<NLAYERS, 64, 0, stream>>>(edge_W, att_edge, scal);
  k_embed <<<(N_NODES*(H/4) + 255)/256, 256, 0, stream>>>(x, emb, h);
  k_deg   <<<(N_EDGES + N_NODES + 255)/256, 256, 0, stream>>>(edge_index, deg);
  k_alloc <<<(N_NODES + 255)/256, 256, 0, stream>>>(deg, row_ptr, (int*)&scal[4]);
  k_scatter<<<(N_EDGES + N_NODES + 255)/256, 256, 0, stream>>>(
      edge_index, edge_attr, scal, row_ptr, cursor, csr_src, csr_dst, csr_ea);

  const int gemm_grid = (N_NODES + 63) / 64;
  const int edge_grid = (N_EDGES + N_NODES + 255) / 256;
  for (int l = 0; l < NLAYERS; ++l){
    k_gemm<<<gemm_grid, 256, 0, stream>>>(
        h, gat_W + (size_t)l*H*H, xt,
        att_src + l*H, att_dst + l*H, a_s, a_d,
        nullptr, 0, N_NODES);
    k_edgew<<<edge_grid, 256, 0, stream>>>(
        a_s, a_d, csr_src, csr_dst, csr_ea, scal, l, csr_w);
    k_aggregate<<<N_NODES, 128, 0, stream>>>(
        xt, csr_src, csr_w, row_ptr, deg, gat_b + l*H, h);
  }
  // dense layers: h -> xt -> h
  k_gemm<<<gemm_grid, 256, 0, stream>>>(h, lin_W,           xt, nullptr, nullptr,
                                        nullptr, nullptr, lin_b,     1, N_NODES);
  k_gemm<<<gemm_grid, 256, 0, stream>>>(xt, lin_W + H*H,    h,  nullptr, nullptr,
                                        nullptr, nullptr, lin_b + H, 1, N_NODES);

  k_out_init<<<(NG + 255)/256, 256, 0, stream>>>(out, wp_b);
  k_readout <<<(N_NODES + 3)/4, 256, 0, stream>>>(h, batch, wp_W, out);
}

// Round 4
// 665.832 us; speedup vs baseline: 1.3367x; 1.1974x over previous
//
#include <hip/hip_runtime.h>
#include <math.h>

#define N_NODES 100000
#define N_EDGES 400000
#define NG 2048
#define H 128
#define NLAYERS 3
#define SLOPE 0.2f

typedef __attribute__((ext_vector_type(8))) short bf16x8;
typedef __attribute__((ext_vector_type(4))) float f32x4;

__device__ __forceinline__ float wave_reduce_sum(float v){
  #pragma unroll
  for (int off = 32; off > 0; off >>= 1) v += __shfl_xor(v, off, 64);
  return v;
}
__device__ __forceinline__ unsigned short bfhi(float f){
  return (unsigned short)(__float_as_uint(f) >> 16);   // truncation; lo term compensates
}
__device__ __forceinline__ float bftof(unsigned short h){
  return __uint_as_float(((unsigned int)h) << 16);
}

// ---- preprocessing ----------------------------------------------------------

__global__ void k_ea_sum(const float* __restrict__ ea, float* __restrict__ scal){
  int i = blockIdx.x * blockDim.x + threadIdx.x;
  int stride = gridDim.x * blockDim.x;
  float v = 0.f;
  for (; i < N_EDGES; i += stride) v += ea[i];
  v = wave_reduce_sum(v);
  if ((threadIdx.x & 63) == 0) atomicAdd(&scal[0], v);
}

__global__ void k_dots(const float* __restrict__ ew, const float* __restrict__ ae,
                       float* __restrict__ scal){
  int l = blockIdx.x;
  int lane = threadIdx.x;  // blockDim = 64
  float p = ew[l*H + lane]*ae[l*H + lane] + ew[l*H + lane + 64]*ae[l*H + lane + 64];
  p = wave_reduce_sum(p);
  if (lane == 0) scal[1 + l] = p;
}

// split W into bf16 hi/lo, transposed: Wt[n][k]. 5 matrices (3 gat + 2 lin).
// layout per matrix m: hi at m*32768, lo at m*32768 + 16384 (ushort units)
__global__ void k_convW(const float* __restrict__ gat_W, const float* __restrict__ lin_W,
                        unsigned short* __restrict__ Wt){
  int i = blockIdx.x * 256 + threadIdx.x;
  if (i >= 5*16384) return;
  int m = i >> 14, r = i & 16383;
  int n = r >> 7, k = r & 127;
  const float* src = (m < 3) ? (gat_W + m*16384) : (lin_W + (m-3)*16384);
  float w = src[k*H + n];
  unsigned short hi = bfhi(w);
  unsigned short lo = bfhi(w - bftof(hi));
  Wt[m*32768 + n*H + k]         = hi;
  Wt[m*32768 + 16384 + n*H + k] = lo;
}

__global__ void k_deg(const int* __restrict__ ei, int* __restrict__ deg){
  int i = blockIdx.x * blockDim.x + threadIdx.x;
  if (i >= N_EDGES + N_NODES) return;
  int d = (i < N_EDGES) ? ei[N_EDGES + i] : (i - N_EDGES);
  atomicAdd(&deg[d], 1);
}

// block scan + one atomic per block (CSR range order across nodes irrelevant)
__global__ __launch_bounds__(256) void k_alloc(
    const int* __restrict__ deg, int* __restrict__ row_ptr, int* __restrict__ counter){
  __shared__ int wsum[4];
  __shared__ int base;
  int n = blockIdx.x * 256 + threadIdx.x;
  int d = (n < N_NODES) ? deg[n] : 0;
  int lane = threadIdx.x & 63, wid = threadIdx.x >> 6;
  int v = d;
  #pragma unroll
  for (int off = 1; off < 64; off <<= 1){
    int u = __shfl_up(v, off, 64);
    if (lane >= off) v += u;
  }
  if (lane == 63) wsum[wid] = v;
  __syncthreads();
  if (threadIdx.x == 0){
    int t0 = wsum[0], t1 = wsum[1], t2 = wsum[2], t3 = wsum[3];
    base = atomicAdd(counter, t0 + t1 + t2 + t3);
    wsum[0] = 0; wsum[1] = t0; wsum[2] = t0 + t1; wsum[3] = t0 + t1 + t2;
  }
  __syncthreads();
  if (n < N_NODES) row_ptr[n] = base + wsum[wid] + (v - d);
}

__global__ void k_scatter(const int* __restrict__ ei, const float* __restrict__ ea,
                          const float* __restrict__ scal, const int* __restrict__ row_ptr,
                          int* __restrict__ cursor, int* __restrict__ csr_src,
                          float* __restrict__ csr_ea){
  int i = blockIdx.x * blockDim.x + threadIdx.x;
  if (i >= N_EDGES + N_NODES) return;
  int s, d; float v;
  if (i < N_EDGES){ s = ei[i]; d = ei[N_EDGES + i]; v = ea[i]; }
  else            { s = d = i - N_EDGES; v = scal[0] * (1.0f / N_EDGES); }  // ea_mean
  int pos = row_ptr[d] + atomicAdd(&cursor[d], 1);
  csr_src[pos] = s;
  csr_ea[pos]  = v;
}

// ---- MFMA GEMM: C[n,j] = A[n,:] @ W  via split-bf16 (hi/lo), no LDS ---------
// mode 0: store C=xt, a_s[n]=C·att1, a_d[n]=C·att2
// mode 1: store C = relu(C + bias)
// mode 2: relu(C + bias) dotted with att1(=wp), atomicAdd into out[batch[row]]
__global__ __launch_bounds__(256) void k_gemm(
    const float* __restrict__ A, const int* __restrict__ xmap,
    const unsigned short* __restrict__ Wt,      // hi; lo at +16384
    float* __restrict__ C,
    const float* __restrict__ att1, const float* __restrict__ att2,
    float* __restrict__ a_s_out, float* __restrict__ a_d_out,
    const float* __restrict__ bias,
    const int* __restrict__ batch, float* __restrict__ out,
    int mode)
{
  int tid  = threadIdx.x;
  int w    = tid >> 6;
  int lane = tid & 63;
  int q    = lane >> 4;
  int ln   = lane & 15;
  int baseRow = blockIdx.x*64 + w*16;

  // A row this lane loads for a-fragments (m = ln)
  int arow = baseRow + ln;
  if (arow >= N_NODES) arow = N_NODES - 1;
  if (xmap) arow = xmap[arow];
  const float* Arow = A + (size_t)arow*H;

  f32x4 acc[8];
  #pragma unroll
  for (int ct = 0; ct < 8; ++ct) acc[ct] = (f32x4){0.f,0.f,0.f,0.f};

  #pragma unroll
  for (int k0 = 0; k0 < H; k0 += 32){
    float4 f0 = *(const float4*)(Arow + k0 + q*8);
    float4 f1 = *(const float4*)(Arow + k0 + q*8 + 4);
    float fa[8] = {f0.x,f0.y,f0.z,f0.w,f1.x,f1.y,f1.z,f1.w};
    bf16x8 ahi, alo;
    #pragma unroll
    for (int j = 0; j < 8; ++j){
      unsigned int u = __float_as_uint(fa[j]);
      unsigned short h = (unsigned short)(u >> 16);
      float r = fa[j] - __uint_as_float(u & 0xFFFF0000u);
      ahi[j] = (short)h;
      alo[j] = (short)(__float_as_uint(r) >> 16);
    }
    #pragma unroll
    for (int ct = 0; ct < 8; ++ct){
      const unsigned short* bp = Wt + (ct*16 + ln)*H + k0 + q*8;
      bf16x8 bhi = *(const bf16x8*)bp;
      bf16x8 blo = *(const bf16x8*)(bp + 16384);
      acc[ct] = __builtin_amdgcn_mfma_f32_16x16x32_bf16(alo, bhi, acc[ct], 0,0,0);
      acc[ct] = __builtin_amdgcn_mfma_f32_16x16x32_bf16(ahi, blo, acc[ct], 0,0,0);
      acc[ct] = __builtin_amdgcn_mfma_f32_16x16x32_bf16(ahi, bhi, acc[ct], 0,0,0);
    }
  }

  // C/D layout: col = ct*16 + ln, row = baseRow + q*4 + r
  if (mode == 0){
    float as_l[8], ad_l[8];
    #pragma unroll
    for (int ct = 0; ct < 8; ++ct){ as_l[ct] = att1[ct*16+ln]; ad_l[ct] = att2[ct*16+ln]; }
    #pragma unroll
    for (int r = 0; r < 4; ++r){
      int grow = baseRow + q*4 + r;
      bool ok = grow < N_NODES;
      float ps = 0.f, pd = 0.f;
      #pragma unroll
      for (int ct = 0; ct < 8; ++ct){
        float v = acc[ct][r];
        if (ok) C[(size_t)grow*H + ct*16 + ln] = v;
        ps += v * as_l[ct]; pd += v * ad_l[ct];
      }
      #pragma unroll
      for (int m = 8; m > 0; m >>= 1){
        ps += __shfl_xor(ps, m, 64);
        pd += __shfl_xor(pd, m, 64);
      }
      if (ok && ln == 0){ a_s_out[grow] = ps; a_d_out[grow] = pd; }
    }
  } else if (mode == 1){
    float b_l[8];
    #pragma unroll
    for (int ct = 0; ct < 8; ++ct) b_l[ct] = bias[ct*16+ln];
    #pragma unroll
    for (int r = 0; r < 4; ++r){
      int grow = baseRow + q*4 + r;
      if (grow >= N_NODES) continue;
      #pragma unroll
      for (int ct = 0; ct < 8; ++ct)
        C[(size_t)grow*H + ct*16 + ln] = fmaxf(acc[ct][r] + b_l[ct], 0.f);
    }
  } else {
    float b_l[8], wp_l[8];
    #pragma unroll
    for (int ct = 0; ct < 8; ++ct){ b_l[ct] = bias[ct*16+ln]; wp_l[ct] = att1[ct*16+ln]; }
    #pragma unroll
    for (int r = 0; r < 4; ++r){
      int grow = baseRow + q*4 + r;
      bool ok = grow < N_NODES;
      float ps = 0.f;
      #pragma unroll
      for (int ct = 0; ct < 8; ++ct)
        ps += fmaxf(acc[ct][r] + b_l[ct], 0.f) * wp_l[ct];
      #pragma unroll
      for (int m = 8; m > 0; m >>= 1) ps += __shfl_xor(ps, m, 64);
      if (ok && ln == 0) atomicAdd(&out[batch[grow]], ps);
    }
  }
}

// ---- aggregate: one wave per node, scalar edge metadata, float2 gathers -----
__global__ __launch_bounds__(256) void k_aggregate(
    const float* __restrict__ xt, const float* __restrict__ a_s,
    const float* __restrict__ a_d, const int* __restrict__ csr_src,
    const float* __restrict__ csr_ea, const int* __restrict__ row_ptr,
    const int* __restrict__ deg, const float* __restrict__ scal, int l,
    const float* __restrict__ bias, float* __restrict__ hout)
{
  int n = __builtin_amdgcn_readfirstlane(blockIdx.x*4 + (threadIdx.x >> 6));
  if (n >= N_NODES) return;
  int lane = threadIdx.x & 63;
  int beg = row_ptr[n];
  int d   = deg[n];              // >= 1 (self loop)
  float adn = a_d[n];
  float dl  = scal[1 + l];

  float2 acc = make_float2(0.f, 0.f);
  float ss = 0.f;
  for (int j0 = 0; j0 < d; j0 += 4){
    int si[4]; float eai[4]; bool okk[4];
    #pragma unroll
    for (int u = 0; u < 4; ++u){
      int jj = j0 + u;
      okk[u] = jj < d;
      int e = beg + (okk[u] ? jj : d - 1);
      si[u]  = csr_src[e];
      eai[u] = csr_ea[e];
    }
    float asv[4]; float2 xv[4];
    #pragma unroll
    for (int u = 0; u < 4; ++u){
      asv[u] = a_s[si[u]];
      xv[u]  = *(const float2*)(xt + (size_t)si[u]*H + lane*2);
    }
    #pragma unroll
    for (int u = 0; u < 4; ++u){
      float lg = asv[u] + adn + dl*eai[u];
      lg = (lg > 0.f) ? lg : SLOPE*lg;
      float wgt = okk[u] ? __expf(lg) : 0.f;   // unstabilized exp is exact math; logits O(+-6)
      ss += wgt;
      acc.x += wgt * xv[u].x;
      acc.y += wgt * xv[u].y;
    }
  }

  float2 bv = *(const float2*)(bias + lane*2);
  acc.x = acc.x/ss + bv.x;
  acc.y = acc.y/ss + bv.y;
  float sq = wave_reduce_sum(acc.x*acc.x + acc.y*acc.y);
  float nrm = fmaxf(sqrtf(sq), 1e-12f);
  float2 o = make_float2(acc.x/nrm, acc.y/nrm);
  *(float2*)(hout + (size_t)n*H + lane*2) = o;
}

// ---- readout init -----------------------------------------------------------
__global__ void k_out_init(float* __restrict__ out, const float* __restrict__ wp_b){
  int g = blockIdx.x * blockDim.x + threadIdx.x;
  if (g < NG) out[g] = wp_b[0];
}

// ---- launch -----------------------------------------------------------------
extern "C" void kernel_launch(void* const* d_in, const int* in_sizes, int n_in,
                              void* d_out, int out_size, void* d_ws, size_t ws_size,
                              hipStream_t stream) {
  const int*   x          = (const int*)  d_in[0];
  const int*   edge_index = (const int*)  d_in[1];
  const float* edge_attr  = (const float*)d_in[2];
  const int*   batch      = (const int*)  d_in[3];
  const float* emb        = (const float*)d_in[4];
  const float* gat_W      = (const float*)d_in[5];
  const float* att_src    = (const float*)d_in[6];
  const float* att_dst    = (const float*)d_in[7];
  const float* edge_W     = (const float*)d_in[8];
  const float* att_edge   = (const float*)d_in[9];
  const float* gat_b      = (const float*)d_in[10];
  const float* lin_W      = (const float*)d_in[11];
  const float* lin_b      = (const float*)d_in[12];
  const float* wp_W       = (const float*)d_in[13];
  const float* wp_b       = (const float*)d_in[14];
  float* out = (float*)d_out;

  // workspace layout
  float* ws     = (float*)d_ws;
  float* h      = ws;                                   // N*H
  float* xt     = h + (size_t)N_NODES*H;                // N*H
  float* a_s    = xt + (size_t)N_NODES*H;               // N
  float* a_d    = a_s + N_NODES;                        // N
  float* csr_ea = a_d + N_NODES;                        // E+N
  float* scal   = csr_ea + (N_EDGES + N_NODES);         // 8: [0]=ea_sum,[1..3]=dot_l,[4]=counter
  int*   deg    = (int*)(scal + 8);                     // N (zeroed)
  int*   cursor = deg + N_NODES;                        // N (zeroed)
  int*   row_ptr= cursor + N_NODES;                     // N
  int*   csr_src= row_ptr + N_NODES;                    // E+N
  unsigned short* Wt = (unsigned short*)(csr_src + (N_EDGES + N_NODES));  // 5*32768 ushorts

  hipMemsetAsync(scal, 0, (size_t)(8 + 2*N_NODES) * sizeof(float), stream);

  k_ea_sum<<<256, 256, 0, stream>>>(edge_attr, scal);
  k_dots  <<<NLAYERS, 64, 0, stream>>>(edge_W, att_edge, scal);
  k_convW <<<(5*16384 + 255)/256, 256, 0, stream>>>(gat_W, lin_W, Wt);
  k_deg   <<<(N_EDGES + N_NODES + 255)/256, 256, 0, stream>>>(edge_index, deg);
  k_alloc <<<(N_NODES + 255)/256, 256, 0, stream>>>(deg, row_ptr, (int*)&scal[4]);
  k_scatter<<<(N_EDGES + N_NODES + 255)/256, 256, 0, stream>>>(
      edge_index, edge_attr, scal, row_ptr, cursor, csr_src, csr_ea);
  k_out_init<<<(NG + 255)/256, 256, 0, stream>>>(out, wp_b);

  const int gemm_grid = (N_NODES + 63) / 64;
  for (int l = 0; l < NLAYERS; ++l){
    k_gemm<<<gemm_grid, 256, 0, stream>>>(
        (l == 0) ? emb : h, (l == 0) ? x : nullptr,
        Wt + (size_t)l*32768, xt,
        att_src + l*H, att_dst + l*H, a_s, a_d,
        nullptr, nullptr, nullptr, 0);
    k_aggregate<<<N_NODES/4, 256, 0, stream>>>(
        xt, a_s, a_d, csr_src, csr_ea, row_ptr, deg, scal, l,
        gat_b + l*H, h);
  }
  // dense 1: h -> xt (relu+bias)
  k_gemm<<<gemm_grid, 256, 0, stream>>>(
      h, nullptr, Wt + (size_t)3*32768, xt,
      nullptr, nullptr, nullptr, nullptr, lin_b, nullptr, nullptr, 1);
  // dense 2 + fused readout: relu(xt@W+b)·wp -> atomicAdd out[batch]
  k_gemm<<<gemm_grid, 256, 0, stream>>>(
      xt, nullptr, Wt + (size_t)4*32768, nullptr,
      wp_W, nullptr, nullptr, nullptr, lin_b + H, batch, out, 2);
}

// Round 5
// 473.523 us; speedup vs baseline: 1.8795x; 1.4061x over previous
//
#include <hip/hip_runtime.h>
#include <math.h>

#define N_NODES 100000
#define N_EDGES 400000
#define NG 2048
#define H 128
#define NLAYERS 3
#define SLOPE 0.2f

typedef __attribute__((ext_vector_type(8))) short bf16x8;
typedef __attribute__((ext_vector_type(4))) float f32x4;

__device__ __forceinline__ float wave_reduce_sum(float v){
  #pragma unroll
  for (int off = 32; off > 0; off >>= 1) v += __shfl_xor(v, off, 64);
  return v;
}
__device__ __forceinline__ unsigned short bfhi(float f){
  return (unsigned short)(__float_as_uint(f) >> 16);   // truncation; lo term compensates
}
__device__ __forceinline__ float bftof(unsigned short h){
  return __uint_as_float(((unsigned int)h) << 16);
}

// ---- preprocessing ----------------------------------------------------------

__global__ void k_ea_sum(const float* __restrict__ ea, float* __restrict__ scal){
  int i = blockIdx.x * blockDim.x + threadIdx.x;
  int stride = gridDim.x * blockDim.x;
  float v = 0.f;
  for (; i < N_EDGES; i += stride) v += ea[i];
  v = wave_reduce_sum(v);
  if ((threadIdx.x & 63) == 0) atomicAdd(&scal[0], v);
}

__global__ void k_dots(const float* __restrict__ ew, const float* __restrict__ ae,
                       float* __restrict__ scal){
  int l = blockIdx.x;
  int lane = threadIdx.x;  // blockDim = 64
  float p = ew[l*H + lane]*ae[l*H + lane] + ew[l*H + lane + 64]*ae[l*H + lane + 64];
  p = wave_reduce_sum(p);
  if (lane == 0) scal[1 + l] = p;
}

// W -> bf16 hi/lo in MFMA B-fragment order.
// Per matrix m (32768 ushorts = 64 KB): index
//   [plane p(2)][k0i(4)][ct(8)][lane(64)][j(8)]
// value = plane_p( W[k][n] ), k = k0i*32 + (lane>>4)*8 + j, n = ct*16 + (lane&15)
__global__ void k_convW(const float* __restrict__ gat_W, const float* __restrict__ lin_W,
                        unsigned short* __restrict__ Wf){
  int i = blockIdx.x * 256 + threadIdx.x;
  if (i >= 5*32768) return;
  int m   = i >> 15;
  int r   = i & 32767;
  int p   = r >> 14;
  int r2  = r & 16383;
  int k0i = r2 >> 12;
  int r3  = r2 & 4095;
  int ct  = r3 >> 9;
  int r4  = r3 & 511;
  int lane= r4 >> 3;
  int j   = r4 & 7;
  int q = lane >> 4, ln = lane & 15;
  int k = k0i*32 + q*8 + j;
  int n = ct*16 + ln;
  const float* src = (m < 3) ? (gat_W + m*16384) : (lin_W + (m-3)*16384);
  float w = src[k*H + n];
  unsigned short hi = bfhi(w);
  Wf[i] = (p == 0) ? hi : bfhi(w - bftof(hi));
}

__global__ void k_deg(const int* __restrict__ ei, int* __restrict__ deg){
  int i = blockIdx.x * blockDim.x + threadIdx.x;
  if (i >= N_EDGES + N_NODES) return;
  int d = (i < N_EDGES) ? ei[N_EDGES + i] : (i - N_EDGES);
  atomicAdd(&deg[d], 1);
}

// block scan + one atomic per block (CSR range order across nodes irrelevant)
__global__ __launch_bounds__(256) void k_alloc(
    const int* __restrict__ deg, int* __restrict__ row_ptr, int* __restrict__ counter){
  __shared__ int wsum[4];
  __shared__ int base;
  int n = blockIdx.x * 256 + threadIdx.x;
  int d = (n < N_NODES) ? deg[n] : 0;
  int lane = threadIdx.x & 63, wid = threadIdx.x >> 6;
  int v = d;
  #pragma unroll
  for (int off = 1; off < 64; off <<= 1){
    int u = __shfl_up(v, off, 64);
    if (lane >= off) v += u;
  }
  if (lane == 63) wsum[wid] = v;
  __syncthreads();
  if (threadIdx.x == 0){
    int t0 = wsum[0], t1 = wsum[1], t2 = wsum[2], t3 = wsum[3];
    base = atomicAdd(counter, t0 + t1 + t2 + t3);
    wsum[0] = 0; wsum[1] = t0; wsum[2] = t0 + t1; wsum[3] = t0 + t1 + t2;
  }
  __syncthreads();
  if (n < N_NODES) row_ptr[n] = base + wsum[wid] + (v - d);
}

__global__ void k_scatter(const int* __restrict__ ei, const float* __restrict__ ea,
                          const float* __restrict__ scal, const int* __restrict__ row_ptr,
                          int* __restrict__ cursor, int* __restrict__ csr_src,
                          float* __restrict__ csr_ea){
  int i = blockIdx.x * blockDim.x + threadIdx.x;
  if (i >= N_EDGES + N_NODES) return;
  int s, d; float v;
  if (i < N_EDGES){ s = ei[i]; d = ei[N_EDGES + i]; v = ea[i]; }
  else            { s = d = i - N_EDGES; v = scal[0] * (1.0f / N_EDGES); }  // ea_mean
  int pos = row_ptr[d] + atomicAdd(&cursor[d], 1);
  csr_src[pos] = s;
  csr_ea[pos]  = v;
}

// ---- MFMA GEMM, split-bf16 (3-term), W staged in LDS, A prefetched ----------
// Block = 256 thr = 4 waves; block tile 128 rows; wave tile 32 rows (2 m-tiles).
// mode 0: C=xt, a_s=C·att1, a_d=C·att2;  mode 1: C=relu(C+bias);
// mode 2: relu(C+bias)·att1 -> atomicAdd out[batch[row]]
__global__ __launch_bounds__(256) void k_gemm(
    const float* __restrict__ A, const int* __restrict__ xmap,
    const unsigned short* __restrict__ Wf,      // fragment-ordered, 32768 ushorts
    float* __restrict__ C,
    const float* __restrict__ att1, const float* __restrict__ att2,
    float* __restrict__ a_s_out, float* __restrict__ a_d_out,
    const float* __restrict__ bias,
    const int* __restrict__ batch, float* __restrict__ out,
    int mode)
{
  __shared__ unsigned short lw[32768];   // exactly 64 KB: hi plane then lo plane
  int tid  = threadIdx.x;
  int w    = tid >> 6;
  int lane = tid & 63;
  int q    = lane >> 4;
  int ln   = lane & 15;
  int waveRow = blockIdx.x*128 + w*32;

  // stage W fragments (coalesced 16B/thread x 16 iters)
  #pragma unroll
  for (int i = 0; i < 16; ++i){
    int idx = (i*256 + tid) * 8;         // ushort index
    *(bf16x8*)(lw + idx) = *(const bf16x8*)(Wf + idx);
  }

  // prefetch A fragments for both m-tiles, all 4 k0 (registers)
  float4 araw[2][8];
  #pragma unroll
  for (int m = 0; m < 2; ++m){
    int r = waveRow + m*16 + ln;
    if (r >= N_NODES) r = N_NODES - 1;
    if (xmap) r = xmap[r];
    const float* Arow = A + (size_t)r*H;
    #pragma unroll
    for (int k0i = 0; k0i < 4; ++k0i){
      araw[m][k0i*2]   = *(const float4*)(Arow + k0i*32 + q*8);
      araw[m][k0i*2+1] = *(const float4*)(Arow + k0i*32 + q*8 + 4);
    }
  }
  __syncthreads();   // W staged (also drains A loads)

  f32x4 acc[2][8];
  #pragma unroll
  for (int m = 0; m < 2; ++m)
    #pragma unroll
    for (int ct = 0; ct < 8; ++ct) acc[m][ct] = (f32x4){0.f,0.f,0.f,0.f};

  #pragma unroll
  for (int k0i = 0; k0i < 4; ++k0i){
    bf16x8 ahi[2], alo[2];
    #pragma unroll
    for (int m = 0; m < 2; ++m){
      float fa[8] = {araw[m][k0i*2].x,   araw[m][k0i*2].y,
                     araw[m][k0i*2].z,   araw[m][k0i*2].w,
                     araw[m][k0i*2+1].x, araw[m][k0i*2+1].y,
                     araw[m][k0i*2+1].z, araw[m][k0i*2+1].w};
      #pragma unroll
      for (int j = 0; j < 8; ++j){
        unsigned int u = __float_as_uint(fa[j]);
        ahi[m][j] = (short)(u >> 16);
        float rr = fa[j] - __uint_as_float(u & 0xFFFF0000u);
        alo[m][j] = (short)(__float_as_uint(rr) >> 16);
      }
    }
    #pragma unroll
    for (int ct = 0; ct < 8; ++ct){
      bf16x8 bhi = *(const bf16x8*)(lw + (k0i*8 + ct)*512 + lane*8);
      bf16x8 blo = *(const bf16x8*)(lw + ((4 + k0i)*8 + ct)*512 + lane*8);
      #pragma unroll
      for (int m = 0; m < 2; ++m){
        acc[m][ct] = __builtin_amdgcn_mfma_f32_16x16x32_bf16(alo[m], bhi, acc[m][ct], 0,0,0);
        acc[m][ct] = __builtin_amdgcn_mfma_f32_16x16x32_bf16(ahi[m], blo, acc[m][ct], 0,0,0);
        acc[m][ct] = __builtin_amdgcn_mfma_f32_16x16x32_bf16(ahi[m], bhi, acc[m][ct], 0,0,0);
      }
    }
  }

  // C/D layout: col = ct*16 + ln, row = (m-tile base) + q*4 + r
  if (mode == 0){
    float as_l[8], ad_l[8];
    #pragma unroll
    for (int ct = 0; ct < 8; ++ct){ as_l[ct] = att1[ct*16+ln]; ad_l[ct] = att2[ct*16+ln]; }
    #pragma unroll
    for (int m = 0; m < 2; ++m){
      #pragma unroll
      for (int r = 0; r < 4; ++r){
        int grow = waveRow + m*16 + q*4 + r;
        bool ok = grow < N_NODES;
        float ps = 0.f, pd = 0.f;
        #pragma unroll
        for (int ct = 0; ct < 8; ++ct){
          float v = acc[m][ct][r];
          if (ok) C[(size_t)grow*H + ct*16 + ln] = v;
          ps += v * as_l[ct]; pd += v * ad_l[ct];
        }
        #pragma unroll
        for (int mk = 8; mk > 0; mk >>= 1){
          ps += __shfl_xor(ps, mk, 64);
          pd += __shfl_xor(pd, mk, 64);
        }
        if (ok && ln == 0){ a_s_out[grow] = ps; a_d_out[grow] = pd; }
      }
    }
  } else if (mode == 1){
    float b_l[8];
    #pragma unroll
    for (int ct = 0; ct < 8; ++ct) b_l[ct] = bias[ct*16+ln];
    #pragma unroll
    for (int m = 0; m < 2; ++m){
      #pragma unroll
      for (int r = 0; r < 4; ++r){
        int grow = waveRow + m*16 + q*4 + r;
        if (grow >= N_NODES) continue;
        #pragma unroll
        for (int ct = 0; ct < 8; ++ct)
          C[(size_t)grow*H + ct*16 + ln] = fmaxf(acc[m][ct][r] + b_l[ct], 0.f);
      }
    }
  } else {
    float b_l[8], wp_l[8];
    #pragma unroll
    for (int ct = 0; ct < 8; ++ct){ b_l[ct] = bias[ct*16+ln]; wp_l[ct] = att1[ct*16+ln]; }
    #pragma unroll
    for (int m = 0; m < 2; ++m){
      #pragma unroll
      for (int r = 0; r < 4; ++r){
        int grow = waveRow + m*16 + q*4 + r;
        bool ok = grow < N_NODES;
        float ps = 0.f;
        #pragma unroll
        for (int ct = 0; ct < 8; ++ct)
          ps += fmaxf(acc[m][ct][r] + b_l[ct], 0.f) * wp_l[ct];
        #pragma unroll
        for (int mk = 8; mk > 0; mk >>= 1) ps += __shfl_xor(ps, mk, 64);
        if (ok && ln == 0) atomicAdd(&out[batch[grow]], ps);
      }
    }
  }
}

// ---- aggregate: one wave per node, scalar edge metadata, float2 gathers -----
__global__ __launch_bounds__(256) void k_aggregate(
    const float* __restrict__ xt, const float* __restrict__ a_s,
    const float* __restrict__ a_d, const int* __restrict__ csr_src,
    const float* __restrict__ csr_ea, const int* __restrict__ row_ptr,
    const int* __restrict__ deg, const float* __restrict__ scal, int l,
    const float* __restrict__ bias, float* __restrict__ hout)
{
  int n = __builtin_amdgcn_readfirstlane(blockIdx.x*4 + (threadIdx.x >> 6));
  if (n >= N_NODES) return;
  int lane = threadIdx.x & 63;
  int beg = row_ptr[n];
  int d   = deg[n];              // >= 1 (self loop)
  float adn = a_d[n];
  float dl  = scal[1 + l];

  float2 acc = make_float2(0.f, 0.f);
  float ss = 0.f;
  for (int j0 = 0; j0 < d; j0 += 4){
    int si[4]; float eai[4]; bool okk[4];
    #pragma unroll
    for (int u = 0; u < 4; ++u){
      int jj = j0 + u;
      okk[u] = jj < d;
      int e = beg + (okk[u] ? jj : d - 1);
      si[u]  = csr_src[e];
      eai[u] = csr_ea[e];
    }
    float asv[4]; float2 xv[4];
    #pragma unroll
    for (int u = 0; u < 4; ++u){
      asv[u] = a_s[si[u]];
      xv[u]  = *(const float2*)(xt + (size_t)si[u]*H + lane*2);
    }
    #pragma unroll
    for (int u = 0; u < 4; ++u){
      float lg = asv[u] + adn + dl*eai[u];
      lg = (lg > 0.f) ? lg : SLOPE*lg;
      float wgt = okk[u] ? __expf(lg) : 0.f;   // unstabilized exp is exact math; logits O(+-6)
      ss += wgt;
      acc.x += wgt * xv[u].x;
      acc.y += wgt * xv[u].y;
    }
  }

  float2 bv = *(const float2*)(bias + lane*2);
  acc.x = acc.x/ss + bv.x;
  acc.y = acc.y/ss + bv.y;
  float sq = wave_reduce_sum(acc.x*acc.x + acc.y*acc.y);
  float nrm = fmaxf(sqrtf(sq), 1e-12f);
  float2 o = make_float2(acc.x/nrm, acc.y/nrm);
  *(float2*)(hout + (size_t)n*H + lane*2) = o;
}

// ---- readout init -----------------------------------------------------------
__global__ void k_out_init(float* __restrict__ out, const float* __restrict__ wp_b){
  int g = blockIdx.x * blockDim.x + threadIdx.x;
  if (g < NG) out[g] = wp_b[0];
}

// ---- launch -----------------------------------------------------------------
extern "C" void kernel_launch(void* const* d_in, const int* in_sizes, int n_in,
                              void* d_out, int out_size, void* d_ws, size_t ws_size,
                              hipStream_t stream) {
  const int*   x          = (const int*)  d_in[0];
  const int*   edge_index = (const int*)  d_in[1];
  const float* edge_attr  = (const float*)d_in[2];
  const int*   batch      = (const int*)  d_in[3];
  const float* emb        = (const float*)d_in[4];
  const float* gat_W      = (const float*)d_in[5];
  const float* att_src    = (const float*)d_in[6];
  const float* att_dst    = (const float*)d_in[7];
  const float* edge_W     = (const float*)d_in[8];
  const float* att_edge   = (const float*)d_in[9];
  const float* gat_b      = (const float*)d_in[10];
  const float* lin_W      = (const float*)d_in[11];
  const float* lin_b      = (const float*)d_in[12];
  const float* wp_W       = (const float*)d_in[13];
  const float* wp_b       = (const float*)d_in[14];
  float* out = (float*)d_out;

  // workspace layout
  float* ws     = (float*)d_ws;
  float* h      = ws;                                   // N*H
  float* xt     = h + (size_t)N_NODES*H;                // N*H
  float* a_s    = xt + (size_t)N_NODES*H;               // N
  float* a_d    = a_s + N_NODES;                        // N
  float* csr_ea = a_d + N_NODES;                        // E+N
  float* scal   = csr_ea + (N_EDGES + N_NODES);         // 8: [0]=ea_sum,[1..3]=dot_l,[4]=counter
  int*   deg    = (int*)(scal + 8);                     // N (zeroed)
  int*   cursor = deg + N_NODES;                        // N (zeroed)
  int*   row_ptr= cursor + N_NODES;                     // N
  int*   csr_src= row_ptr + N_NODES;                    // E+N
  unsigned short* Wt = (unsigned short*)(csr_src + (N_EDGES + N_NODES));  // 5*32768 ushorts

  hipMemsetAsync(scal, 0, (size_t)(8 + 2*N_NODES) * sizeof(float), stream);

  k_ea_sum<<<256, 256, 0, stream>>>(edge_attr, scal);
  k_dots  <<<NLAYERS, 64, 0, stream>>>(edge_W, att_edge, scal);
  k_convW <<<(5*32768 + 255)/256, 256, 0, stream>>>(gat_W, lin_W, Wt);
  k_deg   <<<(N_EDGES + N_NODES + 255)/256, 256, 0, stream>>>(edge_index, deg);
  k_alloc <<<(N_NODES + 255)/256, 256, 0, stream>>>(deg, row_ptr, (int*)&scal[4]);
  k_scatter<<<(N_EDGES + N_NODES + 255)/256, 256, 0, stream>>>(
      edge_index, edge_attr, scal, row_ptr, cursor, csr_src, csr_ea);
  k_out_init<<<(NG + 255)/256, 256, 0, stream>>>(out, wp_b);

  const int gemm_grid = (N_NODES + 127) / 128;
  for (int l = 0; l < NLAYERS; ++l){
    k_gemm<<<gemm_grid, 256, 0, stream>>>(
        (l == 0) ? emb : h, (l == 0) ? x : nullptr,
        Wt + (size_t)l*32768, xt,
        att_src + l*H, att_dst + l*H, a_s, a_d,
        nullptr, nullptr, nullptr, 0);
    k_aggregate<<<N_NODES/4, 256, 0, stream>>>(
        xt, a_s, a_d, csr_src, csr_ea, row_ptr, deg, scal, l,
        gat_b + l*H, h);
  }
  // dense 1: h -> xt (relu+bias)
  k_gemm<<<gemm_grid, 256, 0, stream>>>(
      h, nullptr, Wt + (size_t)3*32768, xt,
      nullptr, nullptr, nullptr, nullptr, lin_b, nullptr, nullptr, 1);
  // dense 2 + fused readout: relu(xt@W+b)·wp -> atomicAdd out[batch]
  k_gemm<<<gemm_grid, 256, 0, stream>>>(
      xt, nullptr, Wt + (size_t)4*32768, nullptr,
      wp_W, nullptr, nullptr, nullptr, lin_b + H, batch, out, 2);
}

// Round 6
// 460.471 us; speedup vs baseline: 1.9328x; 1.0283x over previous
//
#include <hip/hip_runtime.h>
#include <math.h>

#define N_NODES 100000
#define N_EDGES 400000
#define NG 2048
#define H 128
#define NLAYERS 3
#define SLOPE 0.2f

typedef __attribute__((ext_vector_type(8))) short bf16x8;
typedef __attribute__((ext_vector_type(4))) float f32x4;

__device__ __forceinline__ float wave_reduce_sum(float v){
  #pragma unroll
  for (int off = 32; off > 0; off >>= 1) v += __shfl_xor(v, off, 64);
  return v;
}
__device__ __forceinline__ unsigned short bfhi(float f){
  return (unsigned short)(__float_as_uint(f) >> 16);   // truncation; lo term compensates
}
__device__ __forceinline__ float bftof(unsigned short h){
  return __uint_as_float(((unsigned int)h) << 16);
}

// ---- preprocessing ----------------------------------------------------------

__global__ void k_ea_sum(const float* __restrict__ ea, float* __restrict__ scal){
  int i = blockIdx.x * blockDim.x + threadIdx.x;
  int stride = gridDim.x * blockDim.x;
  float v = 0.f;
  for (; i < N_EDGES; i += stride) v += ea[i];
  v = wave_reduce_sum(v);
  if ((threadIdx.x & 63) == 0) atomicAdd(&scal[0], v);
}

__global__ void k_dots(const float* __restrict__ ew, const float* __restrict__ ae,
                       float* __restrict__ scal){
  int l = blockIdx.x;
  int lane = threadIdx.x;  // blockDim = 64
  float p = ew[l*H + lane]*ae[l*H + lane] + ew[l*H + lane + 64]*ae[l*H + lane + 64];
  p = wave_reduce_sum(p);
  if (lane == 0) scal[1 + l] = p;
}

// W -> bf16 hi/lo in MFMA B-fragment order.
// Per matrix m (32768 ushorts = 64 KB): index
//   [plane p(2)][k0i(4)][ct(8)][lane(64)][j(8)]
// value = plane_p( W[k][n] ), k = k0i*32 + (lane>>4)*8 + j, n = ct*16 + (lane&15)
__global__ void k_convW(const float* __restrict__ gat_W, const float* __restrict__ lin_W,
                        unsigned short* __restrict__ Wf){
  int i = blockIdx.x * 256 + threadIdx.x;
  if (i >= 5*32768) return;
  int m   = i >> 15;
  int r   = i & 32767;
  int p   = r >> 14;
  int r2  = r & 16383;
  int k0i = r2 >> 12;
  int r3  = r2 & 4095;
  int ct  = r3 >> 9;
  int r4  = r3 & 511;
  int lane= r4 >> 3;
  int j   = r4 & 7;
  int q = lane >> 4, ln = lane & 15;
  int k = k0i*32 + q*8 + j;
  int n = ct*16 + ln;
  const float* src = (m < 3) ? (gat_W + m*16384) : (lin_W + (m-3)*16384);
  float w = src[k*H + n];
  unsigned short hi = bfhi(w);
  Wf[i] = (p == 0) ? hi : bfhi(w - bftof(hi));
}

__global__ void k_deg(const int* __restrict__ ei, int* __restrict__ deg){
  int i = blockIdx.x * blockDim.x + threadIdx.x;
  if (i >= N_EDGES + N_NODES) return;
  int d = (i < N_EDGES) ? ei[N_EDGES + i] : (i - N_EDGES);
  atomicAdd(&deg[d], 1);
}

// block scan + one atomic per block (CSR range order across nodes irrelevant)
__global__ __launch_bounds__(256) void k_alloc(
    const int* __restrict__ deg, int* __restrict__ row_ptr, int* __restrict__ counter){
  __shared__ int wsum[4];
  __shared__ int base;
  int n = blockIdx.x * 256 + threadIdx.x;
  int d = (n < N_NODES) ? deg[n] : 0;
  int lane = threadIdx.x & 63, wid = threadIdx.x >> 6;
  int v = d;
  #pragma unroll
  for (int off = 1; off < 64; off <<= 1){
    int u = __shfl_up(v, off, 64);
    if (lane >= off) v += u;
  }
  if (lane == 63) wsum[wid] = v;
  __syncthreads();
  if (threadIdx.x == 0){
    int t0 = wsum[0], t1 = wsum[1], t2 = wsum[2], t3 = wsum[3];
    base = atomicAdd(counter, t0 + t1 + t2 + t3);
    wsum[0] = 0; wsum[1] = t0; wsum[2] = t0 + t1; wsum[3] = t0 + t1 + t2;
  }
  __syncthreads();
  if (n < N_NODES) row_ptr[n] = base + wsum[wid] + (v - d);
}

__global__ void k_scatter(const int* __restrict__ ei, const float* __restrict__ ea,
                          const float* __restrict__ scal, const int* __restrict__ row_ptr,
                          int* __restrict__ cursor, int* __restrict__ csr_src,
                          int* __restrict__ csr_dst, float* __restrict__ csr_ea){
  int i = blockIdx.x * blockDim.x + threadIdx.x;
  if (i >= N_EDGES + N_NODES) return;
  int s, d; float v;
  if (i < N_EDGES){ s = ei[i]; d = ei[N_EDGES + i]; v = ea[i]; }
  else            { s = d = i - N_EDGES; v = scal[0] * (1.0f / N_EDGES); }  // ea_mean
  int pos = row_ptr[d] + atomicAdd(&cursor[d], 1);
  csr_src[pos] = s;
  csr_dst[pos] = d;
  csr_ea[pos]  = v;
}

// per-edge softmax numerator, packed (src, w) for the aggregate hot loop.
// unstabilized exp is exact math (e^l / sum e^l); logits O(+-6)
__global__ void k_edgew(const float* __restrict__ a_s, const float* __restrict__ a_d,
                        const int* __restrict__ csr_src, const int* __restrict__ csr_dst,
                        const float* __restrict__ csr_ea, const float* __restrict__ scal,
                        int l, int2* __restrict__ csr_sw){
  int i = blockIdx.x * 256 + threadIdx.x;
  if (i >= N_EDGES + N_NODES) return;
  int s = csr_src[i];
  float lg = a_s[s] + a_d[csr_dst[i]] + scal[1 + l]*csr_ea[i];
  lg = (lg > 0.f) ? lg : SLOPE*lg;
  int2 p; p.x = s; p.y = __float_as_int(__expf(lg));
  csr_sw[i] = p;
}

// ---- MFMA GEMM, split-bf16 (3-term), W staged in LDS, A prefetched ----------
// Block = 256 thr = 4 waves; block tile 128 rows; wave tile 32 rows (2 m-tiles).
// mode 0: C=xt, a_s=C·att1, a_d=C·att2;  mode 1: C=relu(C+bias);
// mode 2: relu(C+bias)·att1 -> atomicAdd out[batch[row]]
__global__ __launch_bounds__(256) void k_gemm(
    const float* __restrict__ A, const int* __restrict__ xmap,
    const unsigned short* __restrict__ Wf,      // fragment-ordered, 32768 ushorts
    float* __restrict__ C,
    const float* __restrict__ att1, const float* __restrict__ att2,
    float* __restrict__ a_s_out, float* __restrict__ a_d_out,
    const float* __restrict__ bias,
    const int* __restrict__ batch, float* __restrict__ out,
    int mode)
{
  __shared__ unsigned short lw[32768];   // exactly 64 KB: hi plane then lo plane
  int tid  = threadIdx.x;
  int w    = tid >> 6;
  int lane = tid & 63;
  int q    = lane >> 4;
  int ln   = lane & 15;
  int waveRow = blockIdx.x*128 + w*32;

  // stage W fragments (coalesced 16B/thread x 16 iters)
  #pragma unroll
  for (int i = 0; i < 16; ++i){
    int idx = (i*256 + tid) * 8;         // ushort index
    *(bf16x8*)(lw + idx) = *(const bf16x8*)(Wf + idx);
  }

  // prefetch A fragments for both m-tiles, all 4 k0 (registers)
  float4 araw[2][8];
  #pragma unroll
  for (int m = 0; m < 2; ++m){
    int r = waveRow + m*16 + ln;
    if (r >= N_NODES) r = N_NODES - 1;
    if (xmap) r = xmap[r];
    const float* Arow = A + (size_t)r*H;
    #pragma unroll
    for (int k0i = 0; k0i < 4; ++k0i){
      araw[m][k0i*2]   = *(const float4*)(Arow + k0i*32 + q*8);
      araw[m][k0i*2+1] = *(const float4*)(Arow + k0i*32 + q*8 + 4);
    }
  }
  __syncthreads();   // W staged (also drains A loads)

  f32x4 acc[2][8];
  #pragma unroll
  for (int m = 0; m < 2; ++m)
    #pragma unroll
    for (int ct = 0; ct < 8; ++ct) acc[m][ct] = (f32x4){0.f,0.f,0.f,0.f};

  #pragma unroll
  for (int k0i = 0; k0i < 4; ++k0i){
    bf16x8 ahi[2], alo[2];
    #pragma unroll
    for (int m = 0; m < 2; ++m){
      float fa[8] = {araw[m][k0i*2].x,   araw[m][k0i*2].y,
                     araw[m][k0i*2].z,   araw[m][k0i*2].w,
                     araw[m][k0i*2+1].x, araw[m][k0i*2+1].y,
                     araw[m][k0i*2+1].z, araw[m][k0i*2+1].w};
      #pragma unroll
      for (int j = 0; j < 8; ++j){
        unsigned int u = __float_as_uint(fa[j]);
        ahi[m][j] = (short)(u >> 16);
        float rr = fa[j] - __uint_as_float(u & 0xFFFF0000u);
        alo[m][j] = (short)(__float_as_uint(rr) >> 16);
      }
    }
    #pragma unroll
    for (int ct = 0; ct < 8; ++ct){
      bf16x8 bhi = *(const bf16x8*)(lw + (k0i*8 + ct)*512 + lane*8);
      bf16x8 blo = *(const bf16x8*)(lw + ((4 + k0i)*8 + ct)*512 + lane*8);
      #pragma unroll
      for (int m = 0; m < 2; ++m){
        acc[m][ct] = __builtin_amdgcn_mfma_f32_16x16x32_bf16(alo[m], bhi, acc[m][ct], 0,0,0);
        acc[m][ct] = __builtin_amdgcn_mfma_f32_16x16x32_bf16(ahi[m], blo, acc[m][ct], 0,0,0);
        acc[m][ct] = __builtin_amdgcn_mfma_f32_16x16x32_bf16(ahi[m], bhi, acc[m][ct], 0,0,0);
      }
    }
  }

  // C/D layout: col = ct*16 + ln, row = (m-tile base) + q*4 + r
  if (mode == 0){
    float as_l[8], ad_l[8];
    #pragma unroll
    for (int ct = 0; ct < 8; ++ct){ as_l[ct] = att1[ct*16+ln]; ad_l[ct] = att2[ct*16+ln]; }
    #pragma unroll
    for (int m = 0; m < 2; ++m){
      #pragma unroll
      for (int r = 0; r < 4; ++r){
        int grow = waveRow + m*16 + q*4 + r;
        bool ok = grow < N_NODES;
        float ps = 0.f, pd = 0.f;
        #pragma unroll
        for (int ct = 0; ct < 8; ++ct){
          float v = acc[m][ct][r];
          if (ok) C[(size_t)grow*H + ct*16 + ln] = v;
          ps += v * as_l[ct]; pd += v * ad_l[ct];
        }
        #pragma unroll
        for (int mk = 8; mk > 0; mk >>= 1){
          ps += __shfl_xor(ps, mk, 64);
          pd += __shfl_xor(pd, mk, 64);
        }
        if (ok && ln == 0){ a_s_out[grow] = ps; a_d_out[grow] = pd; }
      }
    }
  } else if (mode == 1){
    float b_l[8];
    #pragma unroll
    for (int ct = 0; ct < 8; ++ct) b_l[ct] = bias[ct*16+ln];
    #pragma unroll
    for (int m = 0; m < 2; ++m){
      #pragma unroll
      for (int r = 0; r < 4; ++r){
        int grow = waveRow + m*16 + q*4 + r;
        if (grow >= N_NODES) continue;
        #pragma unroll
        for (int ct = 0; ct < 8; ++ct)
          C[(size_t)grow*H + ct*16 + ln] = fmaxf(acc[m][ct][r] + b_l[ct], 0.f);
      }
    }
  } else {
    float b_l[8], wp_l[8];
    #pragma unroll
    for (int ct = 0; ct < 8; ++ct){ b_l[ct] = bias[ct*16+ln]; wp_l[ct] = att1[ct*16+ln]; }
    #pragma unroll
    for (int m = 0; m < 2; ++m){
      #pragma unroll
      for (int r = 0; r < 4; ++r){
        int grow = waveRow + m*16 + q*4 + r;
        bool ok = grow < N_NODES;
        float ps = 0.f;
        #pragma unroll
        for (int ct = 0; ct < 8; ++ct)
          ps += fmaxf(acc[m][ct][r] + b_l[ct], 0.f) * wp_l[ct];
        #pragma unroll
        for (int mk = 8; mk > 0; mk >>= 1) ps += __shfl_xor(ps, mk, 64);
        if (ok && ln == 0) atomicAdd(&out[batch[grow]], ps);
      }
    }
  }
}

// ---- aggregate: one wave per node; (src,w) pairs precomputed ----------------
// Loop body = 8 induction-addressed int2 broadcast loads (clusterable), then
// 8 independent 512B row gathers, then 16 FMAs. No dependent-address chain.
__global__ __launch_bounds__(256, 4) void k_aggregate(
    const float* __restrict__ xt, const int2* __restrict__ csr_sw,
    const int* __restrict__ row_ptr, const int* __restrict__ deg,
    const float* __restrict__ bias, float* __restrict__ hout)
{
  int n = __builtin_amdgcn_readfirstlane(blockIdx.x*4 + (threadIdx.x >> 6));
  if (n >= N_NODES) return;
  int lane = threadIdx.x & 63;
  int beg = row_ptr[n];
  int d   = deg[n];              // >= 1 (self loop)

  float2 acc = make_float2(0.f, 0.f);
  float ss = 0.f;
  for (int j0 = 0; j0 < d; j0 += 8){
    int2 sw[8];
    #pragma unroll
    for (int u = 0; u < 8; ++u){
      int jj = j0 + u;
      sw[u] = csr_sw[beg + (jj < d ? jj : 0)];
      if (jj >= d) sw[u].y = 0;              // w = 0.0f
    }
    float2 xv[8];
    #pragma unroll
    for (int u = 0; u < 8; ++u)
      xv[u] = *(const float2*)(xt + (size_t)sw[u].x*H + lane*2);
    #pragma unroll
    for (int u = 0; u < 8; ++u){
      float wgt = __int_as_float(sw[u].y);
      ss    += wgt;
      acc.x += wgt * xv[u].x;
      acc.y += wgt * xv[u].y;
    }
  }

  float2 bv = *(const float2*)(bias + lane*2);
  acc.x = acc.x/ss + bv.x;
  acc.y = acc.y/ss + bv.y;
  float sq = wave_reduce_sum(acc.x*acc.x + acc.y*acc.y);
  float nrm = fmaxf(sqrtf(sq), 1e-12f);
  float2 o = make_float2(acc.x/nrm, acc.y/nrm);
  *(float2*)(hout + (size_t)n*H + lane*2) = o;
}

// ---- readout init -----------------------------------------------------------
__global__ void k_out_init(float* __restrict__ out, const float* __restrict__ wp_b){
  int g = blockIdx.x * blockDim.x + threadIdx.x;
  if (g < NG) out[g] = wp_b[0];
}

// ---- launch -----------------------------------------------------------------
extern "C" void kernel_launch(void* const* d_in, const int* in_sizes, int n_in,
                              void* d_out, int out_size, void* d_ws, size_t ws_size,
                              hipStream_t stream) {
  const int*   x          = (const int*)  d_in[0];
  const int*   edge_index = (const int*)  d_in[1];
  const float* edge_attr  = (const float*)d_in[2];
  const int*   batch      = (const int*)  d_in[3];
  const float* emb        = (const float*)d_in[4];
  const float* gat_W      = (const float*)d_in[5];
  const float* att_src    = (const float*)d_in[6];
  const float* att_dst    = (const float*)d_in[7];
  const float* edge_W     = (const float*)d_in[8];
  const float* att_edge   = (const float*)d_in[9];
  const float* gat_b      = (const float*)d_in[10];
  const float* lin_W      = (const float*)d_in[11];
  const float* lin_b      = (const float*)d_in[12];
  const float* wp_W       = (const float*)d_in[13];
  const float* wp_b       = (const float*)d_in[14];
  float* out = (float*)d_out;

  // workspace layout (d_ws is >=256B aligned; h+xt keep 8B alignment for int2)
  float* ws     = (float*)d_ws;
  float* h      = ws;                                   // N*H
  float* xt     = h + (size_t)N_NODES*H;                // N*H
  int2*  csr_sw = (int2*)(xt + (size_t)N_NODES*H);      // E+N
  float* a_s    = (float*)(csr_sw + (N_EDGES + N_NODES)); // N
  float* a_d    = a_s + N_NODES;                        // N
  float* csr_ea = a_d + N_NODES;                        // E+N
  float* scal   = csr_ea + (N_EDGES + N_NODES);         // 8: [0]=ea_sum,[1..3]=dot_l,[4]=counter
  int*   deg    = (int*)(scal + 8);                     // N (zeroed)
  int*   cursor = deg + N_NODES;                        // N (zeroed)
  int*   row_ptr= cursor + N_NODES;                     // N
  int*   csr_src= row_ptr + N_NODES;                    // E+N
  int*   csr_dst= csr_src + (N_EDGES + N_NODES);        // E+N
  unsigned short* Wt = (unsigned short*)(csr_dst + (N_EDGES + N_NODES)); // 5*32768

  hipMemsetAsync(scal, 0, (size_t)(8 + 2*N_NODES) * sizeof(float), stream);

  k_ea_sum<<<256, 256, 0, stream>>>(edge_attr, scal);
  k_dots  <<<NLAYERS, 64, 0, stream>>>(edge_W, att_edge, scal);
  k_convW <<<(5*32768 + 255)/256, 256, 0, stream>>>(gat_W, lin_W, Wt);
  k_deg   <<<(N_EDGES + N_NODES + 255)/256, 256, 0, stream>>>(edge_index, deg);
  k_alloc <<<(N_NODES + 255)/256, 256, 0, stream>>>(deg, row_ptr, (int*)&scal[4]);
  k_scatter<<<(N_EDGES + N_NODES + 255)/256, 256, 0, stream>>>(
      edge_index, edge_attr, scal, row_ptr, cursor, csr_src, csr_dst, csr_ea);
  k_out_init<<<(NG + 255)/256, 256, 0, stream>>>(out, wp_b);

  const int gemm_grid = (N_NODES + 127) / 128;
  const int edge_grid = (N_EDGES + N_NODES + 255) / 256;
  for (int l = 0; l < NLAYERS; ++l){
    k_gemm<<<gemm_grid, 256, 0, stream>>>(
        (l == 0) ? emb : h, (l == 0) ? x : nullptr,
        Wt + (size_t)l*32768, xt,
        att_src + l*H, att_dst + l*H, a_s, a_d,
        nullptr, nullptr, nullptr, 0);
    k_edgew<<<edge_grid, 256, 0, stream>>>(
        a_s, a_d, csr_src, csr_dst, csr_ea, scal, l, csr_sw);
    k_aggregate<<<N_NODES/4, 256, 0, stream>>>(
        xt, csr_sw, row_ptr, deg, gat_b + l*H, h);
  }
  // dense 1: h -> xt (relu+bias)
  k_gemm<<<gemm_grid, 256, 0, stream>>>(
      h, nullptr, Wt + (size_t)3*32768, xt,
      nullptr, nullptr, nullptr, nullptr, lin_b, nullptr, nullptr, 1);
  // dense 2 + fused readout: relu(xt@W+b)·wp -> atomicAdd out[batch]
  k_gemm<<<gemm_grid, 256, 0, stream>>>(
      xt, nullptr, Wt + (size_t)4*32768, nullptr,
      wp_W, nullptr, nullptr, nullptr, lin_b + H, batch, out, 2);
}

// Round 7
// 425.799 us; speedup vs baseline: 2.0902x; 1.0814x over previous
//
#include <hip/hip_runtime.h>
#include <math.h>

#define N_NODES 100000
#define N_EDGES 400000
#define NG 2048
#define H 128
#define NLAYERS 3
#define SLOPE 0.2f

typedef __attribute__((ext_vector_type(8))) short bf16x8;
typedef __attribute__((ext_vector_type(4))) float f32x4;

__device__ __forceinline__ float wave_reduce_sum(float v){
  #pragma unroll
  for (int off = 32; off > 0; off >>= 1) v += __shfl_xor(v, off, 64);
  return v;
}
__device__ __forceinline__ unsigned short bfhi(float f){
  return (unsigned short)(__float_as_uint(f) >> 16);   // truncation; lo term compensates
}
__device__ __forceinline__ float bftof(unsigned short h){
  return __uint_as_float(((unsigned int)h) << 16);
}
__device__ __forceinline__ void cvt8(float4 f0, float4 f1, bf16x8* hi, bf16x8* lo){
  float fa[8] = {f0.x,f0.y,f0.z,f0.w,f1.x,f1.y,f1.z,f1.w};
  #pragma unroll
  for (int j = 0; j < 8; ++j){
    unsigned int u = __float_as_uint(fa[j]);
    (*hi)[j] = (short)(u >> 16);
    float rr = fa[j] - __uint_as_float(u & 0xFFFF0000u);
    (*lo)[j] = (short)(__float_as_uint(rr) >> 16);
  }
}

// ---- preprocessing ----------------------------------------------------------

__global__ void k_ea_sum(const float* __restrict__ ea, float* __restrict__ scal){
  int i = blockIdx.x * blockDim.x + threadIdx.x;
  int stride = gridDim.x * blockDim.x;
  float v = 0.f;
  for (; i < N_EDGES; i += stride) v += ea[i];
  v = wave_reduce_sum(v);
  if ((threadIdx.x & 63) == 0) atomicAdd(&scal[0], v);
}

__global__ void k_dots(const float* __restrict__ ew, const float* __restrict__ ae,
                       float* __restrict__ scal){
  int l = blockIdx.x;
  int lane = threadIdx.x;  // blockDim = 64
  float p = ew[l*H + lane]*ae[l*H + lane] + ew[l*H + lane + 64]*ae[l*H + lane + 64];
  p = wave_reduce_sum(p);
  if (lane == 0) scal[1 + l] = p;
}

// W -> bf16 hi/lo, MFMA B-fragment order, K-PHASE OUTERMOST for 32KB staging.
// Per matrix m (32768 ushorts): idx = kp*16384 + p*8192 + ki*4096 + ct*512 + lane*8 + j
// where k = (kp*2+ki)*32 + (lane>>4)*8 + j, n = ct*16 + (lane&15), p = hi/lo plane.
__global__ void k_convW(const float* __restrict__ gat_W, const float* __restrict__ lin_W,
                        unsigned short* __restrict__ Wf){
  int i = blockIdx.x * 256 + threadIdx.x;
  if (i >= 5*32768) return;
  int m   = i >> 15;
  int r   = i & 32767;
  int kp  = r >> 14;
  int r2  = r & 16383;
  int p   = r2 >> 13;
  int r3  = r2 & 8191;
  int ki  = r3 >> 12;
  int r4  = r3 & 4095;
  int ct  = r4 >> 9;
  int r5  = r4 & 511;
  int lane= r5 >> 3;
  int j   = r5 & 7;
  int q = lane >> 4, ln = lane & 15;
  int k = (kp*2 + ki)*32 + q*8 + j;
  int n = ct*16 + ln;
  const float* src = (m < 3) ? (gat_W + m*16384) : (lin_W + (m-3)*16384);
  float w = src[k*H + n];
  unsigned short hi = bfhi(w);
  Wf[i] = (p == 0) ? hi : bfhi(w - bftof(hi));
}

__global__ void k_deg(const int* __restrict__ ei, int* __restrict__ deg){
  int i = blockIdx.x * blockDim.x + threadIdx.x;
  if (i >= N_EDGES + N_NODES) return;
  int d = (i < N_EDGES) ? ei[N_EDGES + i] : (i - N_EDGES);
  atomicAdd(&deg[d], 1);
}

// block scan + one atomic per block (CSR range order across nodes irrelevant)
__global__ __launch_bounds__(256) void k_alloc(
    const int* __restrict__ deg, int* __restrict__ row_ptr, int* __restrict__ counter){
  __shared__ int wsum[4];
  __shared__ int base;
  int n = blockIdx.x * 256 + threadIdx.x;
  int d = (n < N_NODES) ? deg[n] : 0;
  int lane = threadIdx.x & 63, wid = threadIdx.x >> 6;
  int v = d;
  #pragma unroll
  for (int off = 1; off < 64; off <<= 1){
    int u = __shfl_up(v, off, 64);
    if (lane >= off) v += u;
  }
  if (lane == 63) wsum[wid] = v;
  __syncthreads();
  if (threadIdx.x == 0){
    int t0 = wsum[0], t1 = wsum[1], t2 = wsum[2], t3 = wsum[3];
    base = atomicAdd(counter, t0 + t1 + t2 + t3);
    wsum[0] = 0; wsum[1] = t0; wsum[2] = t0 + t1; wsum[3] = t0 + t1 + t2;
  }
  __syncthreads();
  if (n < N_NODES) row_ptr[n] = base + wsum[wid] + (v - d);
}

__global__ void k_scatter(const int* __restrict__ ei, const float* __restrict__ ea,
                          const float* __restrict__ scal, const int* __restrict__ row_ptr,
                          int* __restrict__ cursor, int* __restrict__ csr_src,
                          int* __restrict__ csr_dst, float* __restrict__ csr_ea){
  int i = blockIdx.x * blockDim.x + threadIdx.x;
  if (i >= N_EDGES + N_NODES) return;
  int s, d; float v;
  if (i < N_EDGES){ s = ei[i]; d = ei[N_EDGES + i]; v = ea[i]; }
  else            { s = d = i - N_EDGES; v = scal[0] * (1.0f / N_EDGES); }  // ea_mean
  int pos = row_ptr[d] + atomicAdd(&cursor[d], 1);
  csr_src[pos] = s;
  csr_dst[pos] = d;
  csr_ea[pos]  = v;
}

// per-edge softmax numerator, packed (src, w) for the aggregate hot loop.
// unstabilized exp is exact math (e^l / sum e^l); logits O(+-6)
__global__ void k_edgew(const float* __restrict__ a_s, const float* __restrict__ a_d,
                        const int* __restrict__ csr_src, const int* __restrict__ csr_dst,
                        const float* __restrict__ csr_ea, const float* __restrict__ scal,
                        int l, int2* __restrict__ csr_sw){
  int i = blockIdx.x * 256 + threadIdx.x;
  if (i >= N_EDGES + N_NODES) return;
  int s = csr_src[i];
  float lg = a_s[s] + a_d[csr_dst[i]] + scal[1 + l]*csr_ea[i];
  lg = (lg > 0.f) ? lg : SLOPE*lg;
  int2 p; p.x = s; p.y = __float_as_int(__expf(lg));
  csr_sw[i] = p;
}

// ---- MFMA GEMM, split-bf16 (3-term), K-phased 32KB LDS W staging ------------
// Block = 256 thr = 4 waves; block tile 128 rows; wave tile 32 rows (2 m-tiles).
// Two K phases of 64 each; phase-1 A loads issued before phase-0 compute.
// mode 0: C=xt, a_s=C·att1, a_d=C·att2;  mode 1: C=relu(C+bias);
// mode 2: relu(C+bias)·att1 -> atomicAdd out[batch[row]]
__global__ __launch_bounds__(256, 4) void k_gemm(
    const float* __restrict__ A, const int* __restrict__ xmap,
    const unsigned short* __restrict__ Wf,      // fragment-ordered, 32768 ushorts
    float* __restrict__ C,
    const float* __restrict__ att1, const float* __restrict__ att2,
    float* __restrict__ a_s_out, float* __restrict__ a_d_out,
    const float* __restrict__ bias,
    const int* __restrict__ batch, float* __restrict__ out,
    int mode)
{
  __shared__ unsigned short lw[16384];   // 32 KB: one K-phase (hi plane + lo plane)
  int tid  = threadIdx.x;
  int w    = tid >> 6;
  int lane = tid & 63;
  int q    = lane >> 4;
  int ln   = lane & 15;
  int waveRow = blockIdx.x*128 + w*32;

  const float* Arow[2];
  #pragma unroll
  for (int m = 0; m < 2; ++m){
    int r = waveRow + m*16 + ln;
    if (r >= N_NODES) r = N_NODES - 1;
    if (xmap) r = xmap[r];
    Arow[m] = A + (size_t)r*H;
  }

  // A loads for phase 0 (k 0..63)
  float4 a0[2][4];
  #pragma unroll
  for (int m = 0; m < 2; ++m)
    #pragma unroll
    for (int ki = 0; ki < 2; ++ki){
      a0[m][ki*2]   = *(const float4*)(Arow[m] + ki*32 + q*8);
      a0[m][ki*2+1] = *(const float4*)(Arow[m] + ki*32 + q*8 + 4);
    }

  // stage W phase 0 (32 KB, coalesced 16B/thread x 8)
  #pragma unroll
  for (int i = 0; i < 8; ++i){
    int idx = (i*256 + tid) * 8;
    *(bf16x8*)(lw + idx) = *(const bf16x8*)(Wf + idx);
  }
  __syncthreads();

  // A loads for phase 1 (k 64..127) — issue now, consumed after next barrier
  float4 a1[2][4];
  #pragma unroll
  for (int m = 0; m < 2; ++m)
    #pragma unroll
    for (int ki = 0; ki < 2; ++ki){
      a1[m][ki*2]   = *(const float4*)(Arow[m] + 64 + ki*32 + q*8);
      a1[m][ki*2+1] = *(const float4*)(Arow[m] + 64 + ki*32 + q*8 + 4);
    }

  f32x4 acc[2][8];
  #pragma unroll
  for (int m = 0; m < 2; ++m)
    #pragma unroll
    for (int ct = 0; ct < 8; ++ct) acc[m][ct] = (f32x4){0.f,0.f,0.f,0.f};

  // compute phase 0
  #pragma unroll
  for (int ki = 0; ki < 2; ++ki){
    bf16x8 ahi[2], alo[2];
    #pragma unroll
    for (int m = 0; m < 2; ++m) cvt8(a0[m][ki*2], a0[m][ki*2+1], &ahi[m], &alo[m]);
    #pragma unroll
    for (int ct = 0; ct < 8; ++ct){
      bf16x8 bhi = *(const bf16x8*)(lw + ki*4096 + ct*512 + lane*8);
      bf16x8 blo = *(const bf16x8*)(lw + 8192 + ki*4096 + ct*512 + lane*8);
      #pragma unroll
      for (int m = 0; m < 2; ++m){
        acc[m][ct] = __builtin_amdgcn_mfma_f32_16x16x32_bf16(alo[m], bhi, acc[m][ct], 0,0,0);
        acc[m][ct] = __builtin_amdgcn_mfma_f32_16x16x32_bf16(ahi[m], blo, acc[m][ct], 0,0,0);
        acc[m][ct] = __builtin_amdgcn_mfma_f32_16x16x32_bf16(ahi[m], bhi, acc[m][ct], 0,0,0);
      }
    }
  }
  __syncthreads();   // all waves done reading phase-0 W

  // stage W phase 1
  #pragma unroll
  for (int i = 0; i < 8; ++i){
    int idx = (i*256 + tid) * 8;
    *(bf16x8*)(lw + idx) = *(const bf16x8*)(Wf + 16384 + idx);
  }
  __syncthreads();

  // compute phase 1
  #pragma unroll
  for (int ki = 0; ki < 2; ++ki){
    bf16x8 ahi[2], alo[2];
    #pragma unroll
    for (int m = 0; m < 2; ++m) cvt8(a1[m][ki*2], a1[m][ki*2+1], &ahi[m], &alo[m]);
    #pragma unroll
    for (int ct = 0; ct < 8; ++ct){
      bf16x8 bhi = *(const bf16x8*)(lw + ki*4096 + ct*512 + lane*8);
      bf16x8 blo = *(const bf16x8*)(lw + 8192 + ki*4096 + ct*512 + lane*8);
      #pragma unroll
      for (int m = 0; m < 2; ++m){
        acc[m][ct] = __builtin_amdgcn_mfma_f32_16x16x32_bf16(alo[m], bhi, acc[m][ct], 0,0,0);
        acc[m][ct] = __builtin_amdgcn_mfma_f32_16x16x32_bf16(ahi[m], blo, acc[m][ct], 0,0,0);
        acc[m][ct] = __builtin_amdgcn_mfma_f32_16x16x32_bf16(ahi[m], bhi, acc[m][ct], 0,0,0);
      }
    }
  }

  // C/D layout: col = ct*16 + ln, row = (m-tile base) + q*4 + r
  if (mode == 0){
    float as_l[8], ad_l[8];
    #pragma unroll
    for (int ct = 0; ct < 8; ++ct){ as_l[ct] = att1[ct*16+ln]; ad_l[ct] = att2[ct*16+ln]; }
    #pragma unroll
    for (int m = 0; m < 2; ++m){
      #pragma unroll
      for (int r = 0; r < 4; ++r){
        int grow = waveRow + m*16 + q*4 + r;
        bool ok = grow < N_NODES;
        float ps = 0.f, pd = 0.f;
        #pragma unroll
        for (int ct = 0; ct < 8; ++ct){
          float v = acc[m][ct][r];
          if (ok) C[(size_t)grow*H + ct*16 + ln] = v;
          ps += v * as_l[ct]; pd += v * ad_l[ct];
        }
        #pragma unroll
        for (int mk = 8; mk > 0; mk >>= 1){
          ps += __shfl_xor(ps, mk, 64);
          pd += __shfl_xor(pd, mk, 64);
        }
        if (ok && ln == 0){ a_s_out[grow] = ps; a_d_out[grow] = pd; }
      }
    }
  } else if (mode == 1){
    float b_l[8];
    #pragma unroll
    for (int ct = 0; ct < 8; ++ct) b_l[ct] = bias[ct*16+ln];
    #pragma unroll
    for (int m = 0; m < 2; ++m){
      #pragma unroll
      for (int r = 0; r < 4; ++r){
        int grow = waveRow + m*16 + q*4 + r;
        if (grow >= N_NODES) continue;
        #pragma unroll
        for (int ct = 0; ct < 8; ++ct)
          C[(size_t)grow*H + ct*16 + ln] = fmaxf(acc[m][ct][r] + b_l[ct], 0.f);
      }
    }
  } else {
    float b_l[8], wp_l[8];
    #pragma unroll
    for (int ct = 0; ct < 8; ++ct){ b_l[ct] = bias[ct*16+ln]; wp_l[ct] = att1[ct*16+ln]; }
    #pragma unroll
    for (int m = 0; m < 2; ++m){
      #pragma unroll
      for (int r = 0; r < 4; ++r){
        int grow = waveRow + m*16 + q*4 + r;
        bool ok = grow < N_NODES;
        float ps = 0.f;
        #pragma unroll
        for (int ct = 0; ct < 8; ++ct)
          ps += fmaxf(acc[m][ct][r] + b_l[ct], 0.f) * wp_l[ct];
        #pragma unroll
        for (int mk = 8; mk > 0; mk >>= 1) ps += __shfl_xor(ps, mk, 64);
        if (ok && ln == 0) atomicAdd(&out[batch[grow]], ps);
      }
    }
  }
}

// ---- aggregate: one wave per node; (src,w) pairs precomputed ----------------
__global__ __launch_bounds__(256, 4) void k_aggregate(
    const float* __restrict__ xt, const int2* __restrict__ csr_sw,
    const int* __restrict__ row_ptr, const int* __restrict__ deg,
    const float* __restrict__ bias, float* __restrict__ hout)
{
  int n = __builtin_amdgcn_readfirstlane(blockIdx.x*4 + (threadIdx.x >> 6));
  if (n >= N_NODES) return;
  int lane = threadIdx.x & 63;
  int beg = row_ptr[n];
  int d   = deg[n];              // >= 1 (self loop)

  float2 acc = make_float2(0.f, 0.f);
  float ss = 0.f;
  for (int j0 = 0; j0 < d; j0 += 8){
    int2 sw[8];
    #pragma unroll
    for (int u = 0; u < 8; ++u){
      int jj = j0 + u;
      sw[u] = csr_sw[beg + (jj < d ? jj : 0)];
      if (jj >= d) sw[u].y = 0;              // w = 0.0f
    }
    float2 xv[8];
    #pragma unroll
    for (int u = 0; u < 8; ++u)
      xv[u] = *(const float2*)(xt + (size_t)sw[u].x*H + lane*2);
    #pragma unroll
    for (int u = 0; u < 8; ++u){
      float wgt = __int_as_float(sw[u].y);
      ss    += wgt;
      acc.x += wgt * xv[u].x;
      acc.y += wgt * xv[u].y;
    }
  }

  float2 bv = *(const float2*)(bias + lane*2);
  acc.x = acc.x/ss + bv.x;
  acc.y = acc.y/ss + bv.y;
  float sq = wave_reduce_sum(acc.x*acc.x + acc.y*acc.y);
  float nrm = fmaxf(sqrtf(sq), 1e-12f);
  float2 o = make_float2(acc.x/nrm, acc.y/nrm);
  *(float2*)(hout + (size_t)n*H + lane*2) = o;
}

// ---- readout init -----------------------------------------------------------
__global__ void k_out_init(float* __restrict__ out, const float* __restrict__ wp_b){
  int g = blockIdx.x * blockDim.x + threadIdx.x;
  if (g < NG) out[g] = wp_b[0];
}

// ---- launch -----------------------------------------------------------------
extern "C" void kernel_launch(void* const* d_in, const int* in_sizes, int n_in,
                              void* d_out, int out_size, void* d_ws, size_t ws_size,
                              hipStream_t stream) {
  const int*   x          = (const int*)  d_in[0];
  const int*   edge_index = (const int*)  d_in[1];
  const float* edge_attr  = (const float*)d_in[2];
  const int*   batch      = (const int*)  d_in[3];
  const float* emb        = (const float*)d_in[4];
  const float* gat_W      = (const float*)d_in[5];
  const float* att_src    = (const float*)d_in[6];
  const float* att_dst    = (const float*)d_in[7];
  const float* edge_W     = (const float*)d_in[8];
  const float* att_edge   = (const float*)d_in[9];
  const float* gat_b      = (const float*)d_in[10];
  const float* lin_W      = (const float*)d_in[11];
  const float* lin_b      = (const float*)d_in[12];
  const float* wp_W       = (const float*)d_in[13];
  const float* wp_b       = (const float*)d_in[14];
  float* out = (float*)d_out;

  // workspace layout (d_ws is >=256B aligned; h+xt keep 8B alignment for int2)
  float* ws     = (float*)d_ws;
  float* h      = ws;                                   // N*H
  float* xt     = h + (size_t)N_NODES*H;                // N*H
  int2*  csr_sw = (int2*)(xt + (size_t)N_NODES*H);      // E+N
  float* a_s    = (float*)(csr_sw + (N_EDGES + N_NODES)); // N
  float* a_d    = a_s + N_NODES;                        // N
  float* csr_ea = a_d + N_NODES;                        // E+N
  float* scal   = csr_ea + (N_EDGES + N_NODES);         // 8: [0]=ea_sum,[1..3]=dot_l,[4]=counter
  int*   deg    = (int*)(scal + 8);                     // N (zeroed)
  int*   cursor = deg + N_NODES;                        // N (zeroed)
  int*   row_ptr= cursor + N_NODES;                     // N
  int*   csr_src= row_ptr + N_NODES;                    // E+N
  int*   csr_dst= csr_src + (N_EDGES + N_NODES);        // E+N
  unsigned short* Wt = (unsigned short*)(csr_dst + (N_EDGES + N_NODES)); // 5*32768

  hipMemsetAsync(scal, 0, (size_t)(8 + 2*N_NODES) * sizeof(float), stream);

  k_ea_sum<<<256, 256, 0, stream>>>(edge_attr, scal);
  k_dots  <<<NLAYERS, 64, 0, stream>>>(edge_W, att_edge, scal);
  k_convW <<<(5*32768 + 255)/256, 256, 0, stream>>>(gat_W, lin_W, Wt);
  k_deg   <<<(N_EDGES + N_NODES + 255)/256, 256, 0, stream>>>(edge_index, deg);
  k_alloc <<<(N_NODES + 255)/256, 256, 0, stream>>>(deg, row_ptr, (int*)&scal[4]);
  k_scatter<<<(N_EDGES + N_NODES + 255)/256, 256, 0, stream>>>(
      edge_index, edge_attr, scal, row_ptr, cursor, csr_src, csr_dst, csr_ea);
  k_out_init<<<(NG + 255)/256, 256, 0, stream>>>(out, wp_b);

  const int gemm_grid = (N_NODES + 127) / 128;
  const int edge_grid = (N_EDGES + N_NODES + 255) / 256;
  for (int l = 0; l < NLAYERS; ++l){
    k_gemm<<<gemm_grid, 256, 0, stream>>>(
        (l == 0) ? emb : h, (l == 0) ? x : nullptr,
        Wt + (size_t)l*32768, xt,
        att_src + l*H, att_dst + l*H, a_s, a_d,
        nullptr, nullptr, nullptr, 0);
    k_edgew<<<edge_grid, 256, 0, stream>>>(
        a_s, a_d, csr_src, csr_dst, csr_ea, scal, l, csr_sw);
    k_aggregate<<<N_NODES/4, 256, 0, stream>>>(
        xt, csr_sw, row_ptr, deg, gat_b + l*H, h);
  }
  // dense 1: h -> xt (relu+bias)
  k_gemm<<<gemm_grid, 256, 0, stream>>>(
      h, nullptr, Wt + (size_t)3*32768, xt,
      nullptr, nullptr, nullptr, nullptr, lin_b, nullptr, nullptr, 1);
  // dense 2 + fused readout: relu(xt@W+b)·wp -> atomicAdd out[batch]
  k_gemm<<<gemm_grid, 256, 0, stream>>>(
      xt, nullptr, Wt + (size_t)4*32768, nullptr,
      wp_W, nullptr, nullptr, nullptr, lin_b + H, batch, out, 2);
}

// Round 8
// 404.575 us; speedup vs baseline: 2.1998x; 1.0525x over previous
//
#include <hip/hip_runtime.h>
#include <math.h>

#define N_NODES 100000
#define N_EDGES 400000
#define NG 2048
#define H 128
#define NLAYERS 3
#define SLOPE 0.2f

typedef __attribute__((ext_vector_type(8))) short bf16x8;
typedef __attribute__((ext_vector_type(4))) float f32x4;

__device__ __forceinline__ float wave_reduce_sum(float v){
  #pragma unroll
  for (int off = 32; off > 0; off >>= 1) v += __shfl_xor(v, off, 64);
  return v;
}
__device__ __forceinline__ unsigned short bfhi(float f){
  return (unsigned short)(__float_as_uint(f) >> 16);   // truncation; lo term compensates
}
__device__ __forceinline__ float bftof(unsigned short h){
  return __uint_as_float(((unsigned int)h) << 16);
}
__device__ __forceinline__ unsigned short rne_bf16(float f){
  unsigned int u = __float_as_uint(f);
  u += 0x7FFF + ((u >> 16) & 1);
  return (unsigned short)(u >> 16);
}
__device__ __forceinline__ void cvt8(float4 f0, float4 f1, bf16x8* hi, bf16x8* lo){
  float fa[8] = {f0.x,f0.y,f0.z,f0.w,f1.x,f1.y,f1.z,f1.w};
  #pragma unroll
  for (int j = 0; j < 8; ++j){
    unsigned int u = __float_as_uint(fa[j]);
    (*hi)[j] = (short)(u >> 16);
    float rr = fa[j] - __uint_as_float(u & 0xFFFF0000u);
    (*lo)[j] = (short)(__float_as_uint(rr) >> 16);
  }
}

// ---- preprocessing ----------------------------------------------------------

__global__ void k_ea_sum(const float* __restrict__ ea, float* __restrict__ scal){
  int i = blockIdx.x * blockDim.x + threadIdx.x;
  int stride = gridDim.x * blockDim.x;
  float v = 0.f;
  for (; i < N_EDGES; i += stride) v += ea[i];
  v = wave_reduce_sum(v);
  if ((threadIdx.x & 63) == 0) atomicAdd(&scal[0], v);
}

__global__ void k_dots(const float* __restrict__ ew, const float* __restrict__ ae,
                       float* __restrict__ scal){
  int l = blockIdx.x;
  int lane = threadIdx.x;  // blockDim = 64
  float p = ew[l*H + lane]*ae[l*H + lane] + ew[l*H + lane + 64]*ae[l*H + lane + 64];
  p = wave_reduce_sum(p);
  if (lane == 0) scal[1 + l] = p;
}

// W -> bf16 hi/lo in MFMA B-fragment order.
// Per matrix m (32768 ushorts = 64 KB): idx = p*16384 + k0i*4096 + ct*512 + lane*8 + j
// value = plane_p( W[k][n] ), k = k0i*32 + (lane>>4)*8 + j, n = ct*16 + (lane&15)
__global__ void k_convW(const float* __restrict__ gat_W, const float* __restrict__ lin_W,
                        unsigned short* __restrict__ Wf){
  int i = blockIdx.x * 256 + threadIdx.x;
  if (i >= 5*32768) return;
  int m   = i >> 15;
  int r   = i & 32767;
  int p   = r >> 14;
  int r2  = r & 16383;
  int k0i = r2 >> 12;
  int r3  = r2 & 4095;
  int ct  = r3 >> 9;
  int r4  = r3 & 511;
  int lane= r4 >> 3;
  int j   = r4 & 7;
  int q = lane >> 4, ln = lane & 15;
  int k = k0i*32 + q*8 + j;
  int n = ct*16 + ln;
  const float* src = (m < 3) ? (gat_W + m*16384) : (lin_W + (m-3)*16384);
  float w = src[k*H + n];
  unsigned short hi = bfhi(w);
  Wf[i] = (p == 0) ? hi : bfhi(w - bftof(hi));
}

__global__ void k_deg(const int* __restrict__ ei, int* __restrict__ deg){
  int i = blockIdx.x * blockDim.x + threadIdx.x;
  if (i >= N_EDGES + N_NODES) return;
  int d = (i < N_EDGES) ? ei[N_EDGES + i] : (i - N_EDGES);
  atomicAdd(&deg[d], 1);
}

// block scan + one atomic per block (CSR range order across nodes irrelevant)
__global__ __launch_bounds__(256) void k_alloc(
    const int* __restrict__ deg, int* __restrict__ row_ptr, int* __restrict__ counter){
  __shared__ int wsum[4];
  __shared__ int base;
  int n = blockIdx.x * 256 + threadIdx.x;
  int d = (n < N_NODES) ? deg[n] : 0;
  int lane = threadIdx.x & 63, wid = threadIdx.x >> 6;
  int v = d;
  #pragma unroll
  for (int off = 1; off < 64; off <<= 1){
    int u = __shfl_up(v, off, 64);
    if (lane >= off) v += u;
  }
  if (lane == 63) wsum[wid] = v;
  __syncthreads();
  if (threadIdx.x == 0){
    int t0 = wsum[0], t1 = wsum[1], t2 = wsum[2], t3 = wsum[3];
    base = atomicAdd(counter, t0 + t1 + t2 + t3);
    wsum[0] = 0; wsum[1] = t0; wsum[2] = t0 + t1; wsum[3] = t0 + t1 + t2;
  }
  __syncthreads();
  if (n < N_NODES) row_ptr[n] = base + wsum[wid] + (v - d);
}

__global__ void k_scatter(const int* __restrict__ ei, const float* __restrict__ ea,
                          const float* __restrict__ scal, const int* __restrict__ row_ptr,
                          int* __restrict__ cursor, int* __restrict__ csr_src,
                          int* __restrict__ csr_dst, float* __restrict__ csr_ea){
  int i = blockIdx.x * blockDim.x + threadIdx.x;
  if (i >= N_EDGES + N_NODES) return;
  int s, d; float v;
  if (i < N_EDGES){ s = ei[i]; d = ei[N_EDGES + i]; v = ea[i]; }
  else            { s = d = i - N_EDGES; v = scal[0] * (1.0f / N_EDGES); }  // ea_mean
  int pos = row_ptr[d] + atomicAdd(&cursor[d], 1);
  csr_src[pos] = s;
  csr_dst[pos] = d;
  csr_ea[pos]  = v;
}

// per-edge softmax numerator, packed (src, w) for the aggregate hot loop.
// unstabilized exp is exact math (e^l / sum e^l); logits O(+-6)
__global__ void k_edgew(const float* __restrict__ a_s, const float* __restrict__ a_d,
                        const int* __restrict__ csr_src, const int* __restrict__ csr_dst,
                        const float* __restrict__ csr_ea, const float* __restrict__ scal,
                        int l, int2* __restrict__ csr_sw){
  int i = blockIdx.x * 256 + threadIdx.x;
  if (i >= N_EDGES + N_NODES) return;
  int s = csr_src[i];
  float lg = a_s[s] + a_d[csr_dst[i]] + scal[1 + l]*csr_ea[i];
  lg = (lg > 0.f) ? lg : SLOPE*lg;
  int2 p; p.x = s; p.y = __float_as_int(__expf(lg));
  csr_sw[i] = p;
}

// ---- MFMA GEMM, split-bf16 (3-term), full 64KB W in LDS, one barrier --------
// Block = 256 thr = 4 waves; block tile 256 rows; wave tile 64 rows (4 m-tiles).
// A loaded one-k0i-ahead to bound VGPRs; 2 blocks/CU (LDS-capped).
// mode 0: Cb=bf16(C), a_s=C·att1, a_d=C·att2;  mode 1: C=relu(C+bias) fp32;
// mode 2: relu(C+bias)·att1 -> atomicAdd out[batch[row]]
__global__ __launch_bounds__(256, 2) void k_gemm(
    const float* __restrict__ A, const int* __restrict__ xmap,
    const unsigned short* __restrict__ Wf,      // fragment-ordered, 32768 ushorts
    float* __restrict__ C, unsigned short* __restrict__ Cb,
    const float* __restrict__ att1, const float* __restrict__ att2,
    float* __restrict__ a_s_out, float* __restrict__ a_d_out,
    const float* __restrict__ bias,
    const int* __restrict__ batch, float* __restrict__ out,
    int mode)
{
  __shared__ unsigned short lw[32768];   // 64 KB: hi plane then lo plane
  int tid  = threadIdx.x;
  int w    = tid >> 6;
  int lane = tid & 63;
  int q    = lane >> 4;
  int ln   = lane & 15;
  int waveRow = blockIdx.x*256 + w*64;

  const float* Arow[4];
  #pragma unroll
  for (int m = 0; m < 4; ++m){
    int r = waveRow + m*16 + ln;
    if (r >= N_NODES) r = N_NODES - 1;
    if (xmap) r = xmap[r];
    Arow[m] = A + (size_t)r*H;
  }

  // prefetch A for k0i = 0
  float4 acur[4][2], anxt[4][2];
  #pragma unroll
  for (int m = 0; m < 4; ++m){
    acur[m][0] = *(const float4*)(Arow[m] + q*8);
    acur[m][1] = *(const float4*)(Arow[m] + q*8 + 4);
  }

  // stage full W (64 KB, coalesced 16B/thread x 16)
  #pragma unroll
  for (int i = 0; i < 16; ++i){
    int idx = (i*256 + tid) * 8;
    *(bf16x8*)(lw + idx) = *(const bf16x8*)(Wf + idx);
  }
  __syncthreads();

  f32x4 acc[4][8];
  #pragma unroll
  for (int m = 0; m < 4; ++m)
    #pragma unroll
    for (int ct = 0; ct < 8; ++ct) acc[m][ct] = (f32x4){0.f,0.f,0.f,0.f};

  #pragma unroll
  for (int k0i = 0; k0i < 4; ++k0i){
    if (k0i < 3){
      #pragma unroll
      for (int m = 0; m < 4; ++m){
        anxt[m][0] = *(const float4*)(Arow[m] + (k0i+1)*32 + q*8);
        anxt[m][1] = *(const float4*)(Arow[m] + (k0i+1)*32 + q*8 + 4);
      }
    }
    bf16x8 ahi[4], alo[4];
    #pragma unroll
    for (int m = 0; m < 4; ++m) cvt8(acur[m][0], acur[m][1], &ahi[m], &alo[m]);
    #pragma unroll
    for (int ct = 0; ct < 8; ++ct){
      bf16x8 bhi = *(const bf16x8*)(lw + k0i*4096 + ct*512 + lane*8);
      bf16x8 blo = *(const bf16x8*)(lw + 16384 + k0i*4096 + ct*512 + lane*8);
      #pragma unroll
      for (int m = 0; m < 4; ++m){
        acc[m][ct] = __builtin_amdgcn_mfma_f32_16x16x32_bf16(alo[m], bhi, acc[m][ct], 0,0,0);
        acc[m][ct] = __builtin_amdgcn_mfma_f32_16x16x32_bf16(ahi[m], blo, acc[m][ct], 0,0,0);
        acc[m][ct] = __builtin_amdgcn_mfma_f32_16x16x32_bf16(ahi[m], bhi, acc[m][ct], 0,0,0);
      }
    }
    #pragma unroll
    for (int m = 0; m < 4; ++m){ acur[m][0] = anxt[m][0]; acur[m][1] = anxt[m][1]; }
  }

  // C/D layout: col = ct*16 + ln, row = (m-tile base) + q*4 + r
  if (mode == 0){
    float as_l[8], ad_l[8];
    #pragma unroll
    for (int ct = 0; ct < 8; ++ct){ as_l[ct] = att1[ct*16+ln]; ad_l[ct] = att2[ct*16+ln]; }
    #pragma unroll
    for (int m = 0; m < 4; ++m){
      #pragma unroll
      for (int r = 0; r < 4; ++r){
        int grow = waveRow + m*16 + q*4 + r;
        bool ok = grow < N_NODES;
        float ps = 0.f, pd = 0.f;
        #pragma unroll
        for (int ct = 0; ct < 8; ++ct){
          float v = acc[m][ct][r];
          if (ok) Cb[(size_t)grow*H + ct*16 + ln] = rne_bf16(v);
          ps += v * as_l[ct]; pd += v * ad_l[ct];
        }
        #pragma unroll
        for (int mk = 8; mk > 0; mk >>= 1){
          ps += __shfl_xor(ps, mk, 64);
          pd += __shfl_xor(pd, mk, 64);
        }
        if (ok && ln == 0){ a_s_out[grow] = ps; a_d_out[grow] = pd; }
      }
    }
  } else if (mode == 1){
    float b_l[8];
    #pragma unroll
    for (int ct = 0; ct < 8; ++ct) b_l[ct] = bias[ct*16+ln];
    #pragma unroll
    for (int m = 0; m < 4; ++m){
      #pragma unroll
      for (int r = 0; r < 4; ++r){
        int grow = waveRow + m*16 + q*4 + r;
        if (grow >= N_NODES) continue;
        #pragma unroll
        for (int ct = 0; ct < 8; ++ct)
          C[(size_t)grow*H + ct*16 + ln] = fmaxf(acc[m][ct][r] + b_l[ct], 0.f);
      }
    }
  } else {
    float b_l[8], wp_l[8];
    #pragma unroll
    for (int ct = 0; ct < 8; ++ct){ b_l[ct] = bias[ct*16+ln]; wp_l[ct] = att1[ct*16+ln]; }
    #pragma unroll
    for (int m = 0; m < 4; ++m){
      #pragma unroll
      for (int r = 0; r < 4; ++r){
        int grow = waveRow + m*16 + q*4 + r;
        bool ok = grow < N_NODES;
        float ps = 0.f;
        #pragma unroll
        for (int ct = 0; ct < 8; ++ct)
          ps += fmaxf(acc[m][ct][r] + b_l[ct], 0.f) * wp_l[ct];
        #pragma unroll
        for (int mk = 8; mk > 0; mk >>= 1) ps += __shfl_xor(ps, mk, 64);
        if (ok && ln == 0) atomicAdd(&out[batch[grow]], ps);
      }
    }
  }
}

// ---- aggregate: one wave per node; bf16 xt rows (4 B/lane gathers) ----------
__global__ __launch_bounds__(256, 4) void k_aggregate(
    const unsigned int* __restrict__ xtb, const int2* __restrict__ csr_sw,
    const int* __restrict__ row_ptr, const int* __restrict__ deg,
    const float* __restrict__ bias, float* __restrict__ hout)
{
  int n = __builtin_amdgcn_readfirstlane(blockIdx.x*4 + (threadIdx.x >> 6));
  if (n >= N_NODES) return;
  int lane = threadIdx.x & 63;
  int beg = row_ptr[n];
  int d   = deg[n];              // >= 1 (self loop)

  float2 acc = make_float2(0.f, 0.f);
  float ss = 0.f;
  for (int j0 = 0; j0 < d; j0 += 8){
    int2 sw[8];
    #pragma unroll
    for (int u = 0; u < 8; ++u){
      int jj = j0 + u;
      sw[u] = csr_sw[beg + (jj < d ? jj : 0)];
      if (jj >= d) sw[u].y = 0;              // w = 0.0f
    }
    unsigned int xv[8];
    #pragma unroll
    for (int u = 0; u < 8; ++u)
      xv[u] = xtb[(size_t)sw[u].x*(H/2) + lane];
    #pragma unroll
    for (int u = 0; u < 8; ++u){
      float wgt = __int_as_float(sw[u].y);
      float x0 = __uint_as_float(xv[u] << 16);          // col lane*2
      float x1 = __uint_as_float(xv[u] & 0xFFFF0000u);  // col lane*2+1
      ss    += wgt;
      acc.x += wgt * x0;
      acc.y += wgt * x1;
    }
  }

  float2 bv = *(const float2*)(bias + lane*2);
  acc.x = acc.x/ss + bv.x;
  acc.y = acc.y/ss + bv.y;
  float sq = wave_reduce_sum(acc.x*acc.x + acc.y*acc.y);
  float nrm = fmaxf(sqrtf(sq), 1e-12f);
  float2 o = make_float2(acc.x/nrm, acc.y/nrm);
  *(float2*)(hout + (size_t)n*H + lane*2) = o;
}

// ---- readout init -----------------------------------------------------------
__global__ void k_out_init(float* __restrict__ out, const float* __restrict__ wp_b){
  int g = blockIdx.x * blockDim.x + threadIdx.x;
  if (g < NG) out[g] = wp_b[0];
}

// ---- launch -----------------------------------------------------------------
extern "C" void kernel_launch(void* const* d_in, const int* in_sizes, int n_in,
                              void* d_out, int out_size, void* d_ws, size_t ws_size,
                              hipStream_t stream) {
  const int*   x          = (const int*)  d_in[0];
  const int*   edge_index = (const int*)  d_in[1];
  const float* edge_attr  = (const float*)d_in[2];
  const int*   batch      = (const int*)  d_in[3];
  const float* emb        = (const float*)d_in[4];
  const float* gat_W      = (const float*)d_in[5];
  const float* att_src    = (const float*)d_in[6];
  const float* att_dst    = (const float*)d_in[7];
  const float* edge_W     = (const float*)d_in[8];
  const float* att_edge   = (const float*)d_in[9];
  const float* gat_b      = (const float*)d_in[10];
  const float* lin_W      = (const float*)d_in[11];
  const float* lin_b      = (const float*)d_in[12];
  const float* wp_W       = (const float*)d_in[13];
  const float* wp_b       = (const float*)d_in[14];
  float* out = (float*)d_out;

  // workspace layout (8B alignment preserved for int2)
  float* ws     = (float*)d_ws;
  float* h      = ws;                                   // N*H
  float* xt     = h + (size_t)N_NODES*H;                // N*H (fp32, dense layers)
  int2*  csr_sw = (int2*)(xt + (size_t)N_NODES*H);      // E+N
  float* a_s    = (float*)(csr_sw + (N_EDGES + N_NODES)); // N
  float* a_d    = a_s + N_NODES;                        // N
  float* csr_ea = a_d + N_NODES;                        // E+N
  float* scal   = csr_ea + (N_EDGES + N_NODES);         // 8: [0]=ea_sum,[1..3]=dot_l,[4]=counter
  int*   deg    = (int*)(scal + 8);                     // N (zeroed)
  int*   cursor = deg + N_NODES;                        // N (zeroed)
  int*   row_ptr= cursor + N_NODES;                     // N
  int*   csr_src= row_ptr + N_NODES;                    // E+N
  int*   csr_dst= csr_src + (N_EDGES + N_NODES);        // E+N
  unsigned short* Wt  = (unsigned short*)(csr_dst + (N_EDGES + N_NODES)); // 5*32768
  unsigned short* xtb = Wt + 5*32768;                   // N*H bf16 (GAT xt)

  hipMemsetAsync(scal, 0, (size_t)(8 + 2*N_NODES) * sizeof(float), stream);

  k_ea_sum<<<256, 256, 0, stream>>>(edge_attr, scal);
  k_dots  <<<NLAYERS, 64, 0, stream>>>(edge_W, att_edge, scal);
  k_convW <<<(5*32768 + 255)/256, 256, 0, stream>>>(gat_W, lin_W, Wt);
  k_deg   <<<(N_EDGES + N_NODES + 255)/256, 256, 0, stream>>>(edge_index, deg);
  k_alloc <<<(N_NODES + 255)/256, 256, 0, stream>>>(deg, row_ptr, (int*)&scal[4]);
  k_scatter<<<(N_EDGES + N_NODES + 255)/256, 256, 0, stream>>>(
      edge_index, edge_attr, scal, row_ptr, cursor, csr_src, csr_dst, csr_ea);
  k_out_init<<<(NG + 255)/256, 256, 0, stream>>>(out, wp_b);

  const int gemm_grid = (N_NODES + 255) / 256;
  const int edge_grid = (N_EDGES + N_NODES + 255) / 256;
  for (int l = 0; l < NLAYERS; ++l){
    k_gemm<<<gemm_grid, 256, 0, stream>>>(
        (l == 0) ? emb : h, (l == 0) ? x : nullptr,
        Wt + (size_t)l*32768, nullptr, xtb,
        att_src + l*H, att_dst + l*H, a_s, a_d,
        nullptr, nullptr, nullptr, 0);
    k_edgew<<<edge_grid, 256, 0, stream>>>(
        a_s, a_d, csr_src, csr_dst, csr_ea, scal, l, csr_sw);
    k_aggregate<<<N_NODES/4, 256, 0, stream>>>(
        (const unsigned int*)xtb, csr_sw, row_ptr, deg, gat_b + l*H, h);
  }
  // dense 1: h -> xt fp32 (relu+bias)
  k_gemm<<<gemm_grid, 256, 0, stream>>>(
      h, nullptr, Wt + (size_t)3*32768, xt, nullptr,
      nullptr, nullptr, nullptr, nullptr, lin_b, nullptr, nullptr, 1);
  // dense 2 + fused readout: relu(xt@W+b)·wp -> atomicAdd out[batch]
  k_gemm<<<gemm_grid, 256, 0, stream>>>(
      xt, nullptr, Wt + (size_t)4*32768, nullptr, nullptr,
      wp_W, nullptr, nullptr, nullptr, lin_b + H, batch, out, 2);
}

// Round 9
// 385.746 us; speedup vs baseline: 2.3072x; 1.0488x over previous
//
#include <hip/hip_runtime.h>
#include <math.h>

#define N_NODES 100000
#define N_EDGES 400000
#define NG 2048
#define H 128
#define NV 100
#define NLAYERS 3
#define SLOPE 0.2f

typedef __attribute__((ext_vector_type(8))) short bf16x8;
typedef __attribute__((ext_vector_type(4))) float f32x4;

__device__ __forceinline__ float wave_reduce_sum(float v){
  #pragma unroll
  for (int off = 32; off > 0; off >>= 1) v += __shfl_xor(v, off, 64);
  return v;
}
__device__ __forceinline__ unsigned short bfhi(float f){
  return (unsigned short)(__float_as_uint(f) >> 16);   // truncation; lo term compensates
}
__device__ __forceinline__ float bftof(unsigned short h){
  return __uint_as_float(((unsigned int)h) << 16);
}
__device__ __forceinline__ unsigned short rne_bf16(float f){
  unsigned int u = __float_as_uint(f);
  u += 0x7FFF + ((u >> 16) & 1);
  return (unsigned short)(u >> 16);
}

// ---- preprocessing ----------------------------------------------------------

__global__ void k_ea_sum(const float* __restrict__ ea, float* __restrict__ scal){
  int i = blockIdx.x * blockDim.x + threadIdx.x;
  int stride = gridDim.x * blockDim.x;
  float v = 0.f;
  for (; i < N_EDGES; i += stride) v += ea[i];
  v = wave_reduce_sum(v);
  if ((threadIdx.x & 63) == 0) atomicAdd(&scal[0], v);
}

__global__ void k_dots(const float* __restrict__ ew, const float* __restrict__ ae,
                       float* __restrict__ scal){
  int l = blockIdx.x;
  int lane = threadIdx.x;  // blockDim = 64
  float p = ew[l*H + lane]*ae[l*H + lane] + ew[l*H + lane + 64]*ae[l*H + lane + 64];
  p = wave_reduce_sum(p);
  if (lane == 0) scal[1 + l] = p;
}

// W -> bf16 hi/lo in MFMA B-fragment order.
// Per matrix m (32768 ushorts = 64 KB): idx = p*16384 + k0i*4096 + ct*512 + lane*8 + j
// value = plane_p( W[k][n] ), k = k0i*32 + (lane>>4)*8 + j, n = ct*16 + (lane&15)
__global__ void k_convW(const float* __restrict__ gat_W, const float* __restrict__ lin_W,
                        unsigned short* __restrict__ Wf){
  int i = blockIdx.x * 256 + threadIdx.x;
  if (i >= 5*32768) return;
  int m   = i >> 15;
  int r   = i & 32767;
  int p   = r >> 14;
  int r2  = r & 16383;
  int k0i = r2 >> 12;
  int r3  = r2 & 4095;
  int ct  = r3 >> 9;
  int r4  = r3 & 511;
  int lane= r4 >> 3;
  int j   = r4 & 7;
  int q = lane >> 4, ln = lane & 15;
  int k = k0i*32 + q*8 + j;
  int n = ct*16 + ln;
  const float* src = (m < 3) ? (gat_W + m*16384) : (lin_W + (m-3)*16384);
  float w = src[k*H + n];
  unsigned short hi = bfhi(w);
  Wf[i] = (p == 0) ? hi : bfhi(w - bftof(hi));
}

// emb -> RNE bf16 table (51 KB, L2-resident)
__global__ void k_convE(const float* __restrict__ emb, unsigned short* __restrict__ embb){
  int i = blockIdx.x * 256 + threadIdx.x;
  if (i >= NV*H) return;
  embb[i] = rne_bf16(emb[i]);
}

__global__ void k_deg(const int* __restrict__ ei, int* __restrict__ deg){
  int i = blockIdx.x * blockDim.x + threadIdx.x;
  if (i >= N_EDGES + N_NODES) return;
  int d = (i < N_EDGES) ? ei[N_EDGES + i] : (i - N_EDGES);
  atomicAdd(&deg[d], 1);
}

// block scan + one atomic per block (CSR range order across nodes irrelevant)
__global__ __launch_bounds__(256) void k_alloc(
    const int* __restrict__ deg, int* __restrict__ row_ptr, int* __restrict__ counter){
  __shared__ int wsum[4];
  __shared__ int base;
  int n = blockIdx.x * 256 + threadIdx.x;
  int d = (n < N_NODES) ? deg[n] : 0;
  int lane = threadIdx.x & 63, wid = threadIdx.x >> 6;
  int v = d;
  #pragma unroll
  for (int off = 1; off < 64; off <<= 1){
    int u = __shfl_up(v, off, 64);
    if (lane >= off) v += u;
  }
  if (lane == 63) wsum[wid] = v;
  __syncthreads();
  if (threadIdx.x == 0){
    int t0 = wsum[0], t1 = wsum[1], t2 = wsum[2], t3 = wsum[3];
    base = atomicAdd(counter, t0 + t1 + t2 + t3);
    wsum[0] = 0; wsum[1] = t0; wsum[2] = t0 + t1; wsum[3] = t0 + t1 + t2;
  }
  __syncthreads();
  if (n < N_NODES) row_ptr[n] = base + wsum[wid] + (v - d);
}

__global__ void k_scatter(const int* __restrict__ ei, const float* __restrict__ ea,
                          const float* __restrict__ scal, const int* __restrict__ row_ptr,
                          int* __restrict__ cursor, int* __restrict__ csr_src,
                          int* __restrict__ csr_dst, float* __restrict__ csr_ea){
  int i = blockIdx.x * blockDim.x + threadIdx.x;
  if (i >= N_EDGES + N_NODES) return;
  int s, d; float v;
  if (i < N_EDGES){ s = ei[i]; d = ei[N_EDGES + i]; v = ea[i]; }
  else            { s = d = i - N_EDGES; v = scal[0] * (1.0f / N_EDGES); }  // ea_mean
  int pos = row_ptr[d] + atomicAdd(&cursor[d], 1);
  csr_src[pos] = s;
  csr_dst[pos] = d;
  csr_ea[pos]  = v;
}

// per-edge softmax numerator, packed (src, w) for the aggregate hot loop.
// unstabilized exp is exact math (e^l / sum e^l); logits O(+-6)
__global__ void k_edgew(const float* __restrict__ a_s, const float* __restrict__ a_d,
                        const int* __restrict__ csr_src, const int* __restrict__ csr_dst,
                        const float* __restrict__ csr_ea, const float* __restrict__ scal,
                        int l, int2* __restrict__ csr_sw){
  int i = blockIdx.x * 256 + threadIdx.x;
  if (i >= N_EDGES + N_NODES) return;
  int s = csr_src[i];
  float lg = a_s[s] + a_d[csr_dst[i]] + scal[1 + l]*csr_ea[i];
  lg = (lg > 0.f) ? lg : SLOPE*lg;
  int2 p; p.x = s; p.y = __float_as_int(__expf(lg));
  csr_sw[i] = p;
}

// ---- MFMA GEMM: bf16 A (native), split-bf16 W (2-term), 64KB W in LDS -------
// Block = 256 thr = 4 waves; block tile 256 rows; wave tile 64 rows (4 m-tiles).
// mode 0: Cb=bf16(acc), a_s=acc·att1, a_d=acc·att2
// mode 1: Cb=bf16(relu(acc+bias))
// mode 2: relu(acc+bias)·att1 -> atomicAdd out[batch[row]]
__global__ __launch_bounds__(256, 2) void k_gemm(
    const unsigned short* __restrict__ Ab, const int* __restrict__ xmap,
    const unsigned short* __restrict__ Wf,      // fragment-ordered, 32768 ushorts
    unsigned short* __restrict__ Cb,
    const float* __restrict__ att1, const float* __restrict__ att2,
    float* __restrict__ a_s_out, float* __restrict__ a_d_out,
    const float* __restrict__ bias,
    const int* __restrict__ batch, float* __restrict__ out,
    int mode)
{
  __shared__ unsigned short lw[32768];   // 64 KB: hi plane then lo plane
  int tid  = threadIdx.x;
  int w    = tid >> 6;
  int lane = tid & 63;
  int q    = lane >> 4;
  int ln   = lane & 15;
  int waveRow = blockIdx.x*256 + w*64;

  // A fragments: native bf16, 16 B per (m, k0i)
  bf16x8 af[4][4];
  #pragma unroll
  for (int m = 0; m < 4; ++m){
    int r = waveRow + m*16 + ln;
    if (r >= N_NODES) r = N_NODES - 1;
    if (xmap) r = xmap[r];
    const unsigned short* Ar = Ab + (size_t)r*H;
    #pragma unroll
    for (int k0i = 0; k0i < 4; ++k0i)
      af[m][k0i] = *(const bf16x8*)(Ar + k0i*32 + q*8);
  }

  // stage full W (64 KB, coalesced 16B/thread x 16)
  #pragma unroll
  for (int i = 0; i < 16; ++i){
    int idx = (i*256 + tid) * 8;
    *(bf16x8*)(lw + idx) = *(const bf16x8*)(Wf + idx);
  }
  __syncthreads();

  f32x4 acc[4][8];
  #pragma unroll
  for (int m = 0; m < 4; ++m)
    #pragma unroll
    for (int ct = 0; ct < 8; ++ct) acc[m][ct] = (f32x4){0.f,0.f,0.f,0.f};

  #pragma unroll
  for (int k0i = 0; k0i < 4; ++k0i){
    #pragma unroll
    for (int ct = 0; ct < 8; ++ct){
      bf16x8 bhi = *(const bf16x8*)(lw + k0i*4096 + ct*512 + lane*8);
      bf16x8 blo = *(const bf16x8*)(lw + 16384 + k0i*4096 + ct*512 + lane*8);
      #pragma unroll
      for (int m = 0; m < 4; ++m){
        acc[m][ct] = __builtin_amdgcn_mfma_f32_16x16x32_bf16(af[m][k0i], blo, acc[m][ct], 0,0,0);
        acc[m][ct] = __builtin_amdgcn_mfma_f32_16x16x32_bf16(af[m][k0i], bhi, acc[m][ct], 0,0,0);
      }
    }
  }

  // C/D layout: col = ct*16 + ln, row = (m-tile base) + q*4 + r
  if (mode == 0){
    float as_l[8], ad_l[8];
    #pragma unroll
    for (int ct = 0; ct < 8; ++ct){ as_l[ct] = att1[ct*16+ln]; ad_l[ct] = att2[ct*16+ln]; }
    #pragma unroll
    for (int m = 0; m < 4; ++m){
      #pragma unroll
      for (int r = 0; r < 4; ++r){
        int grow = waveRow + m*16 + q*4 + r;
        bool ok = grow < N_NODES;
        float ps = 0.f, pd = 0.f;
        #pragma unroll
        for (int ct = 0; ct < 8; ++ct){
          float v = acc[m][ct][r];
          if (ok) Cb[(size_t)grow*H + ct*16 + ln] = rne_bf16(v);
          ps += v * as_l[ct]; pd += v * ad_l[ct];
        }
        #pragma unroll
        for (int mk = 8; mk > 0; mk >>= 1){
          ps += __shfl_xor(ps, mk, 64);
          pd += __shfl_xor(pd, mk, 64);
        }
        if (ok && ln == 0){ a_s_out[grow] = ps; a_d_out[grow] = pd; }
      }
    }
  } else if (mode == 1){
    float b_l[8];
    #pragma unroll
    for (int ct = 0; ct < 8; ++ct) b_l[ct] = bias[ct*16+ln];
    #pragma unroll
    for (int m = 0; m < 4; ++m){
      #pragma unroll
      for (int r = 0; r < 4; ++r){
        int grow = waveRow + m*16 + q*4 + r;
        if (grow >= N_NODES) continue;
        #pragma unroll
        for (int ct = 0; ct < 8; ++ct)
          Cb[(size_t)grow*H + ct*16 + ln] = rne_bf16(fmaxf(acc[m][ct][r] + b_l[ct], 0.f));
      }
    }
  } else {
    float b_l[8], wp_l[8];
    #pragma unroll
    for (int ct = 0; ct < 8; ++ct){ b_l[ct] = bias[ct*16+ln]; wp_l[ct] = att1[ct*16+ln]; }
    #pragma unroll
    for (int m = 0; m < 4; ++m){
      #pragma unroll
      for (int r = 0; r < 4; ++r){
        int grow = waveRow + m*16 + q*4 + r;
        bool ok = grow < N_NODES;
        float ps = 0.f;
        #pragma unroll
        for (int ct = 0; ct < 8; ++ct)
          ps += fmaxf(acc[m][ct][r] + b_l[ct], 0.f) * wp_l[ct];
        #pragma unroll
        for (int mk = 8; mk > 0; mk >>= 1) ps += __shfl_xor(ps, mk, 64);
        if (ok && ln == 0) atomicAdd(&out[batch[grow]], ps);
      }
    }
  }
}

// ---- aggregate: one wave per node; bf16 gathers, bf16 packed output ---------
__global__ __launch_bounds__(256, 4) void k_aggregate(
    const unsigned int* __restrict__ xtb, const int2* __restrict__ csr_sw,
    const int* __restrict__ row_ptr, const int* __restrict__ deg,
    const float* __restrict__ bias, unsigned int* __restrict__ hb)
{
  int n = __builtin_amdgcn_readfirstlane(blockIdx.x*4 + (threadIdx.x >> 6));
  if (n >= N_NODES) return;
  int lane = threadIdx.x & 63;
  int beg = row_ptr[n];
  int d   = deg[n];              // >= 1 (self loop)

  float2 acc = make_float2(0.f, 0.f);
  float ss = 0.f;
  for (int j0 = 0; j0 < d; j0 += 8){
    int2 sw[8];
    #pragma unroll
    for (int u = 0; u < 8; ++u){
      int jj = j0 + u;
      sw[u] = csr_sw[beg + (jj < d ? jj : 0)];
      if (jj >= d) sw[u].y = 0;              // w = 0.0f
    }
    unsigned int xv[8];
    #pragma unroll
    for (int u = 0; u < 8; ++u)
      xv[u] = xtb[(size_t)sw[u].x*(H/2) + lane];
    #pragma unroll
    for (int u = 0; u < 8; ++u){
      float wgt = __int_as_float(sw[u].y);
      float x0 = __uint_as_float(xv[u] << 16);          // col lane*2
      float x1 = __uint_as_float(xv[u] & 0xFFFF0000u);  // col lane*2+1
      ss    += wgt;
      acc.x += wgt * x0;
      acc.y += wgt * x1;
    }
  }

  float2 bv = *(const float2*)(bias + lane*2);
  acc.x = acc.x/ss + bv.x;
  acc.y = acc.y/ss + bv.y;
  float sq = wave_reduce_sum(acc.x*acc.x + acc.y*acc.y);
  float nrm = fmaxf(sqrtf(sq), 1e-12f);
  unsigned int pk = ((unsigned int)rne_bf16(acc.y/nrm) << 16) | rne_bf16(acc.x/nrm);
  hb[(size_t)n*(H/2) + lane] = pk;
}

// ---- readout init -----------------------------------------------------------
__global__ void k_out_init(float* __restrict__ out, const float* __restrict__ wp_b){
  int g = blockIdx.x * blockDim.x + threadIdx.x;
  if (g < NG) out[g] = wp_b[0];
}

// ---- launch -----------------------------------------------------------------
extern "C" void kernel_launch(void* const* d_in, const int* in_sizes, int n_in,
                              void* d_out, int out_size, void* d_ws, size_t ws_size,
                              hipStream_t stream) {
  const int*   x          = (const int*)  d_in[0];
  const int*   edge_index = (const int*)  d_in[1];
  const float* edge_attr  = (const float*)d_in[2];
  const int*   batch      = (const int*)  d_in[3];
  const float* emb        = (const float*)d_in[4];
  const float* gat_W      = (const float*)d_in[5];
  const float* att_src    = (const float*)d_in[6];
  const float* att_dst    = (const float*)d_in[7];
  const float* edge_W     = (const float*)d_in[8];
  const float* att_edge   = (const float*)d_in[9];
  const float* gat_b      = (const float*)d_in[10];
  const float* lin_W      = (const float*)d_in[11];
  const float* lin_b      = (const float*)d_in[12];
  const float* wp_W       = (const float*)d_in[13];
  const float* wp_b       = (const float*)d_in[14];
  float* out = (float*)d_out;

  // workspace layout — 16B-aligned bf16 arrays first, then int2, then 4B arrays
  unsigned short* hb  = (unsigned short*)d_ws;          // N*H bf16
  unsigned short* xtb = hb + (size_t)N_NODES*H;         // N*H bf16
  unsigned short* Wt  = xtb + (size_t)N_NODES*H;        // 5*32768
  unsigned short* embb= Wt + 5*32768;                   // NV*H
  int2*  csr_sw = (int2*)(embb + NV*H);                 // E+N
  float* a_s    = (float*)(csr_sw + (N_EDGES + N_NODES)); // N
  float* a_d    = a_s + N_NODES;                        // N
  float* csr_ea = a_d + N_NODES;                        // E+N
  float* scal   = csr_ea + (N_EDGES + N_NODES);         // 8
  int*   deg    = (int*)(scal + 8);                     // N (zeroed)
  int*   cursor = deg + N_NODES;                        // N (zeroed)
  int*   row_ptr= cursor + N_NODES;                     // N
  int*   csr_src= row_ptr + N_NODES;                    // E+N
  int*   csr_dst= csr_src + (N_EDGES + N_NODES);        // E+N

  hipMemsetAsync(scal, 0, (size_t)(8 + 2*N_NODES) * sizeof(float), stream);

  k_ea_sum<<<256, 256, 0, stream>>>(edge_attr, scal);
  k_dots  <<<NLAYERS, 64, 0, stream>>>(edge_W, att_edge, scal);
  k_convW <<<(5*32768 + 255)/256, 256, 0, stream>>>(gat_W, lin_W, Wt);
  k_convE <<<(NV*H + 255)/256, 256, 0, stream>>>(emb, embb);
  k_deg   <<<(N_EDGES + N_NODES + 255)/256, 256, 0, stream>>>(edge_index, deg);
  k_alloc <<<(N_NODES + 255)/256, 256, 0, stream>>>(deg, row_ptr, (int*)&scal[4]);
  k_scatter<<<(N_EDGES + N_NODES + 255)/256, 256, 0, stream>>>(
      edge_index, edge_attr, scal, row_ptr, cursor, csr_src, csr_dst, csr_ea);
  k_out_init<<<(NG + 255)/256, 256, 0, stream>>>(out, wp_b);

  const int gemm_grid = (N_NODES + 255) / 256;
  const int edge_grid = (N_EDGES + N_NODES + 255) / 256;
  for (int l = 0; l < NLAYERS; ++l){
    k_gemm<<<gemm_grid, 256, 0, stream>>>(
        (l == 0) ? embb : hb, (l == 0) ? x : nullptr,
        Wt + (size_t)l*32768, xtb,
        att_src + l*H, att_dst + l*H, a_s, a_d,
        nullptr, nullptr, nullptr, 0);
    k_edgew<<<edge_grid, 256, 0, stream>>>(
        a_s, a_d, csr_src, csr_dst, csr_ea, scal, l, csr_sw);
    k_aggregate<<<N_NODES/4, 256, 0, stream>>>(
        (const unsigned int*)xtb, csr_sw, row_ptr, deg, gat_b + l*H,
        (unsigned int*)hb);
  }
  // dense 1: hb -> xtb (relu+bias, bf16)
  k_gemm<<<gemm_grid, 256, 0, stream>>>(
      hb, nullptr, Wt + (size_t)3*32768, xtb,
      nullptr, nullptr, nullptr, nullptr, lin_b, nullptr, nullptr, 1);
  // dense 2 + fused readout: relu(xtb@W+b)·wp -> atomicAdd out[batch]
  k_gemm<<<gemm_grid, 256, 0, stream>>>(
      xtb, nullptr, Wt + (size_t)4*32768, nullptr,
      wp_W, nullptr, nullptr, nullptr, lin_b + H, batch, out, 2);
}

// Round 10
// 374.656 us; speedup vs baseline: 2.3755x; 1.0296x over previous
//
#include <hip/hip_runtime.h>
#include <math.h>

#define N_NODES 100000
#define N_EDGES 400000
#define NG 2048
#define H 128
#define NV 100
#define NLAYERS 3
#define SLOPE 0.2f

typedef __attribute__((ext_vector_type(8))) short bf16x8;
typedef __attribute__((ext_vector_type(4))) float f32x4;

__device__ __forceinline__ float wave_reduce_sum(float v){
  #pragma unroll
  for (int off = 32; off > 0; off >>= 1) v += __shfl_xor(v, off, 64);
  return v;
}
__device__ __forceinline__ unsigned short bfhi(float f){
  return (unsigned short)(__float_as_uint(f) >> 16);   // truncation; lo term compensates
}
__device__ __forceinline__ float bftof(unsigned short h){
  return __uint_as_float(((unsigned int)h) << 16);
}
__device__ __forceinline__ unsigned short rne_bf16(float f){
  unsigned int u = __float_as_uint(f);
  u += 0x7FFF + ((u >> 16) & 1);
  return (unsigned short)(u >> 16);
}

// ---- fused prep: convW | convE | out_init | dots | ea_sum | deg -------------
// All depend only on the preceding memset; branch by block range.
#define PB_CONVW 640                    // 5*32768/256
#define PB_CONVE (PB_CONVW + 50)        // NV*H/256
#define PB_OUT   (PB_CONVE + 8)         // NG/256
#define PB_DOTS  (PB_OUT + 1)           // 3 waves in one block
#define PB_EASUM (PB_DOTS + 256)
#define PB_DEG   (PB_EASUM + 1954)      // (E+N)/256
__global__ __launch_bounds__(256) void k_prep(
    const float* __restrict__ gat_W, const float* __restrict__ lin_W,
    unsigned short* __restrict__ Wf,
    const float* __restrict__ emb, unsigned short* __restrict__ embb,
    const float* __restrict__ ea, const float* __restrict__ ew,
    const float* __restrict__ ae, float* __restrict__ scal,
    const float* __restrict__ wp_b, float* __restrict__ out,
    const int* __restrict__ ei, int* __restrict__ deg)
{
  int b = blockIdx.x, tid = threadIdx.x;
  if (b < PB_CONVW){
    // W -> bf16 hi/lo in MFMA B-fragment order:
    // idx = m*32768 + p*16384 + k0i*4096 + ct*512 + lane*8 + j
    // k = k0i*32 + (lane>>4)*8 + j, n = ct*16 + (lane&15)
    int i = b*256 + tid;
    int m   = i >> 15;
    int r   = i & 32767;
    int p   = r >> 14;
    int r2  = r & 16383;
    int k0i = r2 >> 12;
    int r3  = r2 & 4095;
    int ct  = r3 >> 9;
    int r4  = r3 & 511;
    int lane= r4 >> 3;
    int j   = r4 & 7;
    int q = lane >> 4, ln = lane & 15;
    int k = k0i*32 + q*8 + j;
    int n = ct*16 + ln;
    const float* src = (m < 3) ? (gat_W + m*16384) : (lin_W + (m-3)*16384);
    float w = src[k*H + n];
    unsigned short hi = bfhi(w);
    Wf[i] = (p == 0) ? hi : bfhi(w - bftof(hi));
  } else if (b < PB_CONVE){
    int i = (b - PB_CONVW)*256 + tid;
    if (i < NV*H) embb[i] = rne_bf16(emb[i]);
  } else if (b < PB_OUT){
    int g = (b - PB_CONVE)*256 + tid;
    if (g < NG) out[g] = wp_b[0];
  } else if (b < PB_DOTS){
    int l = tid >> 6, ln = tid & 63;
    if (l < NLAYERS){
      float p = ew[l*H + ln]*ae[l*H + ln] + ew[l*H + ln + 64]*ae[l*H + ln + 64];
      p = wave_reduce_sum(p);
      if (ln == 0) scal[1 + l] = p;
    }
  } else if (b < PB_EASUM){
    int i = (b - PB_DOTS)*256 + tid;
    int stride = 256*256;
    float v = 0.f;
    for (; i < N_EDGES; i += stride) v += ea[i];
    v = wave_reduce_sum(v);
    if ((tid & 63) == 0) atomicAdd(&scal[0], v);
  } else {
    int i = (b - PB_EASUM)*256 + tid;
    if (i < N_EDGES + N_NODES){
      int d = (i < N_EDGES) ? ei[N_EDGES + i] : (i - N_EDGES);
      atomicAdd(&deg[d], 1);
    }
  }
}

// block scan + one atomic per block (CSR range order across nodes irrelevant)
__global__ __launch_bounds__(256) void k_alloc(
    const int* __restrict__ deg, int* __restrict__ row_ptr, int* __restrict__ counter){
  __shared__ int wsum[4];
  __shared__ int base;
  int n = blockIdx.x * 256 + threadIdx.x;
  int d = (n < N_NODES) ? deg[n] : 0;
  int lane = threadIdx.x & 63, wid = threadIdx.x >> 6;
  int v = d;
  #pragma unroll
  for (int off = 1; off < 64; off <<= 1){
    int u = __shfl_up(v, off, 64);
    if (lane >= off) v += u;
  }
  if (lane == 63) wsum[wid] = v;
  __syncthreads();
  if (threadIdx.x == 0){
    int t0 = wsum[0], t1 = wsum[1], t2 = wsum[2], t3 = wsum[3];
    base = atomicAdd(counter, t0 + t1 + t2 + t3);
    wsum[0] = 0; wsum[1] = t0; wsum[2] = t0 + t1; wsum[3] = t0 + t1 + t2;
  }
  __syncthreads();
  if (n < N_NODES) row_ptr[n] = base + wsum[wid] + (v - d);
}

__global__ void k_scatter(const int* __restrict__ ei, const float* __restrict__ ea,
                          const float* __restrict__ scal, const int* __restrict__ row_ptr,
                          int* __restrict__ cursor, int* __restrict__ csr_src,
                          float* __restrict__ csr_ea){
  int i = blockIdx.x * blockDim.x + threadIdx.x;
  if (i >= N_EDGES + N_NODES) return;
  int s, d; float v;
  if (i < N_EDGES){ s = ei[i]; d = ei[N_EDGES + i]; v = ea[i]; }
  else            { s = d = i - N_EDGES; v = scal[0] * (1.0f / N_EDGES); }  // ea_mean
  int pos = row_ptr[d] + atomicAdd(&cursor[d], 1);
  csr_src[pos] = s;
  csr_ea[pos]  = v;
}

// ---- MFMA GEMM: bf16 A (native), split-bf16 W (2-term), 64KB W in LDS -------
// Block = 256 thr = 4 waves; block tile 256 rows; wave tile 64 rows (4 m-tiles).
// mode 0: Cb=bf16(acc), a_s=acc·att1, a_d=acc·att2
// mode 1: Cb=bf16(relu(acc+bias))
// mode 2: relu(acc+bias)·att1 -> atomicAdd out[batch[row]]
__global__ __launch_bounds__(256, 2) void k_gemm(
    const unsigned short* __restrict__ Ab, const int* __restrict__ xmap,
    const unsigned short* __restrict__ Wf,      // fragment-ordered, 32768 ushorts
    unsigned short* __restrict__ Cb,
    const float* __restrict__ att1, const float* __restrict__ att2,
    float* __restrict__ a_s_out, float* __restrict__ a_d_out,
    const float* __restrict__ bias,
    const int* __restrict__ batch, float* __restrict__ out,
    int mode)
{
  __shared__ unsigned short lw[32768];   // 64 KB: hi plane then lo plane
  int tid  = threadIdx.x;
  int w    = tid >> 6;
  int lane = tid & 63;
  int q    = lane >> 4;
  int ln   = lane & 15;
  int waveRow = blockIdx.x*256 + w*64;

  // A fragments: native bf16, 16 B per (m, k0i)
  bf16x8 af[4][4];
  #pragma unroll
  for (int m = 0; m < 4; ++m){
    int r = waveRow + m*16 + ln;
    if (r >= N_NODES) r = N_NODES - 1;
    if (xmap) r = xmap[r];
    const unsigned short* Ar = Ab + (size_t)r*H;
    #pragma unroll
    for (int k0i = 0; k0i < 4; ++k0i)
      af[m][k0i] = *(const bf16x8*)(Ar + k0i*32 + q*8);
  }

  // stage full W (64 KB, coalesced 16B/thread x 16)
  #pragma unroll
  for (int i = 0; i < 16; ++i){
    int idx = (i*256 + tid) * 8;
    *(bf16x8*)(lw + idx) = *(const bf16x8*)(Wf + idx);
  }
  __syncthreads();

  f32x4 acc[4][8];
  #pragma unroll
  for (int m = 0; m < 4; ++m)
    #pragma unroll
    for (int ct = 0; ct < 8; ++ct) acc[m][ct] = (f32x4){0.f,0.f,0.f,0.f};

  #pragma unroll
  for (int k0i = 0; k0i < 4; ++k0i){
    #pragma unroll
    for (int ct = 0; ct < 8; ++ct){
      bf16x8 bhi = *(const bf16x8*)(lw + k0i*4096 + ct*512 + lane*8);
      bf16x8 blo = *(const bf16x8*)(lw + 16384 + k0i*4096 + ct*512 + lane*8);
      #pragma unroll
      for (int m = 0; m < 4; ++m){
        acc[m][ct] = __builtin_amdgcn_mfma_f32_16x16x32_bf16(af[m][k0i], blo, acc[m][ct], 0,0,0);
        acc[m][ct] = __builtin_amdgcn_mfma_f32_16x16x32_bf16(af[m][k0i], bhi, acc[m][ct], 0,0,0);
      }
    }
  }

  // C/D layout: col = ct*16 + ln, row = (m-tile base) + q*4 + r
  if (mode == 0){
    float as_l[8], ad_l[8];
    #pragma unroll
    for (int ct = 0; ct < 8; ++ct){ as_l[ct] = att1[ct*16+ln]; ad_l[ct] = att2[ct*16+ln]; }
    #pragma unroll
    for (int m = 0; m < 4; ++m){
      #pragma unroll
      for (int r = 0; r < 4; ++r){
        int grow = waveRow + m*16 + q*4 + r;
        bool ok = grow < N_NODES;
        float ps = 0.f, pd = 0.f;
        #pragma unroll
        for (int ct = 0; ct < 8; ++ct){
          float v = acc[m][ct][r];
          if (ok) Cb[(size_t)grow*H + ct*16 + ln] = rne_bf16(v);
          ps += v * as_l[ct]; pd += v * ad_l[ct];
        }
        #pragma unroll
        for (int mk = 8; mk > 0; mk >>= 1){
          ps += __shfl_xor(ps, mk, 64);
          pd += __shfl_xor(pd, mk, 64);
        }
        if (ok && ln == 0){ a_s_out[grow] = ps; a_d_out[grow] = pd; }
      }
    }
  } else if (mode == 1){
    float b_l[8];
    #pragma unroll
    for (int ct = 0; ct < 8; ++ct) b_l[ct] = bias[ct*16+ln];
    #pragma unroll
    for (int m = 0; m < 4; ++m){
      #pragma unroll
      for (int r = 0; r < 4; ++r){
        int grow = waveRow + m*16 + q*4 + r;
        if (grow >= N_NODES) continue;
        #pragma unroll
        for (int ct = 0; ct < 8; ++ct)
          Cb[(size_t)grow*H + ct*16 + ln] = rne_bf16(fmaxf(acc[m][ct][r] + b_l[ct], 0.f));
      }
    }
  } else {
    float b_l[8], wp_l[8];
    #pragma unroll
    for (int ct = 0; ct < 8; ++ct){ b_l[ct] = bias[ct*16+ln]; wp_l[ct] = att1[ct*16+ln]; }
    #pragma unroll
    for (int m = 0; m < 4; ++m){
      #pragma unroll
      for (int r = 0; r < 4; ++r){
        int grow = waveRow + m*16 + q*4 + r;
        bool ok = grow < N_NODES;
        float ps = 0.f;
        #pragma unroll
        for (int ct = 0; ct < 8; ++ct)
          ps += fmaxf(acc[m][ct][r] + b_l[ct], 0.f) * wp_l[ct];
        #pragma unroll
        for (int mk = 8; mk > 0; mk >>= 1) ps += __shfl_xor(ps, mk, 64);
        if (ok && ln == 0) atomicAdd(&out[batch[grow]], ps);
      }
    }
  }
}

// ---- aggregate with fused edge weights --------------------------------------
// One wave per node. Lanes 0..cnt-1 compute per-edge softmax numerators in
// parallel (coalesced csr loads, parallel a_s gathers, one exp per edge);
// (src,w) then broadcast via wave-uniform shuffles into the 8-deep gather loop.
// Unstabilized exp is exact math (e^l/sum e^l); logits O(+-6).
__global__ __launch_bounds__(256, 4) void k_aggregate(
    const unsigned int* __restrict__ xtb, const float* __restrict__ a_s,
    const float* __restrict__ a_d, const int* __restrict__ csr_src,
    const float* __restrict__ csr_ea, const int* __restrict__ row_ptr,
    const int* __restrict__ deg, const float* __restrict__ scal, int l,
    const float* __restrict__ bias, unsigned int* __restrict__ hb)
{
  int n = __builtin_amdgcn_readfirstlane(blockIdx.x*4 + (threadIdx.x >> 6));
  if (n >= N_NODES) return;
  int lane = threadIdx.x & 63;
  int beg = row_ptr[n];
  int d   = deg[n];              // >= 1 (self loop)
  float dl  = scal[1 + l];
  float adn = a_d[n];

  float2 acc = make_float2(0.f, 0.f);
  float ss = 0.f;
  for (int base = 0; base < d; base += 64){
    int cnt = min(64, d - base);
    int s = 0; float wgt = 0.f;
    if (lane < cnt){
      int e = beg + base + lane;
      s = csr_src[e];                                   // coalesced
      float lg = a_s[s] + adn + dl*csr_ea[e];
      lg = (lg > 0.f) ? lg : SLOPE*lg;
      wgt = __expf(lg);
    }
    for (int u = 0; u < cnt; u += 8){
      int s8[8]; float w8[8];
      #pragma unroll
      for (int j = 0; j < 8; ++j){
        int uu = u + j;
        s8[j] = __shfl(s, uu < cnt ? uu : 0, 64);
        w8[j] = (uu < cnt) ? __shfl(wgt, uu, 64) : 0.f;
      }
      unsigned int xv[8];
      #pragma unroll
      for (int j = 0; j < 8; ++j)
        xv[j] = xtb[(size_t)s8[j]*(H/2) + lane];
      #pragma unroll
      for (int j = 0; j < 8; ++j){
        float x0 = __uint_as_float(xv[j] << 16);          // col lane*2
        float x1 = __uint_as_float(xv[j] & 0xFFFF0000u);  // col lane*2+1
        ss    += w8[j];
        acc.x += w8[j] * x0;
        acc.y += w8[j] * x1;
      }
    }
  }

  float2 bv = *(const float2*)(bias + lane*2);
  acc.x = acc.x/ss + bv.x;
  acc.y = acc.y/ss + bv.y;
  float sq = wave_reduce_sum(acc.x*acc.x + acc.y*acc.y);
  float nrm = fmaxf(sqrtf(sq), 1e-12f);
  unsigned int pk = ((unsigned int)rne_bf16(acc.y/nrm) << 16) | rne_bf16(acc.x/nrm);
  hb[(size_t)n*(H/2) + lane] = pk;
}

// ---- launch -----------------------------------------------------------------
extern "C" void kernel_launch(void* const* d_in, const int* in_sizes, int n_in,
                              void* d_out, int out_size, void* d_ws, size_t ws_size,
                              hipStream_t stream) {
  const int*   x          = (const int*)  d_in[0];
  const int*   edge_index = (const int*)  d_in[1];
  const float* edge_attr  = (const float*)d_in[2];
  const int*   batch      = (const int*)  d_in[3];
  const float* emb        = (const float*)d_in[4];
  const float* gat_W      = (const float*)d_in[5];
  const float* att_src    = (const float*)d_in[6];
  const float* att_dst    = (const float*)d_in[7];
  const float* edge_W     = (const float*)d_in[8];
  const float* att_edge   = (const float*)d_in[9];
  const float* gat_b      = (const float*)d_in[10];
  const float* lin_W      = (const float*)d_in[11];
  const float* lin_b      = (const float*)d_in[12];
  const float* wp_W       = (const float*)d_in[13];
  const float* wp_b       = (const float*)d_in[14];
  float* out = (float*)d_out;

  // workspace layout — 16B-aligned bf16 arrays first, then 4B arrays
  unsigned short* hb  = (unsigned short*)d_ws;          // N*H bf16
  unsigned short* xtb = hb + (size_t)N_NODES*H;         // N*H bf16
  unsigned short* Wt  = xtb + (size_t)N_NODES*H;        // 5*32768
  unsigned short* embb= Wt + 5*32768;                   // NV*H
  float* a_s    = (float*)(embb + NV*H);                // N
  float* a_d    = a_s + N_NODES;                        // N
  float* csr_ea = a_d + N_NODES;                        // E+N
  float* scal   = csr_ea + (N_EDGES + N_NODES);         // 8
  int*   deg    = (int*)(scal + 8);                     // N (zeroed)
  int*   cursor = deg + N_NODES;                        // N (zeroed)
  int*   row_ptr= cursor + N_NODES;                     // N
  int*   csr_src= row_ptr + N_NODES;                    // E+N

  hipMemsetAsync(scal, 0, (size_t)(8 + 2*N_NODES) * sizeof(float), stream);

  k_prep<<<PB_DEG, 256, 0, stream>>>(
      gat_W, lin_W, Wt, emb, embb, edge_attr, edge_W, att_edge, scal,
      wp_b, out, edge_index, deg);
  k_alloc<<<(N_NODES + 255)/256, 256, 0, stream>>>(deg, row_ptr, (int*)&scal[4]);
  k_scatter<<<(N_EDGES + N_NODES + 255)/256, 256, 0, stream>>>(
      edge_index, edge_attr, scal, row_ptr, cursor, csr_src, csr_ea);

  const int gemm_grid = (N_NODES + 255) / 256;
  for (int l = 0; l < NLAYERS; ++l){
    k_gemm<<<gemm_grid, 256, 0, stream>>>(
        (l == 0) ? embb : hb, (l == 0) ? x : nullptr,
        Wt + (size_t)l*32768, xtb,
        att_src + l*H, att_dst + l*H, a_s, a_d,
        nullptr, nullptr, nullptr, 0);
    k_aggregate<<<N_NODES/4, 256, 0, stream>>>(
        (const unsigned int*)xtb, a_s, a_d, csr_src, csr_ea, row_ptr, deg,
        scal, l, gat_b + l*H, (unsigned int*)hb);
  }
  // dense 1: hb -> xtb (relu+bias, bf16)
  k_gemm<<<gemm_grid, 256, 0, stream>>>(
      hb, nullptr, Wt + (size_t)3*32768, xtb,
      nullptr, nullptr, nullptr, nullptr, lin_b, nullptr, nullptr, 1);
  // dense 2 + fused readout: relu(xtb@W+b)·wp -> atomicAdd out[batch]
  k_gemm<<<gemm_grid, 256, 0, stream>>>(
      xtb, nullptr, Wt + (size_t)4*32768, nullptr,
      wp_W, nullptr, nullptr, nullptr, lin_b + H, batch, out, 2);
}

// Round 12
// 372.261 us; speedup vs baseline: 2.3908x; 1.0064x over previous
//
#include <hip/hip_runtime.h>
#include <math.h>

#define N_NODES 100000
#define N_EDGES 400000
#define NG 2048
#define H 128
#define NV 100
#define NLAYERS 3
#define SLOPE 0.2f

// scal layout (64 floats = 256 B, all zeroed):
//  [0]      ea_sum        (atomic, k_prep)
//  [32+l]   dot_l l=0..2  (atomic, k_prep — separate 128B line from [0])
//  [48]     alloc counter (atomic, k_alloc — no plain stores on its line then)
#define SCAL_N 64

typedef __attribute__((ext_vector_type(8))) short bf16x8;
typedef __attribute__((ext_vector_type(4))) float f32x4;

__device__ __forceinline__ float wave_reduce_sum(float v){
  #pragma unroll
  for (int off = 32; off > 0; off >>= 1) v += __shfl_xor(v, off, 64);
  return v;
}
__device__ __forceinline__ unsigned short bfhi(float f){
  return (unsigned short)(__float_as_uint(f) >> 16);   // truncation; lo term compensates
}
__device__ __forceinline__ float bftof(unsigned short h){
  return __uint_as_float(((unsigned int)h) << 16);
}
__device__ __forceinline__ unsigned short rne_bf16(float f){
  unsigned int u = __float_as_uint(f);
  u += 0x7FFF + ((u >> 16) & 1);
  return (unsigned short)(u >> 16);
}

// ---- fused prep: convW | convE | out_init | dots | ea_sum | deg -------------
// NOTE: every write to the scal region in this dispatch is ATOMIC — mixed
// atomic/non-atomic traffic on one cache line across XCDs (non-coherent L2s)
// caused the R11 flaky post-timing divergence.
#define PB_CONVW 640                    // 5*32768/256
#define PB_CONVE (PB_CONVW + 50)        // NV*H/256
#define PB_OUT   (PB_CONVE + 8)         // NG/256
#define PB_DOTS  (PB_OUT + 1)           // 3 waves in one block
#define PB_EASUM (PB_DOTS + 256)
#define PB_DEG   (PB_EASUM + 1954)      // (E+N)/256
__global__ __launch_bounds__(256) void k_prep(
    const float* __restrict__ gat_W, const float* __restrict__ lin_W,
    unsigned short* __restrict__ Wf,
    const float* __restrict__ emb, unsigned short* __restrict__ embb,
    const float* __restrict__ ea, const float* __restrict__ ew,
    const float* __restrict__ ae, float* __restrict__ scal,
    const float* __restrict__ wp_b, float* __restrict__ out,
    const int* __restrict__ ei, int* __restrict__ deg)
{
  int b = blockIdx.x, tid = threadIdx.x;
  if (b < PB_CONVW){
    // W -> bf16 hi/lo in MFMA B-fragment order:
    // idx = m*32768 + p*16384 + k0i*4096 + ct*512 + lane*8 + j
    // k = k0i*32 + (lane>>4)*8 + j, n = ct*16 + (lane&15)
    int i = b*256 + tid;
    int m   = i >> 15;
    int r   = i & 32767;
    int p   = r >> 14;
    int r2  = r & 16383;
    int k0i = r2 >> 12;
    int r3  = r2 & 4095;
    int ct  = r3 >> 9;
    int r4  = r3 & 511;
    int lane= r4 >> 3;
    int j   = r4 & 7;
    int q = lane >> 4, ln = lane & 15;
    int k = k0i*32 + q*8 + j;
    int n = ct*16 + ln;
    const float* src = (m < 3) ? (gat_W + m*16384) : (lin_W + (m-3)*16384);
    float w = src[k*H + n];
    unsigned short hi = bfhi(w);
    Wf[i] = (p == 0) ? hi : bfhi(w - bftof(hi));
  } else if (b < PB_CONVE){
    int i = (b - PB_CONVW)*256 + tid;
    if (i < NV*H) embb[i] = rne_bf16(emb[i]);
  } else if (b < PB_OUT){
    int g = (b - PB_CONVE)*256 + tid;
    if (g < NG) out[g] = wp_b[0];
  } else if (b < PB_DOTS){
    int l = tid >> 6, ln = tid & 63;
    if (l < NLAYERS){
      float p = ew[l*H + ln]*ae[l*H + ln] + ew[l*H + ln + 64]*ae[l*H + ln + 64];
      p = wave_reduce_sum(p);
      if (ln == 0) atomicAdd(&scal[32 + l], p);   // atomic: no dirty-line hazard
    }
  } else if (b < PB_EASUM){
    int i = (b - PB_DOTS)*256 + tid;
    int stride = 256*256;
    float v = 0.f;
    for (; i < N_EDGES; i += stride) v += ea[i];
    v = wave_reduce_sum(v);
    if ((tid & 63) == 0) atomicAdd(&scal[0], v);
  } else {
    int i = (b - PB_EASUM)*256 + tid;
    if (i < N_EDGES + N_NODES){
      int d = (i < N_EDGES) ? ei[N_EDGES + i] : (i - N_EDGES);
      atomicAdd(&deg[d], 1);
    }
  }
}

// block scan + one atomic per block (CSR range order across nodes irrelevant)
__global__ __launch_bounds__(256) void k_alloc(
    const int* __restrict__ deg, int* __restrict__ row_ptr, int* __restrict__ counter){
  __shared__ int wsum[4];
  __shared__ int base;
  int n = blockIdx.x * 256 + threadIdx.x;
  int d = (n < N_NODES) ? deg[n] : 0;
  int lane = threadIdx.x & 63, wid = threadIdx.x >> 6;
  int v = d;
  #pragma unroll
  for (int off = 1; off < 64; off <<= 1){
    int u = __shfl_up(v, off, 64);
    if (lane >= off) v += u;
  }
  if (lane == 63) wsum[wid] = v;
  __syncthreads();
  if (threadIdx.x == 0){
    int t0 = wsum[0], t1 = wsum[1], t2 = wsum[2], t3 = wsum[3];
    base = atomicAdd(counter, t0 + t1 + t2 + t3);
    wsum[0] = 0; wsum[1] = t0; wsum[2] = t0 + t1; wsum[3] = t0 + t1 + t2;
  }
  __syncthreads();
  if (n < N_NODES) row_ptr[n] = base + wsum[wid] + (v - d);
}

__global__ void k_scatter(const int* __restrict__ ei, const float* __restrict__ ea,
                          const float* __restrict__ scal, const int* __restrict__ row_ptr,
                          int* __restrict__ cursor, int* __restrict__ csr_src,
                          int* __restrict__ csr_dst, float* __restrict__ csr_ea){
  int i = blockIdx.x * blockDim.x + threadIdx.x;
  if (i >= N_EDGES + N_NODES) return;
  int s, d; float v;
  if (i < N_EDGES){ s = ei[i]; d = ei[N_EDGES + i]; v = ea[i]; }
  else            { s = d = i - N_EDGES; v = scal[0] * (1.0f / N_EDGES); }  // ea_mean
  int pos = row_ptr[d] + atomicAdd(&cursor[d], 1);
  csr_src[pos] = s;
  csr_dst[pos] = d;
  csr_ea[pos]  = v;
}

// per-edge softmax numerator, packed (src, w) for the aggregate hot loop.
// unstabilized exp is exact math (e^l / sum e^l); logits O(+-6)
__global__ void k_edgew(const float* __restrict__ a_s, const float* __restrict__ a_d,
                        const int* __restrict__ csr_src, const int* __restrict__ csr_dst,
                        const float* __restrict__ csr_ea, const float* __restrict__ scal,
                        int l, int2* __restrict__ csr_sw){
  int i = blockIdx.x * 256 + threadIdx.x;
  if (i >= N_EDGES + N_NODES) return;
  int s = csr_src[i];
  float lg = a_s[s] + a_d[csr_dst[i]] + scal[32 + l]*csr_ea[i];
  lg = (lg > 0.f) ? lg : SLOPE*lg;
  int2 p; p.x = s; p.y = __float_as_int(__expf(lg));
  csr_sw[i] = p;
}

// ---- MFMA GEMM: bf16 A (native), split-bf16 W (2-term), 64KB W in LDS -------
// Block = 256 thr = 4 waves; block tile 256 rows; wave tile 64 rows (4 m-tiles).
// mode 0: Cb=bf16(acc), a_s=acc·att1, a_d=acc·att2
// mode 1: Cb=bf16(relu(acc+bias))
// mode 2: relu(acc+bias)·att1 -> atomicAdd out[batch[row]]
__global__ __launch_bounds__(256, 2) void k_gemm(
    const unsigned short* __restrict__ Ab, const int* __restrict__ xmap,
    const unsigned short* __restrict__ Wf,      // fragment-ordered, 32768 ushorts
    unsigned short* __restrict__ Cb,
    const float* __restrict__ att1, const float* __restrict__ att2,
    float* __restrict__ a_s_out, float* __restrict__ a_d_out,
    const float* __restrict__ bias,
    const int* __restrict__ batch, float* __restrict__ out,
    int mode)
{
  __shared__ unsigned short lw[32768];   // 64 KB: hi plane then lo plane
  int tid  = threadIdx.x;
  int w    = tid >> 6;
  int lane = tid & 63;
  int q    = lane >> 4;
  int ln   = lane & 15;
  int waveRow = blockIdx.x*256 + w*64;

  // A fragments: native bf16, 16 B per (m, k0i)
  bf16x8 af[4][4];
  #pragma unroll
  for (int m = 0; m < 4; ++m){
    int r = waveRow + m*16 + ln;
    if (r >= N_NODES) r = N_NODES - 1;
    if (xmap) r = xmap[r];
    const unsigned short* Ar = Ab + (size_t)r*H;
    #pragma unroll
    for (int k0i = 0; k0i < 4; ++k0i)
      af[m][k0i] = *(const bf16x8*)(Ar + k0i*32 + q*8);
  }

  // stage full W (64 KB, coalesced 16B/thread x 16)
  #pragma unroll
  for (int i = 0; i < 16; ++i){
    int idx = (i*256 + tid) * 8;
    *(bf16x8*)(lw + idx) = *(const bf16x8*)(Wf + idx);
  }
  __syncthreads();

  f32x4 acc[4][8];
  #pragma unroll
  for (int m = 0; m < 4; ++m)
    #pragma unroll
    for (int ct = 0; ct < 8; ++ct) acc[m][ct] = (f32x4){0.f,0.f,0.f,0.f};

  #pragma unroll
  for (int k0i = 0; k0i < 4; ++k0i){
    #pragma unroll
    for (int ct = 0; ct < 8; ++ct){
      bf16x8 bhi = *(const bf16x8*)(lw + k0i*4096 + ct*512 + lane*8);
      bf16x8 blo = *(const bf16x8*)(lw + 16384 + k0i*4096 + ct*512 + lane*8);
      #pragma unroll
      for (int m = 0; m < 4; ++m){
        acc[m][ct] = __builtin_amdgcn_mfma_f32_16x16x32_bf16(af[m][k0i], blo, acc[m][ct], 0,0,0);
        acc[m][ct] = __builtin_amdgcn_mfma_f32_16x16x32_bf16(af[m][k0i], bhi, acc[m][ct], 0,0,0);
      }
    }
  }

  // C/D layout: col = ct*16 + ln, row = (m-tile base) + q*4 + r
  if (mode == 0){
    float as_l[8], ad_l[8];
    #pragma unroll
    for (int ct = 0; ct < 8; ++ct){ as_l[ct] = att1[ct*16+ln]; ad_l[ct] = att2[ct*16+ln]; }
    #pragma unroll
    for (int m = 0; m < 4; ++m){
      #pragma unroll
      for (int r = 0; r < 4; ++r){
        int grow = waveRow + m*16 + q*4 + r;
        bool ok = grow < N_NODES;
        float ps = 0.f, pd = 0.f;
        #pragma unroll
        for (int ct = 0; ct < 8; ++ct){
          float v = acc[m][ct][r];
          if (ok) Cb[(size_t)grow*H + ct*16 + ln] = rne_bf16(v);
          ps += v * as_l[ct]; pd += v * ad_l[ct];
        }
        #pragma unroll
        for (int mk = 8; mk > 0; mk >>= 1){
          ps += __shfl_xor(ps, mk, 64);
          pd += __shfl_xor(pd, mk, 64);
        }
        if (ok && ln == 0){ a_s_out[grow] = ps; a_d_out[grow] = pd; }
      }
    }
  } else if (mode == 1){
    float b_l[8];
    #pragma unroll
    for (int ct = 0; ct < 8; ++ct) b_l[ct] = bias[ct*16+ln];
    #pragma unroll
    for (int m = 0; m < 4; ++m){
      #pragma unroll
      for (int r = 0; r < 4; ++r){
        int grow = waveRow + m*16 + q*4 + r;
        if (grow >= N_NODES) continue;
        #pragma unroll
        for (int ct = 0; ct < 8; ++ct)
          Cb[(size_t)grow*H + ct*16 + ln] = rne_bf16(fmaxf(acc[m][ct][r] + b_l[ct], 0.f));
      }
    }
  } else {
    float b_l[8], wp_l[8];
    #pragma unroll
    for (int ct = 0; ct < 8; ++ct){ b_l[ct] = bias[ct*16+ln]; wp_l[ct] = att1[ct*16+ln]; }
    #pragma unroll
    for (int m = 0; m < 4; ++m){
      #pragma unroll
      for (int r = 0; r < 4; ++r){
        int grow = waveRow + m*16 + q*4 + r;
        bool ok = grow < N_NODES;
        float ps = 0.f;
        #pragma unroll
        for (int ct = 0; ct < 8; ++ct)
          ps += fmaxf(acc[m][ct][r] + b_l[ct], 0.f) * wp_l[ct];
        #pragma unroll
        for (int mk = 8; mk > 0; mk >>= 1) ps += __shfl_xor(ps, mk, 64);
        if (ok && ln == 0) atomicAdd(&out[batch[grow]], ps);
      }
    }
  }
}

// ---- aggregate: one wave per node; precomputed (src,w); bf16 gathers --------
// Hot loop: 8 induction-addressed int2 broadcast loads, 8 independent 256B row
// gathers, 16 FMAs. No shuffles, no exp, no dependent addresses.
__global__ __launch_bounds__(256, 4) void k_aggregate(
    const unsigned int* __restrict__ xtb, const int2* __restrict__ csr_sw,
    const int* __restrict__ row_ptr, const int* __restrict__ deg,
    const float* __restrict__ bias, unsigned int* __restrict__ hb)
{
  int n = __builtin_amdgcn_readfirstlane(blockIdx.x*4 + (threadIdx.x >> 6));
  if (n >= N_NODES) return;
  int lane = threadIdx.x & 63;
  int beg = row_ptr[n];
  int d   = deg[n];              // >= 1 (self loop)

  float2 acc = make_float2(0.f, 0.f);
  float ss = 0.f;
  for (int j0 = 0; j0 < d; j0 += 8){
    int2 sw[8];
    #pragma unroll
    for (int u = 0; u < 8; ++u){
      int jj = j0 + u;
      sw[u] = csr_sw[beg + (jj < d ? jj : 0)];
      if (jj >= d) sw[u].y = 0;              // w = 0.0f
    }
    unsigned int xv[8];
    #pragma unroll
    for (int u = 0; u < 8; ++u)
      xv[u] = xtb[(size_t)sw[u].x*(H/2) + lane];
    #pragma unroll
    for (int u = 0; u < 8; ++u){
      float wgt = __int_as_float(sw[u].y);
      float x0 = __uint_as_float(xv[u] << 16);          // col lane*2
      float x1 = __uint_as_float(xv[u] & 0xFFFF0000u);  // col lane*2+1
      ss    += wgt;
      acc.x += wgt * x0;
      acc.y += wgt * x1;
    }
  }

  float2 bv = *(const float2*)(bias + lane*2);
  acc.x = acc.x/ss + bv.x;
  acc.y = acc.y/ss + bv.y;
  float sq = wave_reduce_sum(acc.x*acc.x + acc.y*acc.y);
  float nrm = fmaxf(sqrtf(sq), 1e-12f);
  unsigned int pk = ((unsigned int)rne_bf16(acc.y/nrm) << 16) | rne_bf16(acc.x/nrm);
  hb[(size_t)n*(H/2) + lane] = pk;
}

// ---- launch -----------------------------------------------------------------
extern "C" void kernel_launch(void* const* d_in, const int* in_sizes, int n_in,
                              void* d_out, int out_size, void* d_ws, size_t ws_size,
                              hipStream_t stream) {
  const int*   x          = (const int*)  d_in[0];
  const int*   edge_index = (const int*)  d_in[1];
  const float* edge_attr  = (const float*)d_in[2];
  const int*   batch      = (const int*)  d_in[3];
  const float* emb        = (const float*)d_in[4];
  const float* gat_W      = (const float*)d_in[5];
  const float* att_src    = (const float*)d_in[6];
  const float* att_dst    = (const float*)d_in[7];
  const float* edge_W     = (const float*)d_in[8];
  const float* att_edge   = (const float*)d_in[9];
  const float* gat_b      = (const float*)d_in[10];
  const float* lin_W      = (const float*)d_in[11];
  const float* lin_b      = (const float*)d_in[12];
  const float* wp_W       = (const float*)d_in[13];
  const float* wp_b       = (const float*)d_in[14];
  float* out = (float*)d_out;

  // workspace layout — 16B-aligned bf16 arrays first, then int2, then 4B arrays
  unsigned short* hb  = (unsigned short*)d_ws;          // N*H bf16
  unsigned short* xtb = hb + (size_t)N_NODES*H;         // N*H bf16
  unsigned short* Wt  = xtb + (size_t)N_NODES*H;        // 5*32768
  unsigned short* embb= Wt + 5*32768;                   // NV*H
  int2*  csr_sw = (int2*)(embb + NV*H);                 // E+N
  float* a_s    = (float*)(csr_sw + (N_EDGES + N_NODES)); // N
  float* a_d    = a_s + N_NODES;                        // N
  float* csr_ea = a_d + N_NODES;                        // E+N
  float* scal   = csr_ea + (N_EDGES + N_NODES);         // SCAL_N (zeroed)
  int*   deg    = (int*)(scal + SCAL_N);                // N (zeroed)
  int*   cursor = deg + N_NODES;                        // N (zeroed)
  int*   row_ptr= cursor + N_NODES;                     // N
  int*   csr_src= row_ptr + N_NODES;                    // E+N
  int*   csr_dst= csr_src + (N_EDGES + N_NODES);        // E+N

  hipMemsetAsync(scal, 0, (size_t)(SCAL_N + 2*N_NODES) * sizeof(float), stream);

  k_prep<<<PB_DEG, 256, 0, stream>>>(
      gat_W, lin_W, Wt, emb, embb, edge_attr, edge_W, att_edge, scal,
      wp_b, out, edge_index, deg);
  k_alloc<<<(N_NODES + 255)/256, 256, 0, stream>>>(deg, row_ptr, (int*)&scal[48]);
  k_scatter<<<(N_EDGES + N_NODES + 255)/256, 256, 0, stream>>>(
      edge_index, edge_attr, scal, row_ptr, cursor, csr_src, csr_dst, csr_ea);

  const int gemm_grid = (N_NODES + 255) / 256;
  const int edge_grid = (N_EDGES + N_NODES + 255) / 256;
  for (int l = 0; l < NLAYERS; ++l){
    k_gemm<<<gemm_grid, 256, 0, stream>>>(
        (l == 0) ? embb : hb, (l == 0) ? x : nullptr,
        Wt + (size_t)l*32768, xtb,
        att_src + l*H, att_dst + l*H, a_s, a_d,
        nullptr, nullptr, nullptr, 0);
    k_edgew<<<edge_grid, 256, 0, stream>>>(
        a_s, a_d, csr_src, csr_dst, csr_ea, scal, l, csr_sw);
    k_aggregate<<<N_NODES/4, 256, 0, stream>>>(
        (const unsigned int*)xtb, csr_sw, row_ptr, deg, gat_b + l*H,
        (unsigned int*)hb);
  }
  // dense 1: hb -> xtb (relu+bias, bf16)
  k_gemm<<<gemm_grid, 256, 0, stream>>>(
      hb, nullptr, Wt + (size_t)3*32768, xtb,
      nullptr, nullptr, nullptr, nullptr, lin_b, nullptr, nullptr, 1);
  // dense 2 + fused readout: relu(xtb@W+b)·wp -> atomicAdd out[batch]
  k_gemm<<<gemm_grid, 256, 0, stream>>>(
      xtb, nullptr, Wt + (size_t)4*32768, nullptr,
      wp_W, nullptr, nullptr, nullptr, lin_b + H, batch, out, 2);
}